// Round 5
// baseline (4029.008 us; speedup 1.0000x reference)
//
#include <hip/hip_runtime.h>
#include <hip/hip_bf16.h>

typedef unsigned short u16;
typedef unsigned int   u32;

#define NN    32768
#define NG    512
#define TSEQ  64
#define NE    131072
#define NP    65536
#define HD    128

__device__ __forceinline__ float bf2f(u16 v){ u32 u=((u32)v)<<16; float f; __builtin_memcpy(&f,&u,4); return f; }
__device__ __forceinline__ u16 f2bf(float f){ u32 u; __builtin_memcpy(&u,&f,4); u32 r=u+0x7fffu+((u>>16)&1u); return (u16)(r>>16); }
__device__ __forceinline__ float sigm(float x){ return 1.f/(1.f+__expf(-x)); }
__device__ __forceinline__ float tanhfast(float x){ return 1.f-2.f/(1.f+__expf(2.f*x)); }
// raw-input read: dt=1 -> bf16, dt=0 -> fp32
__device__ __forceinline__ float rg(const void* p, size_t i, int dt){
  return dt ? bf2f(((const u16*)p)[i]) : ((const float*)p)[i];
}

// A-source modes / epilogues
enum { A_XF, A_F32, A_B16, A_MSG, A_C3, A_EDGE, A_BOOST };
enum { E_LN_RELU, E_LN, E_LN_RELU_TANH, E_RESID_LN, E_HE0_RELU, E_GI, E_LN_RELU_DUAL };

// Register-tiled fp32 GEMM core (4x8 micro-tile). A staged once per chunk;
// W DOUBLE-BUFFERED in 16-k sub-chunks (2 x 8 KB LDS): next sub-chunk's W
// is prefetched into registers BEFORE computing the current one and written
// to the other buffer after (T14 issue-early/write-late) — barriers drain
// only ds_writes, not global-load latency. Total LDS ~51 KB -> 3 blocks/CU.
// NSEG>1 (E_GI only): loop NSEG weight segments over the SAME staged A,
// gate outputs written from registers as ushort4.
// fp32 FMA in ascending k-order (numerics preserved).
template<int AM, int EP, int NCH, int NSEG>
__launch_bounds__(256)
__global__ void k_dense(
    const void* a0v, const void* a1v, const void* a2v,
    const int* dsti, const int* ptr, const int* cidx, const void* abias,
    const void* W, const void* W2, int wbase,
    const void* bias, const void* bias2, const void* gamma, const void* beta, int prmoff,
    const float* resid, const u16* he0b,
    float* outf, u16* outb, u16* outb2, const int* dflag,
    int ktot, int astride, int ostride, int ocoff)
{
  __shared__ __align__(16) float sa[64*132];    // A tile (stride 132: rows 16B-aligned)
  __shared__ __align__(16) float wb[2][16*128]; // W sub-chunks [k][c], double-buffered
  float* so = sa;                 // reused for C after compute (NSEG==1 paths)
  __shared__ float s_mu[64], s_rs[64];
  __shared__ int s_e[64], s_pe[64], s_d[64];
  __shared__ float s_ab[128];

  const int dt  = *dflag;
  const int tid = threadIdx.x;
  const int bx  = blockIdx.x;

  if constexpr (AM==A_EDGE){
    if (tid < 64){
      int eb = bx*32;
      int e = (tid<32) ? (eb+tid) : (NP + eb + tid - 32);
      s_e[tid]  = e;
      s_pe[tid] = (tid<32) ? (e+NP) : (e-NP);
      s_d[tid]  = dsti[e];
    }
    __syncthreads();
  }
  if constexpr (AM==A_BOOST){
    if (tid < 128) s_ab[tid] = rg(abias, tid, dt);
    __syncthreads();
  }
  const int rbase = (AM==A_EDGE) ? 0 : bx*64;

  const int row = tid>>2, qq = tid&3;   // epilogue mapping
  const int ry4 = (tid>>4)*4;           // compute: rows ry4..ry4+3
  const int cxx = (tid&15)*4;           // compute: cols cxx..+3 and 64+cxx..+3
  const int wc  = tid>>1;               // W-stage: column owned
  const int wkh = (tid&1)*8;            // W-stage: k 8-group (0 or 8) within 16-k sub

  float acc[4][8];

  for (int seg=0; seg<NSEG; ++seg){
    #pragma unroll
    for (int i=0;i<4;i++)
      #pragma unroll
      for (int j=0;j<8;j++) acc[i][j]=0.f;

    const int wb_seg = (NSEG==6) ? (seg%3)*(ktot*HD) : wbase;
    const void* Wt   = (NSEG==6 && seg>=3) ? W2 : W;
    const bool wvec  = ((ktot&3)==0) && ((wb_seg&3)==0);
    const int wpath  = (wvec && dt==0) ? 0 : (wvec ? 1 : 2);

    for (int ch=0; ch<NCH; ++ch){
      int klim = ktot - ch*128; if (klim > 128) klim = 128;

      // ---- W prefetch registers + load/store helpers (8 values/thread) ----
      float4 wf0, wf1; ushort4 wh0, wh1; float wsc[8];
      auto wload = [&](int kkL){
        size_t wrow = (size_t)wb_seg + (size_t)wc*ktot + (size_t)ch*128 + kkL + wkh;
        if (wpath==0){
          const float* Wf = (const float*)Wt;
          if (kkL+wkh+8 <= klim){
            wf0 = *(const float4*)(Wf + wrow);
            wf1 = *(const float4*)(Wf + wrow + 4);
          } else {
            float t[8];
            #pragma unroll
            for (int j=0;j<8;j++) t[j] = (kkL+wkh+j < klim) ? Wf[wrow+j] : 0.f;
            wf0 = make_float4(t[0],t[1],t[2],t[3]);
            wf1 = make_float4(t[4],t[5],t[6],t[7]);
          }
        } else if (wpath==1){
          const u16* Wh = (const u16*)Wt;
          if (kkL+wkh+8 <= klim){
            wh0 = *(const ushort4*)(Wh + wrow);
            wh1 = *(const ushort4*)(Wh + wrow + 4);
          } else {
            u16 t[8];
            #pragma unroll
            for (int j=0;j<8;j++) t[j] = (kkL+wkh+j < klim) ? Wh[wrow+j] : (u16)0;
            wh0 = make_ushort4(t[0],t[1],t[2],t[3]);
            wh1 = make_ushort4(t[4],t[5],t[6],t[7]);
          }
        } else {
          #pragma unroll
          for (int j=0;j<8;j++) wsc[j] = (kkL+wkh+j < klim) ? rg(Wt, wrow+j, dt) : 0.f;
        }
      };
      auto wstore = [&](float* dstw){
        if (wpath==0){
          dstw[(wkh+0)*128+wc]=wf0.x; dstw[(wkh+1)*128+wc]=wf0.y;
          dstw[(wkh+2)*128+wc]=wf0.z; dstw[(wkh+3)*128+wc]=wf0.w;
          dstw[(wkh+4)*128+wc]=wf1.x; dstw[(wkh+5)*128+wc]=wf1.y;
          dstw[(wkh+6)*128+wc]=wf1.z; dstw[(wkh+7)*128+wc]=wf1.w;
        } else if (wpath==1){
          dstw[(wkh+0)*128+wc]=bf2f(wh0.x); dstw[(wkh+1)*128+wc]=bf2f(wh0.y);
          dstw[(wkh+2)*128+wc]=bf2f(wh0.z); dstw[(wkh+3)*128+wc]=bf2f(wh0.w);
          dstw[(wkh+4)*128+wc]=bf2f(wh1.x); dstw[(wkh+5)*128+wc]=bf2f(wh1.y);
          dstw[(wkh+6)*128+wc]=bf2f(wh1.z); dstw[(wkh+7)*128+wc]=bf2f(wh1.w);
        } else {
          #pragma unroll
          for (int j=0;j<8;j++) dstw[(wkh+j)*128+wc]=wsc[j];
        }
      };

      if (seg==0){
        // ---- stage 64x128 fp32 A-chunk ----
        if constexpr (AM==A_XF){
          for (int idx=tid; idx<8192; idx+=256){
            int r = idx>>7, lk = idx&127, k = ch*128 + lk;
            float v = 0.f;
            if (k < ktot) v = rg(a0v, (size_t)(rbase+r)*astride + k, dt);
            sa[r*132 + lk] = v;
          }
        }
        if constexpr (AM==A_F32){
          for (int idx=tid; idx<2048; idx+=256){
            int r = idx>>5, c4 = (idx&31)*4;
            float4 v = *(const float4*)((const float*)a0v + (size_t)(rbase+r)*astride + ch*128 + c4);
            *(float4*)&sa[r*132 + c4] = v;
          }
        }
        if constexpr (AM==A_B16){
          for (int idx=tid; idx<2048; idx+=256){
            int r = idx>>5, c4 = (idx&31)*4;
            ushort4 u = *(const ushort4*)((const u16*)a0v + (size_t)(rbase+r)*astride + ch*128 + c4);
            *(float4*)&sa[r*132 + c4] = make_float4(bf2f(u.x),bf2f(u.y),bf2f(u.z),bf2f(u.w));
          }
        }
        if constexpr (AM==A_C3){
          const float* src = (ch==0)?(const float*)a0v:(ch==1)?(const float*)a1v:(const float*)a2v;
          for (int idx=tid; idx<2048; idx+=256){
            int r = idx>>5, c4 = (idx&31)*4;
            float4 v = *(const float4*)(src + (size_t)(rbase+r)*HD + c4);
            *(float4*)&sa[r*132 + c4] = v;
          }
        }
        if constexpr (AM==A_BOOST){
          for (int idx=tid; idx<2048; idx+=256){
            int r = idx>>5, c4 = (idx&31)*4;
            float4 v = *(const float4*)((const float*)a0v + (size_t)(rbase+r)*HD + c4);
            v.x = fmaxf(v.x + s_ab[c4+0], 0.f);
            v.y = fmaxf(v.y + s_ab[c4+1], 0.f);
            v.z = fmaxf(v.z + s_ab[c4+2], 0.f);
            v.w = fmaxf(v.w + s_ab[c4+3], 0.f);
            *(float4*)&sa[r*132 + c4] = v;
          }
        }
        if constexpr (AM==A_EDGE){
          for (int idx=tid; idx<2048; idx+=256){
            int r = idx>>5, c4 = (idx&31)*4;
            float4 va = *(const float4*)((const float*)a0v + (size_t)s_d[r]*HD + c4);
            float4 vb = *(const float4*)((const float*)a1v + (size_t)s_pe[r]*HD + c4);
            *(float4*)&sa[r*132 + c4] = make_float4(va.x-vb.x, va.y-vb.y, va.z-vb.z, va.w-vb.w);
          }
        }
        if constexpr (AM==A_MSG){
          if (ch==0){
            for (int idx=tid; idx<2048; idx+=256){
              int r = idx>>5, c4 = (idx&31)*4;
              float4 v = *(const float4*)((const float*)a0v + (size_t)(rbase+r)*HD + c4);
              *(float4*)&sa[r*132 + c4] = v;
            }
          } else {
            for (int idx=tid; idx<8192; idx+=256){
              int r = idx>>7, cc = idx&127;
              int node = rbase+r;
              int b = ptr[node], en = ptr[node+1];
              float s=0.f, m=0.f;
              for (int i=b;i<en;++i){
                float t = ((const float*)a1v)[(size_t)cidx[i]*HD + cc];
                s += t; m = fmaxf(m,t);
              }
              sa[r*132 + cc] = s*m;   // m_sum * relu(segment_max); he>=0
            }
          }
        }
      }

      // ---- prologue: stage W sub-chunk 0 into wb[0] ----
      wload(0);
      wstore(&wb[0][0]);
      __syncthreads();   // sa (if staged) + wb[0] ready

      int cur = 0;
      for (int kk=0; kk<klim; kk+=16){
        const bool hn = (kk+16) < klim;
        if (hn) wload(kk+16);          // prefetch next W (latency hides under compute)

        // ---- compute: 16 k's from wb[cur]; zero-padded tails contribute 0 ----
        const float* wbc = wb[cur];
        for (int kc=0; kc<16; kc+=4){
          float4 aa[4];
          #pragma unroll
          for (int i=0;i<4;i++)
            aa[i] = *(const float4*)&sa[(ry4+i)*132 + kk + kc];
          #pragma unroll
          for (int t=0;t<4;t++){
            float4 b0 = *(const float4*)&wbc[(kc+t)*128 + cxx];
            float4 b1 = *(const float4*)&wbc[(kc+t)*128 + 64 + cxx];
            #pragma unroll
            for (int i=0;i<4;i++){
              float a = (t==0)?aa[i].x:(t==1)?aa[i].y:(t==2)?aa[i].z:aa[i].w;
              acc[i][0]+=a*b0.x; acc[i][1]+=a*b0.y; acc[i][2]+=a*b0.z; acc[i][3]+=a*b0.w;
              acc[i][4]+=a*b1.x; acc[i][5]+=a*b1.y; acc[i][6]+=a*b1.z; acc[i][7]+=a*b1.w;
            }
          }
        }
        if (hn) wstore(&wb[cur^1][0]); // write prefetched W to the other buffer
        __syncthreads();               // drains only ds_writes (cheap)
        cur ^= 1;
      }
    }

    if constexpr (EP==E_GI){
      // register epilogue: out = f2bf(acc + bias), packed ushort4 stores
      const void* bsrc = (NSEG==6 && seg>=3) ? bias2 : bias;
      const int   po   = (NSEG==6) ? (seg%3)*HD : prmoff;
      u16*        op   = (NSEG==6) ? (seg<3 ? outb : outb2) : outb;
      const int   oc   = (NSEG==6) ? (seg%3)*HD : ocoff;
      float b0[4], b1[4];
      #pragma unroll
      for (int j=0;j<4;j++){
        b0[j] = rg(bsrc, po + cxx + j, dt);
        b1[j] = rg(bsrc, po + 64 + cxx + j, dt);
      }
      #pragma unroll
      for (int i=0;i<4;i++){
        size_t gr = (size_t)(rbase + ry4 + i);
        ushort4 u0, u1;
        u0.x=f2bf(acc[i][0]+b0[0]); u0.y=f2bf(acc[i][1]+b0[1]);
        u0.z=f2bf(acc[i][2]+b0[2]); u0.w=f2bf(acc[i][3]+b0[3]);
        u1.x=f2bf(acc[i][4]+b1[0]); u1.y=f2bf(acc[i][5]+b1[1]);
        u1.z=f2bf(acc[i][6]+b1[2]); u1.w=f2bf(acc[i][7]+b1[3]);
        *(ushort4*)&op[gr*ostride + oc + cxx]      = u0;
        *(ushort4*)&op[gr*ostride + oc + 64 + cxx] = u1;
      }
    }
  }

  if constexpr (EP==E_GI) return;

  // dump C to LDS (so aliases sa; all sa reads completed at the barrier above)
  #pragma unroll
  for (int i=0;i<4;i++){
    *(float4*)&so[(ry4+i)*132 + cxx]      = make_float4(acc[i][0],acc[i][1],acc[i][2],acc[i][3]);
    *(float4*)&so[(ry4+i)*132 + 64 + cxx] = make_float4(acc[i][4],acc[i][5],acc[i][6],acc[i][7]);
  }
  __syncthreads();

  if constexpr (EP==E_HE0_RELU){
    for (int idx=tid; idx<8192; idx+=256){
      int r = idx>>7, c = idx&127;
      int e = s_e[r];
      float v = so[r*132+c] + rg(bias,prmoff+c,dt) + bf2f(he0b[(size_t)e*HD + c]);
      outf[(size_t)e*HD + c] = fmaxf(v,0.f);
    }
    return;
  }
  if constexpr (EP==E_LN_RELU || EP==E_LN || EP==E_LN_RELU_TANH || EP==E_RESID_LN || EP==E_LN_RELU_DUAL){
    float sm=0.f, sq=0.f;
    for (int i=0;i<32;i++){
      int c = qq*32+i;
      float v = so[row*132+c] + rg(bias,prmoff+c,dt);
      if constexpr (EP==E_RESID_LN) v = resid[(size_t)(rbase+row)*HD + c] + fmaxf(v,0.f);
      sm += v; sq += v*v;
    }
    sm += __shfl_xor(sm,1); sq += __shfl_xor(sq,1);
    sm += __shfl_xor(sm,2); sq += __shfl_xor(sq,2);
    if (qq==0){
      float mu = sm*(1.f/128.f);
      float var = sq*(1.f/128.f) - mu*mu;
      s_mu[row] = mu;
      s_rs[row] = rsqrtf(fmaxf(var,0.f)+1e-5f);
    }
    __syncthreads();
    for (int idx=tid; idx<8192; idx+=256){
      int r = idx>>7, c = idx&127;
      float v = so[r*132+c] + rg(bias,prmoff+c,dt);
      if constexpr (EP==E_RESID_LN) v = resid[(size_t)(rbase+r)*HD + c] + fmaxf(v,0.f);
      float y = (v - s_mu[r])*s_rs[r]*rg(gamma,prmoff+c,dt) + rg(beta,prmoff+c,dt);
      // E_RESID_LN: h_v = LN(h_v + relu(upd)) — no ReLU after LN.
      if constexpr (EP==E_LN_RELU || EP==E_LN_RELU_DUAL) y = fmaxf(y,0.f);
      if constexpr (EP==E_LN_RELU_TANH) y = tanhfast(fmaxf(y,0.f));
      if constexpr (EP==E_LN_RELU_DUAL){
        outf[(size_t)(rbase+r)*HD + c] = y;          // he (fp32)
        outb[(size_t)(rbase+r)*HD + c] = f2bf(y);    // he0 (bf16, single rounding)
      } else {
        outf[(size_t)(rbase+r)*HD + c] = y;
      }
    }
  }
}

// merged weight pre-convert: 4 (whh,bhh) pairs raw -> fp32 [49152|384] blocks
__global__ void k_cvt4(const void* w0,const void* b0,const void* w1,const void* b1,
                       const void* w2,const void* b2,const void* w3,const void* b3,
                       float* d0, float* d1, float* d2, float* d3, const int* dflag){
  int dt = *dflag;
  int p  = blockIdx.y;
  const void* wsrc = (p==0)?w0:(p==1)?w1:(p==2)?w2:w3;
  const void* bsrc = (p==0)?b0:(p==1)?b1:(p==2)?b2:b3;
  float* dst       = (p==0)?d0:(p==1)?d1:(p==2)?d2:d3;
  int i = blockIdx.x*256 + threadIdx.x;
  if (i < 49152)      dst[i] = rg(wsrc, i, dt);
  else if (i < 49536) dst[i] = rg(bsrc, i-49152, dt);
}

// BiGRU, W-in-registers: one block = 2 graphs x one dir (grid 256x2 = 512
// blocks). launch_bounds(384,1): measured config giving VGPR~128, no spill
// — do NOT raise min-waves (r3: (384,3) -> VGPR 84 -> wreg spilled, 2.4x
// slower). Thread owns gate-row d=tid; whh row (32 float4) in registers
// all 64 steps. gi for step t+1 prefetched during step t's GEMV (full-step
// latency cover). sgh stride 3 (gcd(3,32)=1): conflict-free cell reads.
// fp32 FMA, same k-order -> numerics preserved.
__launch_bounds__(384,1)
__global__ void k_gru(
  const u16* gi_f, const u16* gi_b,
  const float* wcf, const float* wcb,
  u16* out_seq, float* zbuf, int write_seq)
{
  const int dir = blockIdx.y;
  const int g0  = blockIdx.x * 2;
  const u16* gi  = dir ? gi_b : gi_f;
  const float* whh = dir ? wcb : wcf;
  const float* bh  = whh + 49152;

  __shared__ float sgh[384*3];               // [row d][graph g], stride 3
  __shared__ __align__(16) float sh[2*128];  // h state [g][d]

  const int tid = threadIdx.x;   // 0..383, owns gate-row d=tid

  // load W row into registers (once)
  float4 wreg[32];
  {
    const float4* wrow = (const float4*)(whh + (size_t)tid*128);
    #pragma unroll
    for (int i=0;i<32;i++) wreg[i] = wrow[i];
  }
  const float bhd = bh[tid];

  const int gA = tid>>7, dA = tid&127;   // cell item (tid<256)

  for (int i=tid;i<256;i+=384) sh[i]=0.f;
  __syncthreads();

  // preload gi for step 0
  u16 aR=0, aZ=0, aN=0;
  if (tid < 256){
    const int t0 = dir ? 63 : 0;
    const u16* gp = gi + (size_t)((g0+gA)*TSEQ + t0)*384;
    aR = gp[dA]; aZ = gp[128+dA]; aN = gp[256+dA];
  }

  for (int step=0; step<64; ++step){
    const int t = dir ? (63-step) : step;

    // ---- issue NEXT step's gi loads (hidden under GEMV + barriers + cell) ----
    u16 nR=0, nZ=0, nN=0;
    if (step+1 < 64 && tid < 256){
      const int tn = dir ? (62-step) : (step+1);
      const u16* gp = gi + (size_t)((g0+gA)*TSEQ + tn)*384;
      nR = gp[dA]; nZ = gp[128+dA]; nN = gp[256+dA];
    }

    // ---- GEMV: gh[d][g] = whh[d]·h[g] + bh[d], W from registers ----
    float a0=0.f, a1=0.f;
    #pragma unroll
    for (int k4=0; k4<32; k4++){
      float4 w  = wreg[k4];
      float4 h0 = *(const float4*)&sh[0*128 + k4*4];
      float4 h1 = *(const float4*)&sh[1*128 + k4*4];
      a0 += h0.x*w.x + h0.y*w.y + h0.z*w.z + h0.w*w.w;
      a1 += h1.x*w.x + h1.y*w.y + h1.z*w.z + h1.w*w.w;
    }
    sgh[tid*3+0] = a0 + bhd;
    sgh[tid*3+1] = a1 + bhd;
    __syncthreads();

    // ---- cell update ----
    if (tid < 256){
      float r = sigm(bf2f(aR) + sgh[dA*3+gA]);
      float z = sigm(bf2f(aZ) + sgh[(128+dA)*3+gA]);
      float n = tanhfast(bf2f(aN) + r*sgh[(256+dA)*3+gA]);
      float h = (1.f-z)*n + z*sh[gA*128+dA];
      sh[gA*128+dA] = h;
      if (write_seq){
        float hc = fminf(fmaxf(h,-10.f),10.f);
        out_seq[(size_t)((g0+gA)*TSEQ + t)*256 + dir*HD + dA] = f2bf(hc);
      }
    }
    __syncthreads();

    aR = nR; aZ = nZ; aN = nN;
  }

  if (!write_seq){
    for (int i=tid;i<256;i+=384){
      int g=i>>7, d=i&127;
      zbuf[(size_t)(g0+g)*256 + dir*HD + d] = fminf(fmaxf(sh[g*128+d],-10.f),10.f);
    }
  }
}

__launch_bounds__(64)
__global__ void k_gather(const float* he, const int* ptr, const int* cidx, float* out){
  int n = blockIdx.x;
  int c = threadIdx.x;
  int b = ptr[n], e = ptr[n+1];
  float s0=0.f,s1=0.f;
  for (int i=b;i<e;++i){
    int eid = cidx[i];
    float2 v = *(const float2*)(he + (size_t)eid*HD + c*2);
    s0+=v.x; s1+=v.y;
  }
  out[(size_t)n*HD + c*2]   = s0;
  out[(size_t)n*HD + c*2+1] = s1;
}

__global__ void k_count(const int* dst, int* cnt){
  int e = blockIdx.x*256+threadIdx.x;
  if (e<NE) atomicAdd(&cnt[dst[e]],1);
}

__launch_bounds__(1024)
__global__ void k_scan(const int* cnt, int* ptr){
  __shared__ int s[1024];
  int tid=threadIdx.x;
  int loc[32]; int tot=0;
  int base = tid*32;
  #pragma unroll
  for (int i=0;i<32;i++){ loc[i]=tot; tot += cnt[base+i]; }
  s[tid]=tot; __syncthreads();
  for (int off=1; off<1024; off<<=1){
    int v = (tid>=off)? s[tid-off] : 0;
    __syncthreads();
    s[tid] += v;
    __syncthreads();
  }
  int ex = s[tid] - tot;
  for (int i=0;i<32;i++) ptr[base+i] = ex + loc[i];
  if (tid==1023) ptr[NN] = ex + tot;
}

__global__ void k_fill(const int* dst, const int* ptr, int* cur, int* cidx){
  int e = blockIdx.x*256+threadIdx.x;
  if (e<NE){
    int d = dst[e];
    int p = ptr[d] + atomicAdd(&cur[d],1);
    cidx[p] = e;
  }
}

// runtime input-dtype detector (fp32 low-halfword exponents ~uniform; bf16 ~always in-range)
__global__ void k_detect(const u16* x, int* flag){
  __shared__ int cnt;
  if (threadIdx.x==0) cnt=0;
  __syncthreads();
  u16 u = x[threadIdx.x*2];
  int e = (u>>7)&0xff;
  if (e>=100 && e<=135) atomicAdd(&cnt,1);
  __syncthreads();
  if (threadIdx.x==0) *flag = (cnt>=128) ? 1 : 0;
}

__launch_bounds__(256)
__global__ void k_bnstats(const float* z, const void* bng, const void* bnb, float* st, const int* dflag){
  int dt = *dflag;
  int c = threadIdx.x;
  float sm=0.f, sq=0.f;
  for (int g=0; g<NG; ++g){ float v = z[(size_t)g*256+c]; sm+=v; sq+=v*v; }
  float mu = sm*(1.f/(float)NG);
  float var = sq*(1.f/(float)NG) - mu*mu;
  float rs = rsqrtf(fmaxf(var,0.f)+1e-5f);
  float sc = rs*rg(bng,c,dt);
  st[c] = sc;
  st[256+c] = rg(bnb,c,dt) - mu*sc;
}

// OUTPUT fp32 (confirmed by r8: finite ref-scale error under fp32 writes)
__global__ void k_pred(const float* z, const float* st, const void* pw, const void* pb, float* out, const int* dflag){
  int dt = *dflag;
  int g = blockIdx.x*256+threadIdx.x;
  if (g>=NG) return;
  float acc = rg(pb,0,dt);
  for (int c=0;c<256;c++) acc += (z[(size_t)g*256+c]*st[c] + st[256+c])*rg(pw,c,dt);
  out[g]=acc;
}

extern "C" void kernel_launch(void* const* d_in, const int* in_sizes, int n_in,
                              void* d_out, int out_size, void* d_ws, size_t ws_size,
                              hipStream_t stream)
{
  const void* X    =d_in[0];
  const void* EA   =d_in[1];
  const void* NW   =d_in[2];
  const void* NB   =d_in[3];
  const void* NGa  =d_in[4];
  const void* NBt  =d_in[5];
  const void* EW   =d_in[6];
  const void* EB   =d_in[7];
  const void* EGa  =d_in[8];
  const void* EBt  =d_in[9];
  const void* LW   =d_in[10];
  const void* LB   =d_in[11];
  const void* LGa  =d_in[12];
  const void* LBt  =d_in[13];
  const void* NUW  =d_in[14];
  const void* NUB  =d_in[15];
  const void* NNG  =d_in[16];
  const void* NNB  =d_in[17];
  const void* EUW  =d_in[18];
  const void* EUB  =d_in[19];
  const void* BOOST=d_in[20];
  const void* BIHW_F=d_in[21];
  const void* BHHW_F=d_in[22];
  const void* BIHB_F=d_in[23];
  const void* BHHB_F=d_in[24];
  const void* BIHW_B=d_in[25];
  const void* BHHW_B=d_in[26];
  const void* BIHB_B=d_in[27];
  const void* BHHB_B=d_in[28];
  const void* PW   =d_in[29];
  const void* PB   =d_in[30];
  const void* PG   =d_in[31];
  const void* PBt  =d_in[32];
  const void* FW   =d_in[33];
  const void* FB   =d_in[34];
  const void* FG   =d_in[35];
  const void* FBt  =d_in[36];
  const void* RIHW_F=d_in[37];
  const void* RHHW_F=d_in[38];
  const void* RIHB_F=d_in[39];
  const void* RHHB_F=d_in[40];
  const void* RIHW_B=d_in[41];
  const void* RHHW_B=d_in[42];
  const void* RIHB_B=d_in[43];
  const void* RHHB_B=d_in[44];
  const void* BNG  =d_in[45];
  const void* BNB  =d_in[46];
  const void* PRW  =d_in[47];
  const void* PRB  =d_in[48];
  const int* EIDX =(const int*)d_in[49];
  const int* DST  = EIDX + NE;

  // ---- Workspace (same map as before; fp32 GRU weights in 2MB..3MB gap) ----
  char* ws=(char*)d_ws;
  const size_t MB = 1048576;
  int*   csrp =(int*)  (ws + 0);
  int*   csrc =(int*)  (ws + 135168);
  int*   csri =(int*)  (ws + 266240);
  float* zbuf =(float*)(ws + 790528);
  float* stats=(float*)(ws + 1314816);
  int*   dflag=(int*)  (ws + 1316864);
  float* wbgf =(float*)(ws + 2*MB);          // [49152 whh | 384 bhh] fp32, boost fwd
  float* wbgb = wbgf + 49536;                // boost bwd
  float* wrgf = wbgb + 49536;                // readout fwd
  float* wrgb = wrgf + 49536;                // readout bwd
  float* hv   =(float*)(ws + 6*MB);
  u16*   he0  =(u16*)  (ws + 22*MB);
  float* he   =(float*)(ws + 54*MB);
  float* mfin =(float*)(ws + 22*MB);
  u16*   gif  =(u16*)  (ws + 54*MB);
  u16*   gib  =(u16*)  (ws + 78*MB);
  u16*   oseq =(u16*)  (ws + 6*MB);
  float* hv2  =(float*)(ws + 38*MB);
  float* hx2  =(float*)(ws + 6*MB);
  float* fout =(float*)(ws + 54*MB);
  u16*   gif_r=(u16*)  (ws + 70*MB);
  u16*   gib_r=(u16*)  (ws + 94*MB);

  k_detect<<<dim3(1),dim3(256),0,stream>>>((const u16*)X, dflag);

  // pre-convert recurrent GRU weights to fp32 (one merged launch)
  k_cvt4<<<dim3(194,4),dim3(256),0,stream>>>(
      BHHW_F,BHHB_F, BHHW_B,BHHB_B, RHHW_F,RHHB_F, RHHW_B,RHHB_B,
      wbgf, wbgb, wrgf, wrgb, dflag);

  // CSR over dst
  hipMemsetAsync(csrc, 0, 131072, stream);
  k_count<<<dim3(512),dim3(256),0,stream>>>(DST, csrc);
  k_scan<<<dim3(1),dim3(1024),0,stream>>>(csrc, csrp);
  hipMemsetAsync(csrc, 0, 131072, stream);
  k_fill<<<dim3(512),dim3(256),0,stream>>>(DST, csrp, csrc, csri);

  // init embeddings
  k_dense<A_XF,E_LN_RELU,2,1><<<dim3(512),dim3(256),0,stream>>>(X,nullptr,nullptr,
      nullptr,nullptr,nullptr,nullptr, NW,nullptr,0, NB,nullptr,NGa,NBt,0, nullptr,nullptr,
      hv,nullptr,nullptr, dflag, 133,133,HD,0);
  k_dense<A_XF,E_LN_RELU_DUAL,1,1><<<dim3(2048),dim3(256),0,stream>>>(EA,nullptr,nullptr,
      nullptr,nullptr,nullptr,nullptr, EW,nullptr,0, EB,nullptr,EGa,EBt,0, nullptr,nullptr,
      he,he0,nullptr, dflag, 14,14,HD,0);

  // message passing
  for (int s=0;s<5;s++){
    k_dense<A_MSG,E_RESID_LN,2,1><<<dim3(512),dim3(256),0,stream>>>(hv,he,nullptr,
        nullptr,csrp,csri,nullptr, NUW,nullptr,s*32768, NUB,nullptr,NNG,NNB,s*128,
        hv,nullptr, hv,nullptr,nullptr, dflag, 256,HD,HD,0);
    k_dense<A_EDGE,E_HE0_RELU,1,1><<<dim3(2048),dim3(256),0,stream>>>(hv,he,nullptr,
        DST,nullptr,nullptr,nullptr, EUW,nullptr,s*16384, EUB,nullptr,nullptr,nullptr,s*128,
        nullptr,he0, he,nullptr,nullptr, dflag, 128,HD,HD,0);
  }
  k_gather<<<dim3(NN),dim3(64),0,stream>>>(he, csrp, csri, mfin);

  // boost GRU input-side gates: ONE launch, 6 weight segments (F0-2,B0-2)
  k_dense<A_BOOST,E_GI,1,6><<<dim3(512),dim3(256),0,stream>>>(hv,nullptr,nullptr,
      nullptr,nullptr,nullptr,BOOST, BIHW_F,BIHW_B,0, BIHB_F,BIHB_B,nullptr,nullptr,0,
      nullptr,nullptr, nullptr,gif,gib, dflag, 128,HD,384,0);
  k_gru<<<dim3(256,2),dim3(384),0,stream>>>(gif, gib, wbgf, wbgb, oseq, zbuf, 1);

  // proj + recompute hx + final merge
  k_dense<A_B16,E_LN_RELU_TANH,2,1><<<dim3(512),dim3(256),0,stream>>>(oseq,nullptr,nullptr,
      nullptr,nullptr,nullptr,nullptr, PW,nullptr,0, PB,nullptr,PG,PBt,0, nullptr,nullptr,
      hv2,nullptr,nullptr, dflag, 256,256,HD,0);
  k_dense<A_XF,E_LN,2,1><<<dim3(512),dim3(256),0,stream>>>(X,nullptr,nullptr,
      nullptr,nullptr,nullptr,nullptr, LW,nullptr,0, LB,nullptr,LGa,LBt,0, nullptr,nullptr,
      hx2,nullptr,nullptr, dflag, 133,133,HD,0);
  k_dense<A_C3,E_LN_RELU,3,1><<<dim3(512),dim3(256),0,stream>>>(hv2,mfin,hx2,
      nullptr,nullptr,nullptr,nullptr, FW,nullptr,0, FB,nullptr,FG,FBt,0, nullptr,nullptr,
      fout,nullptr,nullptr, dflag, 384,HD,HD,0);

  // readout GRU gates (ONE launch, 6 segments) + GRU
  k_dense<A_F32,E_GI,1,6><<<dim3(512),dim3(256),0,stream>>>(fout,nullptr,nullptr,
      nullptr,nullptr,nullptr,nullptr, RIHW_F,RIHW_B,0, RIHB_F,RIHB_B,nullptr,nullptr,0,
      nullptr,nullptr, nullptr,gif_r,gib_r, dflag, 128,HD,384,0);
  k_gru<<<dim3(256,2),dim3(384),0,stream>>>(gif_r, gib_r, wrgf, wrgb, oseq, zbuf, 0);

  // BN + prediction
  k_bnstats<<<dim3(1),dim3(256),0,stream>>>(zbuf, BNG, BNB, stats, dflag);
  k_pred<<<dim3(2),dim3(256),0,stream>>>(zbuf, stats, PRW, PRB, (float*)d_out, dflag);

  (void)in_sizes; (void)n_in; (void)out_size; (void)ws_size;
}

// Round 6
// 3099.877 us; speedup vs baseline: 1.2997x; 1.2997x over previous
//
#include <hip/hip_runtime.h>
#include <hip/hip_bf16.h>

typedef unsigned short u16;
typedef unsigned int   u32;

#define NN    32768
#define NG    512
#define TSEQ  64
#define NE    131072
#define NP    65536
#define HD    128

__device__ __forceinline__ float bf2f(u16 v){ u32 u=((u32)v)<<16; float f; __builtin_memcpy(&f,&u,4); return f; }
__device__ __forceinline__ float u2f(u32 u){ float f; __builtin_memcpy(&f,&u,4); return f; }
__device__ __forceinline__ u16 f2bf(float f){ u32 u; __builtin_memcpy(&u,&f,4); u32 r=u+0x7fffu+((u>>16)&1u); return (u16)(r>>16); }
__device__ __forceinline__ float sigm(float x){ return 1.f/(1.f+__expf(-x)); }
__device__ __forceinline__ float tanhfast(float x){ return 1.f-2.f/(1.f+__expf(2.f*x)); }
// raw-input read: dt=1 -> bf16, dt=0 -> fp32
__device__ __forceinline__ float rg(const void* p, size_t i, int dt){
  return dt ? bf2f(((const u16*)p)[i]) : ((const float*)p)[i];
}

// A-source modes / epilogues
enum { A_XF, A_F32, A_B16, A_MSG, A_C3, A_EDGE, A_BOOST };
enum { E_LN_RELU, E_LN, E_LN_RELU_TANH, E_RESID_LN, E_HE0_RELU, E_GI, E_LN_RELU_DUAL };

// Register-tiled fp32 GEMM core (4x8 micro-tile). A staged once per chunk
// (vectorized); W staged in 32-k sub-chunks (16 KB LDS, single buffer).
// Pipelining (wfull path, klim==128 && wvec): next sub-chunk's W loaded as
// RAW uint4 bits during current sub-chunk's compute (no conversion at load
// -> loads issue and retire under ~2000cy of FMAs); convert + ds_write
// between the two barriers. One raw payload (4x uint4) serves both dtypes
// -> no r5-style register-union blow-up. Small-k launches (133/14) use the
// synchronous scalar path. NSEG>1 (E_GI): loop weight segments over the
// same staged A, gate outputs written from registers as ushort4.
// fp32 FMA in ascending k-order (numerics preserved).
template<int AM, int EP, int NCH, int NSEG>
__launch_bounds__(256)
__global__ void k_dense(
    const void* a0v, const void* a1v, const void* a2v,
    const int* dsti, const int* ptr, const int* cidx, const void* abias,
    const void* W, const void* W2, int wbase,
    const void* bias, const void* bias2, const void* gamma, const void* beta, int prmoff,
    const float* resid, const u16* he0b,
    float* outf, u16* outb, u16* outb2, const int* dflag,
    int ktot, int astride, int ostride, int ocoff)
{
  __shared__ __align__(16) float sa[64*132];   // A tile (stride 132: rows 16B-aligned)
  __shared__ __align__(16) float wb[32*128];   // W sub-chunk [k][c], 16 KB
  float* so = sa;                 // reused for C after compute (NSEG==1 paths)
  __shared__ float s_mu[64], s_rs[64];
  __shared__ int s_e[64], s_pe[64], s_d[64];
  __shared__ float s_ab[128];

  const int dt  = *dflag;
  const int tid = threadIdx.x;
  const int bx  = blockIdx.x;

  if constexpr (AM==A_EDGE){
    if (tid < 64){
      int eb = bx*32;
      int e = (tid<32) ? (eb+tid) : (NP + eb + tid - 32);
      s_e[tid]  = e;
      s_pe[tid] = (tid<32) ? (e+NP) : (e-NP);
      s_d[tid]  = dsti[e];
    }
    __syncthreads();
  }
  if constexpr (AM==A_BOOST){
    if (tid < 128) s_ab[tid] = rg(abias, tid, dt);
    __syncthreads();
  }
  const int rbase = (AM==A_EDGE) ? 0 : bx*64;

  const int row = tid>>2, qq = tid&3;   // epilogue mapping
  const int ry4 = (tid>>4)*4;           // compute: rows ry4..ry4+3
  const int cxx = (tid&15)*4;           // compute: cols cxx..+3 and 64+cxx..+3
  const int wc  = tid>>1;               // W-stage: column owned
  const int wkh = (tid&1)*16;           // W-stage: k-half (0/16) within 32-k sub

  float acc[4][8];

  // 4x8 micro-tile over 32 k's from wb, A from sa at k-offset kk
  auto mtile = [&](int kk){
    for (int kc=0; kc<32; kc+=4){
      float4 aa[4];
      #pragma unroll
      for (int i=0;i<4;i++)
        aa[i] = *(const float4*)&sa[(ry4+i)*132 + kk + kc];
      #pragma unroll
      for (int t=0;t<4;t++){
        float4 b0 = *(const float4*)&wb[(kc+t)*128 + cxx];
        float4 b1 = *(const float4*)&wb[(kc+t)*128 + 64 + cxx];
        #pragma unroll
        for (int i=0;i<4;i++){
          float a = (t==0)?aa[i].x:(t==1)?aa[i].y:(t==2)?aa[i].z:aa[i].w;
          acc[i][0]+=a*b0.x; acc[i][1]+=a*b0.y; acc[i][2]+=a*b0.z; acc[i][3]+=a*b0.w;
          acc[i][4]+=a*b1.x; acc[i][5]+=a*b1.y; acc[i][6]+=a*b1.z; acc[i][7]+=a*b1.w;
        }
      }
    }
  };

  for (int seg=0; seg<NSEG; ++seg){
    #pragma unroll
    for (int i=0;i<4;i++)
      #pragma unroll
      for (int j=0;j<8;j++) acc[i][j]=0.f;

    const int wb_seg = (NSEG==6) ? (seg%3)*(ktot*HD) : wbase;
    const void* Wt   = (NSEG==6 && seg>=3) ? W2 : W;
    const bool wvec  = ((ktot&3)==0) && ((wb_seg&3)==0);

    for (int ch=0; ch<NCH; ++ch){
      int klim = ktot - ch*128; if (klim > 128) klim = 128;
      const bool wfull = wvec && (klim==128);

      if (seg==0){
        // ---- stage 64x128 fp32 A-chunk ----
        if constexpr (AM==A_XF){
          for (int idx=tid; idx<8192; idx+=256){
            int r = idx>>7, lk = idx&127, k = ch*128 + lk;
            float v = 0.f;
            if (k < ktot) v = rg(a0v, (size_t)(rbase+r)*astride + k, dt);
            sa[r*132 + lk] = v;
          }
        }
        if constexpr (AM==A_F32){
          for (int idx=tid; idx<2048; idx+=256){
            int r = idx>>5, c4 = (idx&31)*4;
            float4 v = *(const float4*)((const float*)a0v + (size_t)(rbase+r)*astride + ch*128 + c4);
            *(float4*)&sa[r*132 + c4] = v;
          }
        }
        if constexpr (AM==A_B16){
          for (int idx=tid; idx<2048; idx+=256){
            int r = idx>>5, c4 = (idx&31)*4;
            ushort4 u = *(const ushort4*)((const u16*)a0v + (size_t)(rbase+r)*astride + ch*128 + c4);
            *(float4*)&sa[r*132 + c4] = make_float4(bf2f(u.x),bf2f(u.y),bf2f(u.z),bf2f(u.w));
          }
        }
        if constexpr (AM==A_C3){
          const float* src = (ch==0)?(const float*)a0v:(ch==1)?(const float*)a1v:(const float*)a2v;
          for (int idx=tid; idx<2048; idx+=256){
            int r = idx>>5, c4 = (idx&31)*4;
            float4 v = *(const float4*)(src + (size_t)(rbase+r)*HD + c4);
            *(float4*)&sa[r*132 + c4] = v;
          }
        }
        if constexpr (AM==A_BOOST){
          for (int idx=tid; idx<2048; idx+=256){
            int r = idx>>5, c4 = (idx&31)*4;
            float4 v = *(const float4*)((const float*)a0v + (size_t)(rbase+r)*HD + c4);
            v.x = fmaxf(v.x + s_ab[c4+0], 0.f);
            v.y = fmaxf(v.y + s_ab[c4+1], 0.f);
            v.z = fmaxf(v.z + s_ab[c4+2], 0.f);
            v.w = fmaxf(v.w + s_ab[c4+3], 0.f);
            *(float4*)&sa[r*132 + c4] = v;
          }
        }
        if constexpr (AM==A_EDGE){
          for (int idx=tid; idx<2048; idx+=256){
            int r = idx>>5, c4 = (idx&31)*4;
            float4 va = *(const float4*)((const float*)a0v + (size_t)s_d[r]*HD + c4);
            float4 vb = *(const float4*)((const float*)a1v + (size_t)s_pe[r]*HD + c4);
            *(float4*)&sa[r*132 + c4] = make_float4(va.x-vb.x, va.y-vb.y, va.z-vb.z, va.w-vb.w);
          }
        }
        if constexpr (AM==A_MSG){
          if (ch==0){
            for (int idx=tid; idx<2048; idx+=256){
              int r = idx>>5, c4 = (idx&31)*4;
              float4 v = *(const float4*)((const float*)a0v + (size_t)(rbase+r)*HD + c4);
              *(float4*)&sa[r*132 + c4] = v;
            }
          } else {
            for (int idx=tid; idx<8192; idx+=256){
              int r = idx>>7, cc = idx&127;
              int node = rbase+r;
              int b = ptr[node], en = ptr[node+1];
              float s=0.f, m=0.f;
              for (int i=b;i<en;++i){
                float t = ((const float*)a1v)[(size_t)cidx[i]*HD + cc];
                s += t; m = fmaxf(m,t);
              }
              sa[r*132 + cc] = s*m;   // m_sum * relu(segment_max); he>=0
            }
          }
        }
      }

      if (wfull){
        // ---- pipelined path: raw-bit W prefetch under compute ----
        uint4 wr0, wr1, wr2, wr3;   // dt==0: 16 f32; dt==1: wr0,wr1 = 16 bf16
        const size_t ebase = (size_t)wb_seg + (size_t)wc*ktot + (size_t)ch*128 + wkh;
        // prologue load (kk=0)
        if (dt==0){
          const uint4* p = (const uint4*)((const float*)Wt + ebase);
          wr0=p[0]; wr1=p[1]; wr2=p[2]; wr3=p[3];
        } else {
          const uint4* p = (const uint4*)((const u16*)Wt + ebase);
          wr0=p[0]; wr1=p[1];
        }
        for (int s4=0; s4<4; ++s4){
          const int kk = s4*32;
          __syncthreads();   // wb writable (prev compute done); s4==0: sa also ready
          if (dt==0){
            const u32 bb[16]={wr0.x,wr0.y,wr0.z,wr0.w, wr1.x,wr1.y,wr1.z,wr1.w,
                              wr2.x,wr2.y,wr2.z,wr2.w, wr3.x,wr3.y,wr3.z,wr3.w};
            #pragma unroll
            for (int j=0;j<16;j++) wb[(wkh+j)*128+wc] = u2f(bb[j]);
          } else {
            const u32 hb[8]={wr0.x,wr0.y,wr0.z,wr0.w, wr1.x,wr1.y,wr1.z,wr1.w};
            #pragma unroll
            for (int j=0;j<8;j++){
              u32 w = hb[j];
              wb[(wkh+2*j  )*128+wc] = u2f(w<<16);
              wb[(wkh+2*j+1)*128+wc] = u2f(w & 0xffff0000u);
            }
          }
          __syncthreads();   // wb ready
          if (s4<3){
            const size_t eo = ebase + (size_t)(kk+32);
            if (dt==0){
              const uint4* p = (const uint4*)((const float*)Wt + eo);
              wr0=p[0]; wr1=p[1]; wr2=p[2]; wr3=p[3];
            } else {
              const uint4* p = (const uint4*)((const u16*)Wt + eo);
              wr0=p[0]; wr1=p[1];
            }
          }
          mtile(kk);         // ~2000cy of FMAs hide the prefetch above
        }
        __syncthreads();     // protect sa/wb before restage or epilogue
      } else {
        // ---- synchronous scalar path (ktot=133/14 launches only) ----
        for (int kk=0; kk<klim; kk+=32){
          {
            size_t wrow = (size_t)wb_seg + (size_t)wc*ktot + (size_t)ch*128 + kk;
            for (int j=0;j<16;j++){
              int kq = wkh + j;
              wb[kq*128+wc] = (kk+kq < klim) ? rg(Wt, wrow+kq, dt) : 0.f;
            }
          }
          __syncthreads();
          mtile(kk);
          __syncthreads();
        }
      }
    }

    if constexpr (EP==E_GI){
      // register epilogue: out = f2bf(acc + bias), packed ushort4 stores
      const void* bsrc = (NSEG==6 && seg>=3) ? bias2 : bias;
      const int   po   = (NSEG==6) ? (seg%3)*HD : prmoff;
      u16*        op   = (NSEG==6) ? (seg<3 ? outb : outb2) : outb;
      const int   oc   = (NSEG==6) ? (seg%3)*HD : ocoff;
      float b0[4], b1[4];
      #pragma unroll
      for (int j=0;j<4;j++){
        b0[j] = rg(bsrc, po + cxx + j, dt);
        b1[j] = rg(bsrc, po + 64 + cxx + j, dt);
      }
      #pragma unroll
      for (int i=0;i<4;i++){
        size_t gr = (size_t)(rbase + ry4 + i);
        ushort4 u0, u1;
        u0.x=f2bf(acc[i][0]+b0[0]); u0.y=f2bf(acc[i][1]+b0[1]);
        u0.z=f2bf(acc[i][2]+b0[2]); u0.w=f2bf(acc[i][3]+b0[3]);
        u1.x=f2bf(acc[i][4]+b1[0]); u1.y=f2bf(acc[i][5]+b1[1]);
        u1.z=f2bf(acc[i][6]+b1[2]); u1.w=f2bf(acc[i][7]+b1[3]);
        *(ushort4*)&op[gr*ostride + oc + cxx]      = u0;
        *(ushort4*)&op[gr*ostride + oc + 64 + cxx] = u1;
      }
    }
  }

  if constexpr (EP==E_GI) return;

  // dump C to LDS (so aliases sa; all sa reads completed at the barrier above)
  #pragma unroll
  for (int i=0;i<4;i++){
    *(float4*)&so[(ry4+i)*132 + cxx]      = make_float4(acc[i][0],acc[i][1],acc[i][2],acc[i][3]);
    *(float4*)&so[(ry4+i)*132 + 64 + cxx] = make_float4(acc[i][4],acc[i][5],acc[i][6],acc[i][7]);
  }
  __syncthreads();

  if constexpr (EP==E_HE0_RELU){
    for (int idx=tid; idx<8192; idx+=256){
      int r = idx>>7, c = idx&127;
      int e = s_e[r];
      float v = so[r*132+c] + rg(bias,prmoff+c,dt) + bf2f(he0b[(size_t)e*HD + c]);
      outf[(size_t)e*HD + c] = fmaxf(v,0.f);
    }
    return;
  }
  if constexpr (EP==E_LN_RELU || EP==E_LN || EP==E_LN_RELU_TANH || EP==E_RESID_LN || EP==E_LN_RELU_DUAL){
    float sm=0.f, sq=0.f;
    for (int i=0;i<32;i++){
      int c = qq*32+i;
      float v = so[row*132+c] + rg(bias,prmoff+c,dt);
      if constexpr (EP==E_RESID_LN) v = resid[(size_t)(rbase+row)*HD + c] + fmaxf(v,0.f);
      sm += v; sq += v*v;
    }
    sm += __shfl_xor(sm,1); sq += __shfl_xor(sq,1);
    sm += __shfl_xor(sm,2); sq += __shfl_xor(sq,2);
    if (qq==0){
      float mu = sm*(1.f/128.f);
      float var = sq*(1.f/128.f) - mu*mu;
      s_mu[row] = mu;
      s_rs[row] = rsqrtf(fmaxf(var,0.f)+1e-5f);
    }
    __syncthreads();
    for (int idx=tid; idx<8192; idx+=256){
      int r = idx>>7, c = idx&127;
      float v = so[r*132+c] + rg(bias,prmoff+c,dt);
      if constexpr (EP==E_RESID_LN) v = resid[(size_t)(rbase+r)*HD + c] + fmaxf(v,0.f);
      float y = (v - s_mu[r])*s_rs[r]*rg(gamma,prmoff+c,dt) + rg(beta,prmoff+c,dt);
      // E_RESID_LN: h_v = LN(h_v + relu(upd)) — no ReLU after LN.
      if constexpr (EP==E_LN_RELU || EP==E_LN_RELU_DUAL) y = fmaxf(y,0.f);
      if constexpr (EP==E_LN_RELU_TANH) y = tanhfast(fmaxf(y,0.f));
      if constexpr (EP==E_LN_RELU_DUAL){
        outf[(size_t)(rbase+r)*HD + c] = y;          // he (fp32)
        outb[(size_t)(rbase+r)*HD + c] = f2bf(y);    // he0 (bf16, single rounding)
      } else {
        outf[(size_t)(rbase+r)*HD + c] = y;
      }
    }
  }
}

// merged weight pre-convert: 4 (whh,bhh) pairs raw -> fp32 [49152|384] blocks
__global__ void k_cvt4(const void* w0,const void* b0,const void* w1,const void* b1,
                       const void* w2,const void* b2,const void* w3,const void* b3,
                       float* d0, float* d1, float* d2, float* d3, const int* dflag){
  int dt = *dflag;
  int p  = blockIdx.y;
  const void* wsrc = (p==0)?w0:(p==1)?w1:(p==2)?w2:w3;
  const void* bsrc = (p==0)?b0:(p==1)?b1:(p==2)?b2:b3;
  float* dst       = (p==0)?d0:(p==1)?d1:(p==2)?d2:d3;
  int i = blockIdx.x*256 + threadIdx.x;
  if (i < 49152)      dst[i] = rg(wsrc, i, dt);
  else if (i < 49536) dst[i] = rg(bsrc, i-49152, dt);
}

// BiGRU, W-in-registers (EXACT r1/r2-measured 319µs config — do not touch):
// one block = 4 graphs x one dir (grid 128x2); 384 threads; thread owns
// gate-row d=tid and keeps its whh row (32 float4) in registers for all 64
// steps. launch_bounds(384,1): VGPR 128, no spill (r3: min-waves=3 -> VGPR
// 84 -> spill, 2.4x slower; r5: next-step gi prefetch -> spill, 1.5x
// slower). Same-step gi prefetch only. sgh stride 5 (gcd(5,32)=1):
// conflict-free cell reads. fp32 FMA, same k-order -> numerics preserved.
__launch_bounds__(384,1)
__global__ void k_gru(
  const u16* gi_f, const u16* gi_b,
  const float* wcf, const float* wcb,
  u16* out_seq, float* zbuf, int write_seq)
{
  const int dir = blockIdx.y;
  const int g0  = blockIdx.x * 4;
  const u16* gi  = dir ? gi_b : gi_f;
  const float* whh = dir ? wcb : wcf;
  const float* bh  = whh + 49152;

  __shared__ float sgh[384*5];               // [row d][graph g], stride 5
  __shared__ __align__(16) float sh[4*128];  // h state [g][d]

  const int tid = threadIdx.x;   // 0..383, owns gate-row d=tid

  // load W row into registers (once)
  float4 wreg[32];
  {
    const float4* wrow = (const float4*)(whh + (size_t)tid*128);
    #pragma unroll
    for (int i=0;i<32;i++) wreg[i] = wrow[i];
  }
  const float bhd = bh[tid];

  // cell-phase ownership: item A = tid (g=tid>>7 in {0,1,2}, d=tid&127);
  // item B = 384+tid for tid<128 (g=3, d=tid)
  const int gA = tid>>7, dA = tid&127;

  for (int i=tid;i<512;i+=384) sh[i]=0.f;
  __syncthreads();

  for (int step=0; step<64; ++step){
    const int t = dir ? (63-step) : step;

    // ---- prefetch gi for this step's cell items (independent of LDS) ----
    const u16* gpA = gi + (size_t)((g0+gA)*TSEQ + t)*384;
    u16 aR = gpA[dA], aZ = gpA[128+dA], aN = gpA[256+dA];
    u16 bR=0, bZ=0, bN=0;
    if (tid < 128){
      const u16* gpB = gi + (size_t)((g0+3)*TSEQ + t)*384;
      bR = gpB[tid]; bZ = gpB[128+tid]; bN = gpB[256+tid];
    }

    // ---- GEMV: gh[d][g] = whh[d]·h[g] + bh[d], W from registers ----
    float a0=0.f, a1=0.f, a2=0.f, a3=0.f;
    #pragma unroll
    for (int k4=0; k4<32; k4++){
      float4 w  = wreg[k4];
      float4 h0 = *(const float4*)&sh[0*128 + k4*4];
      float4 h1 = *(const float4*)&sh[1*128 + k4*4];
      float4 h2 = *(const float4*)&sh[2*128 + k4*4];
      float4 h3 = *(const float4*)&sh[3*128 + k4*4];
      a0 += h0.x*w.x + h0.y*w.y + h0.z*w.z + h0.w*w.w;
      a1 += h1.x*w.x + h1.y*w.y + h1.z*w.z + h1.w*w.w;
      a2 += h2.x*w.x + h2.y*w.y + h2.z*w.z + h2.w*w.w;
      a3 += h3.x*w.x + h3.y*w.y + h3.z*w.z + h3.w*w.w;
    }
    sgh[tid*5+0] = a0 + bhd;
    sgh[tid*5+1] = a1 + bhd;
    sgh[tid*5+2] = a2 + bhd;
    sgh[tid*5+3] = a3 + bhd;
    __syncthreads();

    // ---- cell update ----
    {
      float r = sigm(bf2f(aR) + sgh[dA*5+gA]);
      float z = sigm(bf2f(aZ) + sgh[(128+dA)*5+gA]);
      float n = tanhfast(bf2f(aN) + r*sgh[(256+dA)*5+gA]);
      float h = (1.f-z)*n + z*sh[gA*128+dA];
      sh[gA*128+dA] = h;
      if (write_seq){
        float hc = fminf(fmaxf(h,-10.f),10.f);
        out_seq[(size_t)((g0+gA)*TSEQ + t)*256 + dir*HD + dA] = f2bf(hc);
      }
    }
    if (tid < 128){
      float r = sigm(bf2f(bR) + sgh[tid*5+3]);
      float z = sigm(bf2f(bZ) + sgh[(128+tid)*5+3]);
      float n = tanhfast(bf2f(bN) + r*sgh[(256+tid)*5+3]);
      float h = (1.f-z)*n + z*sh[3*128+tid];
      sh[3*128+tid] = h;
      if (write_seq){
        float hc = fminf(fmaxf(h,-10.f),10.f);
        out_seq[(size_t)((g0+3)*TSEQ + t)*256 + dir*HD + tid] = f2bf(hc);
      }
    }
    __syncthreads();
  }

  if (!write_seq){
    for (int i=tid;i<512;i+=384){
      int g=i>>7, d=i&127;
      zbuf[(size_t)(g0+g)*256 + dir*HD + d] = fminf(fmaxf(sh[g*128+d],-10.f),10.f);
    }
  }
}

__launch_bounds__(64)
__global__ void k_gather(const float* he, const int* ptr, const int* cidx, float* out){
  int n = blockIdx.x;
  int c = threadIdx.x;
  int b = ptr[n], e = ptr[n+1];
  float s0=0.f,s1=0.f;
  for (int i=b;i<e;++i){
    int eid = cidx[i];
    float2 v = *(const float2*)(he + (size_t)eid*HD + c*2);
    s0+=v.x; s1+=v.y;
  }
  out[(size_t)n*HD + c*2]   = s0;
  out[(size_t)n*HD + c*2+1] = s1;
}

__global__ void k_count(const int* dst, int* cnt){
  int e = blockIdx.x*256+threadIdx.x;
  if (e<NE) atomicAdd(&cnt[dst[e]],1);
}

__launch_bounds__(1024)
__global__ void k_scan(const int* cnt, int* ptr){
  __shared__ int s[1024];
  int tid=threadIdx.x;
  int loc[32]; int tot=0;
  int base = tid*32;
  #pragma unroll
  for (int i=0;i<32;i++){ loc[i]=tot; tot += cnt[base+i]; }
  s[tid]=tot; __syncthreads();
  for (int off=1; off<1024; off<<=1){
    int v = (tid>=off)? s[tid-off] : 0;
    __syncthreads();
    s[tid] += v;
    __syncthreads();
  }
  int ex = s[tid] - tot;
  for (int i=0;i<32;i++) ptr[base+i] = ex + loc[i];
  if (tid==1023) ptr[NN] = ex + tot;
}

__global__ void k_fill(const int* dst, const int* ptr, int* cur, int* cidx){
  int e = blockIdx.x*256+threadIdx.x;
  if (e<NE){
    int d = dst[e];
    int p = ptr[d] + atomicAdd(&cur[d],1);
    cidx[p] = e;
  }
}

// runtime input-dtype detector (fp32 low-halfword exponents ~uniform; bf16 ~always in-range)
__global__ void k_detect(const u16* x, int* flag){
  __shared__ int cnt;
  if (threadIdx.x==0) cnt=0;
  __syncthreads();
  u16 u = x[threadIdx.x*2];
  int e = (u>>7)&0xff;
  if (e>=100 && e<=135) atomicAdd(&cnt,1);
  __syncthreads();
  if (threadIdx.x==0) *flag = (cnt>=128) ? 1 : 0;
}

__launch_bounds__(256)
__global__ void k_bnstats(const float* z, const void* bng, const void* bnb, float* st, const int* dflag){
  int dt = *dflag;
  int c = threadIdx.x;
  float sm=0.f, sq=0.f;
  for (int g=0; g<NG; ++g){ float v = z[(size_t)g*256+c]; sm+=v; sq+=v*v; }
  float mu = sm*(1.f/(float)NG);
  float var = sq*(1.f/(float)NG) - mu*mu;
  float rs = rsqrtf(fmaxf(var,0.f)+1e-5f);
  float sc = rs*rg(bng,c,dt);
  st[c] = sc;
  st[256+c] = rg(bnb,c,dt) - mu*sc;
}

// OUTPUT fp32 (confirmed by r8: finite ref-scale error under fp32 writes)
__global__ void k_pred(const float* z, const float* st, const void* pw, const void* pb, float* out, const int* dflag){
  int dt = *dflag;
  int g = blockIdx.x*256+threadIdx.x;
  if (g>=NG) return;
  float acc = rg(pb,0,dt);
  for (int c=0;c<256;c++) acc += (z[(size_t)g*256+c]*st[c] + st[256+c])*rg(pw,c,dt);
  out[g]=acc;
}

extern "C" void kernel_launch(void* const* d_in, const int* in_sizes, int n_in,
                              void* d_out, int out_size, void* d_ws, size_t ws_size,
                              hipStream_t stream)
{
  const void* X    =d_in[0];
  const void* EA   =d_in[1];
  const void* NW   =d_in[2];
  const void* NB   =d_in[3];
  const void* NGa  =d_in[4];
  const void* NBt  =d_in[5];
  const void* EW   =d_in[6];
  const void* EB   =d_in[7];
  const void* EGa  =d_in[8];
  const void* EBt  =d_in[9];
  const void* LW   =d_in[10];
  const void* LB   =d_in[11];
  const void* LGa  =d_in[12];
  const void* LBt  =d_in[13];
  const void* NUW  =d_in[14];
  const void* NUB  =d_in[15];
  const void* NNG  =d_in[16];
  const void* NNB  =d_in[17];
  const void* EUW  =d_in[18];
  const void* EUB  =d_in[19];
  const void* BOOST=d_in[20];
  const void* BIHW_F=d_in[21];
  const void* BHHW_F=d_in[22];
  const void* BIHB_F=d_in[23];
  const void* BHHB_F=d_in[24];
  const void* BIHW_B=d_in[25];
  const void* BHHW_B=d_in[26];
  const void* BIHB_B=d_in[27];
  const void* BHHB_B=d_in[28];
  const void* PW   =d_in[29];
  const void* PB   =d_in[30];
  const void* PG   =d_in[31];
  const void* PBt  =d_in[32];
  const void* FW   =d_in[33];
  const void* FB   =d_in[34];
  const void* FG   =d_in[35];
  const void* FBt  =d_in[36];
  const void* RIHW_F=d_in[37];
  const void* RHHW_F=d_in[38];
  const void* RIHB_F=d_in[39];
  const void* RHHB_F=d_in[40];
  const void* RIHW_B=d_in[41];
  const void* RHHW_B=d_in[42];
  const void* RIHB_B=d_in[43];
  const void* RHHB_B=d_in[44];
  const void* BNG  =d_in[45];
  const void* BNB  =d_in[46];
  const void* PRW  =d_in[47];
  const void* PRB  =d_in[48];
  const int* EIDX =(const int*)d_in[49];
  const int* DST  = EIDX + NE;

  // ---- Workspace (same map as before; fp32 GRU weights in 2MB..3MB gap) ----
  char* ws=(char*)d_ws;
  const size_t MB = 1048576;
  int*   csrp =(int*)  (ws + 0);
  int*   csrc =(int*)  (ws + 135168);
  int*   csri =(int*)  (ws + 266240);
  float* zbuf =(float*)(ws + 790528);
  float* stats=(float*)(ws + 1314816);
  int*   dflag=(int*)  (ws + 1316864);
  float* wbgf =(float*)(ws + 2*MB);          // [49152 whh | 384 bhh] fp32, boost fwd
  float* wbgb = wbgf + 49536;                // boost bwd
  float* wrgf = wbgb + 49536;                // readout fwd
  float* wrgb = wrgf + 49536;                // readout bwd
  float* hv   =(float*)(ws + 6*MB);
  u16*   he0  =(u16*)  (ws + 22*MB);
  float* he   =(float*)(ws + 54*MB);
  float* mfin =(float*)(ws + 22*MB);
  u16*   gif  =(u16*)  (ws + 54*MB);
  u16*   gib  =(u16*)  (ws + 78*MB);
  u16*   oseq =(u16*)  (ws + 6*MB);
  float* hv2  =(float*)(ws + 38*MB);
  float* hx2  =(float*)(ws + 6*MB);
  float* fout =(float*)(ws + 54*MB);
  u16*   gif_r=(u16*)  (ws + 70*MB);
  u16*   gib_r=(u16*)  (ws + 94*MB);

  k_detect<<<dim3(1),dim3(256),0,stream>>>((const u16*)X, dflag);

  // pre-convert recurrent GRU weights to fp32 (one merged launch)
  k_cvt4<<<dim3(194,4),dim3(256),0,stream>>>(
      BHHW_F,BHHB_F, BHHW_B,BHHB_B, RHHW_F,RHHB_F, RHHW_B,RHHB_B,
      wbgf, wbgb, wrgf, wrgb, dflag);

  // CSR over dst
  hipMemsetAsync(csrc, 0, 131072, stream);
  k_count<<<dim3(512),dim3(256),0,stream>>>(DST, csrc);
  k_scan<<<dim3(1),dim3(1024),0,stream>>>(csrc, csrp);
  hipMemsetAsync(csrc, 0, 131072, stream);
  k_fill<<<dim3(512),dim3(256),0,stream>>>(DST, csrp, csrc, csri);

  // init embeddings
  k_dense<A_XF,E_LN_RELU,2,1><<<dim3(512),dim3(256),0,stream>>>(X,nullptr,nullptr,
      nullptr,nullptr,nullptr,nullptr, NW,nullptr,0, NB,nullptr,NGa,NBt,0, nullptr,nullptr,
      hv,nullptr,nullptr, dflag, 133,133,HD,0);
  k_dense<A_XF,E_LN_RELU_DUAL,1,1><<<dim3(2048),dim3(256),0,stream>>>(EA,nullptr,nullptr,
      nullptr,nullptr,nullptr,nullptr, EW,nullptr,0, EB,nullptr,EGa,EBt,0, nullptr,nullptr,
      he,he0,nullptr, dflag, 14,14,HD,0);

  // message passing
  for (int s=0;s<5;s++){
    k_dense<A_MSG,E_RESID_LN,2,1><<<dim3(512),dim3(256),0,stream>>>(hv,he,nullptr,
        nullptr,csrp,csri,nullptr, NUW,nullptr,s*32768, NUB,nullptr,NNG,NNB,s*128,
        hv,nullptr, hv,nullptr,nullptr, dflag, 256,HD,HD,0);
    k_dense<A_EDGE,E_HE0_RELU,1,1><<<dim3(2048),dim3(256),0,stream>>>(hv,he,nullptr,
        DST,nullptr,nullptr,nullptr, EUW,nullptr,s*16384, EUB,nullptr,nullptr,nullptr,s*128,
        nullptr,he0, he,nullptr,nullptr, dflag, 128,HD,HD,0);
  }
  k_gather<<<dim3(NN),dim3(64),0,stream>>>(he, csrp, csri, mfin);

  // boost GRU input-side gates: ONE launch, 6 weight segments (F0-2,B0-2)
  k_dense<A_BOOST,E_GI,1,6><<<dim3(512),dim3(256),0,stream>>>(hv,nullptr,nullptr,
      nullptr,nullptr,nullptr,BOOST, BIHW_F,BIHW_B,0, BIHB_F,BIHB_B,nullptr,nullptr,0,
      nullptr,nullptr, nullptr,gif,gib, dflag, 128,HD,384,0);
  k_gru<<<dim3(128,2),dim3(384),0,stream>>>(gif, gib, wbgf, wbgb, oseq, zbuf, 1);

  // proj + recompute hx + final merge
  k_dense<A_B16,E_LN_RELU_TANH,2,1><<<dim3(512),dim3(256),0,stream>>>(oseq,nullptr,nullptr,
      nullptr,nullptr,nullptr,nullptr, PW,nullptr,0, PB,nullptr,PG,PBt,0, nullptr,nullptr,
      hv2,nullptr,nullptr, dflag, 256,256,HD,0);
  k_dense<A_XF,E_LN,2,1><<<dim3(512),dim3(256),0,stream>>>(X,nullptr,nullptr,
      nullptr,nullptr,nullptr,nullptr, LW,nullptr,0, LB,nullptr,LGa,LBt,0, nullptr,nullptr,
      hx2,nullptr,nullptr, dflag, 133,133,HD,0);
  k_dense<A_C3,E_LN_RELU,3,1><<<dim3(512),dim3(256),0,stream>>>(hv2,mfin,hx2,
      nullptr,nullptr,nullptr,nullptr, FW,nullptr,0, FB,nullptr,FG,FBt,0, nullptr,nullptr,
      fout,nullptr,nullptr, dflag, 384,HD,HD,0);

  // readout GRU gates (ONE launch, 6 segments) + GRU
  k_dense<A_F32,E_GI,1,6><<<dim3(512),dim3(256),0,stream>>>(fout,nullptr,nullptr,
      nullptr,nullptr,nullptr,nullptr, RIHW_F,RIHW_B,0, RIHB_F,RIHB_B,nullptr,nullptr,0,
      nullptr,nullptr, nullptr,gif_r,gib_r, dflag, 128,HD,384,0);
  k_gru<<<dim3(128,2),dim3(384),0,stream>>>(gif_r, gib_r, wrgf, wrgb, oseq, zbuf, 0);

  // BN + prediction
  k_bnstats<<<dim3(1),dim3(256),0,stream>>>(zbuf, BNG, BNB, stats, dflag);
  k_pred<<<dim3(2),dim3(256),0,stream>>>(zbuf, stats, PRW, PRB, (float*)d_out, dflag);

  (void)in_sizes; (void)n_in; (void)out_size; (void)ws_size;
}

// Round 7
// 2661.967 us; speedup vs baseline: 1.5135x; 1.1645x over previous
//
#include <hip/hip_runtime.h>
#include <hip/hip_bf16.h>

typedef unsigned short u16;
typedef unsigned int   u32;

#define NN    32768
#define NG    512
#define TSEQ  64
#define NE    131072
#define NP    65536
#define HD    128

__device__ __forceinline__ float bf2f(u16 v){ u32 u=((u32)v)<<16; float f; __builtin_memcpy(&f,&u,4); return f; }
__device__ __forceinline__ u16 f2bf(float f){ u32 u; __builtin_memcpy(&u,&f,4); u32 r=u+0x7fffu+((u>>16)&1u); return (u16)(r>>16); }
__device__ __forceinline__ float sigm(float x){ return 1.f/(1.f+__expf(-x)); }
__device__ __forceinline__ float tanhfast(float x){ return 1.f-2.f/(1.f+__expf(2.f*x)); }
// raw-input read: dt=1 -> bf16, dt=0 -> fp32
__device__ __forceinline__ float rg(const void* p, size_t i, int dt){
  return dt ? bf2f(((const u16*)p)[i]) : ((const float*)p)[i];
}

// A-source modes / epilogues
enum { A_XF, A_F32, A_B16, A_MSG, A_C3, A_EDGE, A_BOOST };
enum { E_LN_RELU, E_LN, E_LN_RELU_TANH, E_RESID_LN, E_HE0_RELU, E_GI, E_LN_RELU_DUAL };

// ===== MEASURED-CONFIG LEDGER (do not re-try losers) =====
// dense: 32-k W single-buffer SYNC stage = BEST (r4 total 2633).
//   - 64-k W tile (r2/r3): no better, 67KB LDS -> 2 blocks/CU.
//   - reg double-buffer W (r5 lambda): -1.0ms REGRESSION (codegen blowup).
//   - raw-bit uint4 pipelined W (r6): -0.5ms REGRESSION.
// k_gru: 4 graphs/block, grid(128,2), launch_bounds(384,1) = BEST (318us).
//   - (384,3): VGPR 84 -> wreg spill -> 780us (r3).
//   - next-step gi prefetch: VGPR overflow -> spill -> 490us (r5).
// =========================================================

// Register-tiled fp32 GEMM core (4x8 micro-tile). A staged once per chunk
// (float4/ushort4 vectorized where layout permits); W staged per 32-k
// sub-chunk (16 KB LDS -> ~51 KB total). NSEG>1 (E_GI only): loop NSEG
// weight segments over the SAME staged A (seg<3 -> W/bias/outb fwd, else
// W2/bias2/outb2 bwd), gate outputs written straight from registers as
// ushort4. fp32 FMA in ascending k-order (numerics preserved).
template<int AM, int EP, int NCH, int NSEG>
__launch_bounds__(256)
__global__ void k_dense(
    const void* a0v, const void* a1v, const void* a2v,
    const int* dsti, const int* ptr, const int* cidx, const void* abias,
    const void* W, const void* W2, int wbase,
    const void* bias, const void* bias2, const void* gamma, const void* beta, int prmoff,
    const float* resid, const u16* he0b,
    float* outf, u16* outb, u16* outb2, const int* dflag,
    int ktot, int astride, int ostride, int ocoff)
{
  __shared__ __align__(16) float sa[64*132];   // A tile (stride 132: rows 16B-aligned)
  __shared__ __align__(16) float wb[32*128];   // W sub-chunk [k][c], 16 KB
  float* so = sa;                 // reused for C after compute (NSEG==1 paths)
  __shared__ float s_mu[64], s_rs[64];
  __shared__ int s_e[64], s_pe[64], s_d[64];
  __shared__ float s_ab[128];

  const int dt  = *dflag;
  const int tid = threadIdx.x;
  const int bx  = blockIdx.x;

  if constexpr (AM==A_EDGE){
    if (tid < 64){
      int eb = bx*32;
      int e = (tid<32) ? (eb+tid) : (NP + eb + tid - 32);
      s_e[tid]  = e;
      s_pe[tid] = (tid<32) ? (e+NP) : (e-NP);
      s_d[tid]  = dsti[e];
    }
    __syncthreads();
  }
  if constexpr (AM==A_BOOST){
    if (tid < 128) s_ab[tid] = rg(abias, tid, dt);
    __syncthreads();
  }
  const int rbase = (AM==A_EDGE) ? 0 : bx*64;

  const int row = tid>>2, qq = tid&3;   // epilogue mapping
  const int ry4 = (tid>>4)*4;           // compute: rows ry4..ry4+3
  const int cxx = (tid&15)*4;           // compute: cols cxx..+3 and 64+cxx..+3

  float acc[4][8];

  for (int seg=0; seg<NSEG; ++seg){
    #pragma unroll
    for (int i=0;i<4;i++)
      #pragma unroll
      for (int j=0;j<8;j++) acc[i][j]=0.f;

    const int wb_seg = (NSEG==6) ? (seg%3)*(ktot*HD) : wbase;
    const void* Wt   = (NSEG==6 && seg>=3) ? W2 : W;
    const bool wvec = ((ktot&3)==0) && ((wb_seg&3)==0);

    for (int ch=0; ch<NCH; ++ch){
      int klim = ktot - ch*128; if (klim > 128) klim = 128;

      if (seg==0){
        // ---- stage 64x128 fp32 A-chunk ----
        if constexpr (AM==A_XF){
          for (int idx=tid; idx<8192; idx+=256){
            int r = idx>>7, lk = idx&127, k = ch*128 + lk;
            float v = 0.f;
            if (k < ktot) v = rg(a0v, (size_t)(rbase+r)*astride + k, dt);
            sa[r*132 + lk] = v;
          }
        }
        if constexpr (AM==A_F32){
          for (int idx=tid; idx<2048; idx+=256){
            int r = idx>>5, c4 = (idx&31)*4;
            float4 v = *(const float4*)((const float*)a0v + (size_t)(rbase+r)*astride + ch*128 + c4);
            *(float4*)&sa[r*132 + c4] = v;
          }
        }
        if constexpr (AM==A_B16){
          for (int idx=tid; idx<2048; idx+=256){
            int r = idx>>5, c4 = (idx&31)*4;
            ushort4 u = *(const ushort4*)((const u16*)a0v + (size_t)(rbase+r)*astride + ch*128 + c4);
            *(float4*)&sa[r*132 + c4] = make_float4(bf2f(u.x),bf2f(u.y),bf2f(u.z),bf2f(u.w));
          }
        }
        if constexpr (AM==A_C3){
          const float* src = (ch==0)?(const float*)a0v:(ch==1)?(const float*)a1v:(const float*)a2v;
          for (int idx=tid; idx<2048; idx+=256){
            int r = idx>>5, c4 = (idx&31)*4;
            float4 v = *(const float4*)(src + (size_t)(rbase+r)*HD + c4);
            *(float4*)&sa[r*132 + c4] = v;
          }
        }
        if constexpr (AM==A_BOOST){
          for (int idx=tid; idx<2048; idx+=256){
            int r = idx>>5, c4 = (idx&31)*4;
            float4 v = *(const float4*)((const float*)a0v + (size_t)(rbase+r)*HD + c4);
            v.x = fmaxf(v.x + s_ab[c4+0], 0.f);
            v.y = fmaxf(v.y + s_ab[c4+1], 0.f);
            v.z = fmaxf(v.z + s_ab[c4+2], 0.f);
            v.w = fmaxf(v.w + s_ab[c4+3], 0.f);
            *(float4*)&sa[r*132 + c4] = v;
          }
        }
        if constexpr (AM==A_EDGE){
          for (int idx=tid; idx<2048; idx+=256){
            int r = idx>>5, c4 = (idx&31)*4;
            float4 va = *(const float4*)((const float*)a0v + (size_t)s_d[r]*HD + c4);
            float4 vb = *(const float4*)((const float*)a1v + (size_t)s_pe[r]*HD + c4);
            *(float4*)&sa[r*132 + c4] = make_float4(va.x-vb.x, va.y-vb.y, va.z-vb.z, va.w-vb.w);
          }
        }
        if constexpr (AM==A_MSG){
          if (ch==0){
            for (int idx=tid; idx<2048; idx+=256){
              int r = idx>>5, c4 = (idx&31)*4;
              float4 v = *(const float4*)((const float*)a0v + (size_t)(rbase+r)*HD + c4);
              *(float4*)&sa[r*132 + c4] = v;
            }
          } else {
            for (int idx=tid; idx<8192; idx+=256){
              int r = idx>>7, cc = idx&127;
              int node = rbase+r;
              int b = ptr[node], en = ptr[node+1];
              float s=0.f, m=0.f;
              for (int i=b;i<en;++i){
                float t = ((const float*)a1v)[(size_t)cidx[i]*HD + cc];
                s += t; m = fmaxf(m,t);
              }
              sa[r*132 + cc] = s*m;   // m_sum * relu(segment_max); he>=0
            }
          }
        }
      }

      for (int kk=0; kk<klim; kk+=32){
        // ---- stage W sub-chunk [32 k][128 c]; thread: c=tid>>1, k-half=(tid&1)*16 ----
        {
          int c = tid>>1, kh = (tid&1)*16;
          size_t wrow = (size_t)wb_seg + (size_t)c*ktot + (size_t)ch*128 + kk;
          if (wvec && dt==0){
            const float* Wf = (const float*)Wt;
            #pragma unroll
            for (int j4=0;j4<4;j4++){
              int kq = kh + j4*4;
              float v0=0.f,v1=0.f,v2=0.f,v3=0.f;
              if (kk+kq+4 <= klim){
                float4 v = *(const float4*)(Wf + wrow + kq);
                v0=v.x; v1=v.y; v2=v.z; v3=v.w;
              } else if (kk+kq < klim){
                v0 = Wf[wrow+kq];
                if (kk+kq+1<klim) v1 = Wf[wrow+kq+1];
                if (kk+kq+2<klim) v2 = Wf[wrow+kq+2];
              }
              wb[(kq+0)*128+c]=v0; wb[(kq+1)*128+c]=v1; wb[(kq+2)*128+c]=v2; wb[(kq+3)*128+c]=v3;
            }
          } else if (wvec){
            const u16* Wh = (const u16*)Wt;
            #pragma unroll
            for (int j4=0;j4<4;j4++){
              int kq = kh + j4*4;
              float v0=0.f,v1=0.f,v2=0.f,v3=0.f;
              if (kk+kq+4 <= klim){
                ushort4 v = *(const ushort4*)(Wh + wrow + kq);
                v0=bf2f(v.x); v1=bf2f(v.y); v2=bf2f(v.z); v3=bf2f(v.w);
              } else if (kk+kq < klim){
                v0 = bf2f(Wh[wrow+kq]);
                if (kk+kq+1<klim) v1 = bf2f(Wh[wrow+kq+1]);
                if (kk+kq+2<klim) v2 = bf2f(Wh[wrow+kq+2]);
              }
              wb[(kq+0)*128+c]=v0; wb[(kq+1)*128+c]=v1; wb[(kq+2)*128+c]=v2; wb[(kq+3)*128+c]=v3;
            }
          } else {
            for (int j=0;j<16;j++){
              int kq = kh + j;
              wb[kq*128+c] = (kk+kq < klim) ? rg(Wt, wrow+kq, dt) : 0.f;
            }
          }
        }
        __syncthreads();   // sa (if staged this round) + wb ready

        // ---- compute: 32 k's, zero-padded tails contribute 0 ----
        for (int kc=0; kc<32; kc+=4){
          float4 aa[4];
          #pragma unroll
          for (int i=0;i<4;i++)
            aa[i] = *(const float4*)&sa[(ry4+i)*132 + kk + kc];
          #pragma unroll
          for (int t=0;t<4;t++){
            float4 b0 = *(const float4*)&wb[(kc+t)*128 + cxx];
            float4 b1 = *(const float4*)&wb[(kc+t)*128 + 64 + cxx];
            #pragma unroll
            for (int i=0;i<4;i++){
              float a = (t==0)?aa[i].x:(t==1)?aa[i].y:(t==2)?aa[i].z:aa[i].w;
              acc[i][0]+=a*b0.x; acc[i][1]+=a*b0.y; acc[i][2]+=a*b0.z; acc[i][3]+=a*b0.w;
              acc[i][4]+=a*b1.x; acc[i][5]+=a*b1.y; acc[i][6]+=a*b1.z; acc[i][7]+=a*b1.w;
            }
          }
        }
        __syncthreads();   // before restaging wb / next A chunk
      }
    }

    if constexpr (EP==E_GI){
      // register epilogue: out = f2bf(acc + bias), packed ushort4 stores
      const void* bsrc = (NSEG==6 && seg>=3) ? bias2 : bias;
      const int   po   = (NSEG==6) ? (seg%3)*HD : prmoff;
      u16*        op   = (NSEG==6) ? (seg<3 ? outb : outb2) : outb;
      const int   oc   = (NSEG==6) ? (seg%3)*HD : ocoff;
      float b0[4], b1[4];
      #pragma unroll
      for (int j=0;j<4;j++){
        b0[j] = rg(bsrc, po + cxx + j, dt);
        b1[j] = rg(bsrc, po + 64 + cxx + j, dt);
      }
      #pragma unroll
      for (int i=0;i<4;i++){
        size_t gr = (size_t)(rbase + ry4 + i);
        ushort4 u0, u1;
        u0.x=f2bf(acc[i][0]+b0[0]); u0.y=f2bf(acc[i][1]+b0[1]);
        u0.z=f2bf(acc[i][2]+b0[2]); u0.w=f2bf(acc[i][3]+b0[3]);
        u1.x=f2bf(acc[i][4]+b1[0]); u1.y=f2bf(acc[i][5]+b1[1]);
        u1.z=f2bf(acc[i][6]+b1[2]); u1.w=f2bf(acc[i][7]+b1[3]);
        *(ushort4*)&op[gr*ostride + oc + cxx]      = u0;
        *(ushort4*)&op[gr*ostride + oc + 64 + cxx] = u1;
      }
    }
  }

  if constexpr (EP==E_GI) return;

  // dump C to LDS (so aliases sa; all sa reads completed at the barrier above)
  #pragma unroll
  for (int i=0;i<4;i++){
    *(float4*)&so[(ry4+i)*132 + cxx]      = make_float4(acc[i][0],acc[i][1],acc[i][2],acc[i][3]);
    *(float4*)&so[(ry4+i)*132 + 64 + cxx] = make_float4(acc[i][4],acc[i][5],acc[i][6],acc[i][7]);
  }
  __syncthreads();

  if constexpr (EP==E_HE0_RELU){
    for (int idx=tid; idx<8192; idx+=256){
      int r = idx>>7, c = idx&127;
      int e = s_e[r];
      float v = so[r*132+c] + rg(bias,prmoff+c,dt) + bf2f(he0b[(size_t)e*HD + c]);
      outf[(size_t)e*HD + c] = fmaxf(v,0.f);
    }
    return;
  }
  if constexpr (EP==E_LN_RELU || EP==E_LN || EP==E_LN_RELU_TANH || EP==E_RESID_LN || EP==E_LN_RELU_DUAL){
    float sm=0.f, sq=0.f;
    for (int i=0;i<32;i++){
      int c = qq*32+i;
      float v = so[row*132+c] + rg(bias,prmoff+c,dt);
      if constexpr (EP==E_RESID_LN) v = resid[(size_t)(rbase+row)*HD + c] + fmaxf(v,0.f);
      sm += v; sq += v*v;
    }
    sm += __shfl_xor(sm,1); sq += __shfl_xor(sq,1);
    sm += __shfl_xor(sm,2); sq += __shfl_xor(sq,2);
    if (qq==0){
      float mu = sm*(1.f/128.f);
      float var = sq*(1.f/128.f) - mu*mu;
      s_mu[row] = mu;
      s_rs[row] = rsqrtf(fmaxf(var,0.f)+1e-5f);
    }
    __syncthreads();
    for (int idx=tid; idx<8192; idx+=256){
      int r = idx>>7, c = idx&127;
      float v = so[r*132+c] + rg(bias,prmoff+c,dt);
      if constexpr (EP==E_RESID_LN) v = resid[(size_t)(rbase+r)*HD + c] + fmaxf(v,0.f);
      float y = (v - s_mu[r])*s_rs[r]*rg(gamma,prmoff+c,dt) + rg(beta,prmoff+c,dt);
      // E_RESID_LN: h_v = LN(h_v + relu(upd)) — no ReLU after LN.
      if constexpr (EP==E_LN_RELU || EP==E_LN_RELU_DUAL) y = fmaxf(y,0.f);
      if constexpr (EP==E_LN_RELU_TANH) y = tanhfast(fmaxf(y,0.f));
      if constexpr (EP==E_LN_RELU_DUAL){
        outf[(size_t)(rbase+r)*HD + c] = y;          // he (fp32)
        outb[(size_t)(rbase+r)*HD + c] = f2bf(y);    // he0 (bf16, single rounding)
      } else {
        outf[(size_t)(rbase+r)*HD + c] = y;
      }
    }
  }
}

// merged weight pre-convert: 4 (whh,bhh) pairs raw -> fp32 [49152|384] blocks
__global__ void k_cvt4(const void* w0,const void* b0,const void* w1,const void* b1,
                       const void* w2,const void* b2,const void* w3,const void* b3,
                       float* d0, float* d1, float* d2, float* d3, const int* dflag){
  int dt = *dflag;
  int p  = blockIdx.y;
  const void* wsrc = (p==0)?w0:(p==1)?w1:(p==2)?w2:w3;
  const void* bsrc = (p==0)?b0:(p==1)?b1:(p==2)?b2:b3;
  float* dst       = (p==0)?d0:(p==1)?d1:(p==2)?d2:d3;
  int i = blockIdx.x*256 + threadIdx.x;
  if (i < 49152)      dst[i] = rg(wsrc, i, dt);
  else if (i < 49536) dst[i] = rg(bsrc, i-49152, dt);
}

// BiGRU, W-in-registers (EXACT r6-measured 318us config — do not touch):
// one block = 4 graphs x one dir (grid 128x2); 384 threads; thread owns
// gate-row d=tid and keeps its whh row (32 float4) in registers for all 64
// steps. launch_bounds(384,1): VGPR 128, no spill (ledger: min-waves=3 and
// next-step prefetch both spill). Same-step gi prefetch only. sgh stride 5
// (gcd(5,32)=1): conflict-free cell reads. fp32 FMA, same k-order.
__launch_bounds__(384,1)
__global__ void k_gru(
  const u16* gi_f, const u16* gi_b,
  const float* wcf, const float* wcb,
  u16* out_seq, float* zbuf, int write_seq)
{
  const int dir = blockIdx.y;
  const int g0  = blockIdx.x * 4;
  const u16* gi  = dir ? gi_b : gi_f;
  const float* whh = dir ? wcb : wcf;
  const float* bh  = whh + 49152;

  __shared__ float sgh[384*5];               // [row d][graph g], stride 5
  __shared__ __align__(16) float sh[4*128];  // h state [g][d]

  const int tid = threadIdx.x;   // 0..383, owns gate-row d=tid

  // load W row into registers (once)
  float4 wreg[32];
  {
    const float4* wrow = (const float4*)(whh + (size_t)tid*128);
    #pragma unroll
    for (int i=0;i<32;i++) wreg[i] = wrow[i];
  }
  const float bhd = bh[tid];

  // cell-phase ownership: item A = tid (g=tid>>7 in {0,1,2}, d=tid&127);
  // item B = 384+tid for tid<128 (g=3, d=tid)
  const int gA = tid>>7, dA = tid&127;

  for (int i=tid;i<512;i+=384) sh[i]=0.f;
  __syncthreads();

  for (int step=0; step<64; ++step){
    const int t = dir ? (63-step) : step;

    // ---- prefetch gi for this step's cell items (independent of LDS) ----
    const u16* gpA = gi + (size_t)((g0+gA)*TSEQ + t)*384;
    u16 aR = gpA[dA], aZ = gpA[128+dA], aN = gpA[256+dA];
    u16 bR=0, bZ=0, bN=0;
    if (tid < 128){
      const u16* gpB = gi + (size_t)((g0+3)*TSEQ + t)*384;
      bR = gpB[tid]; bZ = gpB[128+tid]; bN = gpB[256+tid];
    }

    // ---- GEMV: gh[d][g] = whh[d]·h[g] + bh[d], W from registers ----
    float a0=0.f, a1=0.f, a2=0.f, a3=0.f;
    #pragma unroll
    for (int k4=0; k4<32; k4++){
      float4 w  = wreg[k4];
      float4 h0 = *(const float4*)&sh[0*128 + k4*4];
      float4 h1 = *(const float4*)&sh[1*128 + k4*4];
      float4 h2 = *(const float4*)&sh[2*128 + k4*4];
      float4 h3 = *(const float4*)&sh[3*128 + k4*4];
      a0 += h0.x*w.x + h0.y*w.y + h0.z*w.z + h0.w*w.w;
      a1 += h1.x*w.x + h1.y*w.y + h1.z*w.z + h1.w*w.w;
      a2 += h2.x*w.x + h2.y*w.y + h2.z*w.z + h2.w*w.w;
      a3 += h3.x*w.x + h3.y*w.y + h3.z*w.z + h3.w*w.w;
    }
    sgh[tid*5+0] = a0 + bhd;
    sgh[tid*5+1] = a1 + bhd;
    sgh[tid*5+2] = a2 + bhd;
    sgh[tid*5+3] = a3 + bhd;
    __syncthreads();

    // ---- cell update ----
    {
      float r = sigm(bf2f(aR) + sgh[dA*5+gA]);
      float z = sigm(bf2f(aZ) + sgh[(128+dA)*5+gA]);
      float n = tanhfast(bf2f(aN) + r*sgh[(256+dA)*5+gA]);
      float h = (1.f-z)*n + z*sh[gA*128+dA];
      sh[gA*128+dA] = h;
      if (write_seq){
        float hc = fminf(fmaxf(h,-10.f),10.f);
        out_seq[(size_t)((g0+gA)*TSEQ + t)*256 + dir*HD + dA] = f2bf(hc);
      }
    }
    if (tid < 128){
      float r = sigm(bf2f(bR) + sgh[tid*5+3]);
      float z = sigm(bf2f(bZ) + sgh[(128+tid)*5+3]);
      float n = tanhfast(bf2f(bN) + r*sgh[(256+tid)*5+3]);
      float h = (1.f-z)*n + z*sh[3*128+tid];
      sh[3*128+tid] = h;
      if (write_seq){
        float hc = fminf(fmaxf(h,-10.f),10.f);
        out_seq[(size_t)((g0+3)*TSEQ + t)*256 + dir*HD + tid] = f2bf(hc);
      }
    }
    __syncthreads();
  }

  if (!write_seq){
    for (int i=tid;i<512;i+=384){
      int g=i>>7, d=i&127;
      zbuf[(size_t)(g0+g)*256 + dir*HD + d] = fminf(fmaxf(sh[g*128+d],-10.f),10.f);
    }
  }
}

__launch_bounds__(64)
__global__ void k_gather(const float* he, const int* ptr, const int* cidx, float* out){
  int n = blockIdx.x;
  int c = threadIdx.x;
  int b = ptr[n], e = ptr[n+1];
  float s0=0.f,s1=0.f;
  for (int i=b;i<e;++i){
    int eid = cidx[i];
    float2 v = *(const float2*)(he + (size_t)eid*HD + c*2);
    s0+=v.x; s1+=v.y;
  }
  out[(size_t)n*HD + c*2]   = s0;
  out[(size_t)n*HD + c*2+1] = s1;
}

__global__ void k_count(const int* dst, int* cnt){
  int e = blockIdx.x*256+threadIdx.x;
  if (e<NE) atomicAdd(&cnt[dst[e]],1);
}

__launch_bounds__(1024)
__global__ void k_scan(const int* cnt, int* ptr){
  __shared__ int s[1024];
  int tid=threadIdx.x;
  int loc[32]; int tot=0;
  int base = tid*32;
  #pragma unroll
  for (int i=0;i<32;i++){ loc[i]=tot; tot += cnt[base+i]; }
  s[tid]=tot; __syncthreads();
  for (int off=1; off<1024; off<<=1){
    int v = (tid>=off)? s[tid-off] : 0;
    __syncthreads();
    s[tid] += v;
    __syncthreads();
  }
  int ex = s[tid] - tot;
  for (int i=0;i<32;i++) ptr[base+i] = ex + loc[i];
  if (tid==1023) ptr[NN] = ex + tot;
}

__global__ void k_fill(const int* dst, const int* ptr, int* cur, int* cidx){
  int e = blockIdx.x*256+threadIdx.x;
  if (e<NE){
    int d = dst[e];
    int p = ptr[d] + atomicAdd(&cur[d],1);
    cidx[p] = e;
  }
}

// runtime input-dtype detector (fp32 low-halfword exponents ~uniform; bf16 ~always in-range)
__global__ void k_detect(const u16* x, int* flag){
  __shared__ int cnt;
  if (threadIdx.x==0) cnt=0;
  __syncthreads();
  u16 u = x[threadIdx.x*2];
  int e = (u>>7)&0xff;
  if (e>=100 && e<=135) atomicAdd(&cnt,1);
  __syncthreads();
  if (threadIdx.x==0) *flag = (cnt>=128) ? 1 : 0;
}

__launch_bounds__(256)
__global__ void k_bnstats(const float* z, const void* bng, const void* bnb, float* st, const int* dflag){
  int dt = *dflag;
  int c = threadIdx.x;
  float sm=0.f, sq=0.f;
  for (int g=0; g<NG; ++g){ float v = z[(size_t)g*256+c]; sm+=v; sq+=v*v; }
  float mu = sm*(1.f/(float)NG);
  float var = sq*(1.f/(float)NG) - mu*mu;
  float rs = rsqrtf(fmaxf(var,0.f)+1e-5f);
  float sc = rs*rg(bng,c,dt);
  st[c] = sc;
  st[256+c] = rg(bnb,c,dt) - mu*sc;
}

// OUTPUT fp32 (confirmed by r8: finite ref-scale error under fp32 writes)
__global__ void k_pred(const float* z, const float* st, const void* pw, const void* pb, float* out, const int* dflag){
  int dt = *dflag;
  int g = blockIdx.x*256+threadIdx.x;
  if (g>=NG) return;
  float acc = rg(pb,0,dt);
  for (int c=0;c<256;c++) acc += (z[(size_t)g*256+c]*st[c] + st[256+c])*rg(pw,c,dt);
  out[g]=acc;
}

extern "C" void kernel_launch(void* const* d_in, const int* in_sizes, int n_in,
                              void* d_out, int out_size, void* d_ws, size_t ws_size,
                              hipStream_t stream)
{
  const void* X    =d_in[0];
  const void* EA   =d_in[1];
  const void* NW   =d_in[2];
  const void* NB   =d_in[3];
  const void* NGa  =d_in[4];
  const void* NBt  =d_in[5];
  const void* EW   =d_in[6];
  const void* EB   =d_in[7];
  const void* EGa  =d_in[8];
  const void* EBt  =d_in[9];
  const void* LW   =d_in[10];
  const void* LB   =d_in[11];
  const void* LGa  =d_in[12];
  const void* LBt  =d_in[13];
  const void* NUW  =d_in[14];
  const void* NUB  =d_in[15];
  const void* NNG  =d_in[16];
  const void* NNB  =d_in[17];
  const void* EUW  =d_in[18];
  const void* EUB  =d_in[19];
  const void* BOOST=d_in[20];
  const void* BIHW_F=d_in[21];
  const void* BHHW_F=d_in[22];
  const void* BIHB_F=d_in[23];
  const void* BHHB_F=d_in[24];
  const void* BIHW_B=d_in[25];
  const void* BHHW_B=d_in[26];
  const void* BIHB_B=d_in[27];
  const void* BHHB_B=d_in[28];
  const void* PW   =d_in[29];
  const void* PB   =d_in[30];
  const void* PG   =d_in[31];
  const void* PBt  =d_in[32];
  const void* FW   =d_in[33];
  const void* FB   =d_in[34];
  const void* FG   =d_in[35];
  const void* FBt  =d_in[36];
  const void* RIHW_F=d_in[37];
  const void* RHHW_F=d_in[38];
  const void* RIHB_F=d_in[39];
  const void* RHHB_F=d_in[40];
  const void* RIHW_B=d_in[41];
  const void* RHHW_B=d_in[42];
  const void* RIHB_B=d_in[43];
  const void* RHHB_B=d_in[44];
  const void* BNG  =d_in[45];
  const void* BNB  =d_in[46];
  const void* PRW  =d_in[47];
  const void* PRB  =d_in[48];
  const int* EIDX =(const int*)d_in[49];
  const int* DST  = EIDX + NE;

  // ---- Workspace (same map as before; fp32 GRU weights in 2MB..3MB gap) ----
  char* ws=(char*)d_ws;
  const size_t MB = 1048576;
  int*   csrp =(int*)  (ws + 0);
  int*   csrc =(int*)  (ws + 135168);
  int*   csri =(int*)  (ws + 266240);
  float* zbuf =(float*)(ws + 790528);
  float* stats=(float*)(ws + 1314816);
  int*   dflag=(int*)  (ws + 1316864);
  float* wbgf =(float*)(ws + 2*MB);          // [49152 whh | 384 bhh] fp32, boost fwd
  float* wbgb = wbgf + 49536;                // boost bwd
  float* wrgf = wbgb + 49536;                // readout fwd
  float* wrgb = wrgf + 49536;                // readout bwd
  float* hv   =(float*)(ws + 6*MB);
  u16*   he0  =(u16*)  (ws + 22*MB);
  float* he   =(float*)(ws + 54*MB);
  float* mfin =(float*)(ws + 22*MB);
  u16*   gif  =(u16*)  (ws + 54*MB);
  u16*   gib  =(u16*)  (ws + 78*MB);
  u16*   oseq =(u16*)  (ws + 6*MB);
  float* hv2  =(float*)(ws + 38*MB);
  float* hx2  =(float*)(ws + 6*MB);
  float* fout =(float*)(ws + 54*MB);
  u16*   gif_r=(u16*)  (ws + 70*MB);
  u16*   gib_r=(u16*)  (ws + 94*MB);

  k_detect<<<dim3(1),dim3(256),0,stream>>>((const u16*)X, dflag);

  // pre-convert recurrent GRU weights to fp32 (one merged launch)
  k_cvt4<<<dim3(194,4),dim3(256),0,stream>>>(
      BHHW_F,BHHB_F, BHHW_B,BHHB_B, RHHW_F,RHHB_F, RHHW_B,RHHB_B,
      wbgf, wbgb, wrgf, wrgb, dflag);

  // CSR over dst
  hipMemsetAsync(csrc, 0, 131072, stream);
  k_count<<<dim3(512),dim3(256),0,stream>>>(DST, csrc);
  k_scan<<<dim3(1),dim3(1024),0,stream>>>(csrc, csrp);
  hipMemsetAsync(csrc, 0, 131072, stream);
  k_fill<<<dim3(512),dim3(256),0,stream>>>(DST, csrp, csrc, csri);

  // init embeddings
  k_dense<A_XF,E_LN_RELU,2,1><<<dim3(512),dim3(256),0,stream>>>(X,nullptr,nullptr,
      nullptr,nullptr,nullptr,nullptr, NW,nullptr,0, NB,nullptr,NGa,NBt,0, nullptr,nullptr,
      hv,nullptr,nullptr, dflag, 133,133,HD,0);
  k_dense<A_XF,E_LN_RELU_DUAL,1,1><<<dim3(2048),dim3(256),0,stream>>>(EA,nullptr,nullptr,
      nullptr,nullptr,nullptr,nullptr, EW,nullptr,0, EB,nullptr,EGa,EBt,0, nullptr,nullptr,
      he,he0,nullptr, dflag, 14,14,HD,0);

  // message passing
  for (int s=0;s<5;s++){
    k_dense<A_MSG,E_RESID_LN,2,1><<<dim3(512),dim3(256),0,stream>>>(hv,he,nullptr,
        nullptr,csrp,csri,nullptr, NUW,nullptr,s*32768, NUB,nullptr,NNG,NNB,s*128,
        hv,nullptr, hv,nullptr,nullptr, dflag, 256,HD,HD,0);
    k_dense<A_EDGE,E_HE0_RELU,1,1><<<dim3(2048),dim3(256),0,stream>>>(hv,he,nullptr,
        DST,nullptr,nullptr,nullptr, EUW,nullptr,s*16384, EUB,nullptr,nullptr,nullptr,s*128,
        nullptr,he0, he,nullptr,nullptr, dflag, 128,HD,HD,0);
  }
  k_gather<<<dim3(NN),dim3(64),0,stream>>>(he, csrp, csri, mfin);

  // boost GRU input-side gates: ONE launch, 6 weight segments (F0-2,B0-2)
  k_dense<A_BOOST,E_GI,1,6><<<dim3(512),dim3(256),0,stream>>>(hv,nullptr,nullptr,
      nullptr,nullptr,nullptr,BOOST, BIHW_F,BIHW_B,0, BIHB_F,BIHB_B,nullptr,nullptr,0,
      nullptr,nullptr, nullptr,gif,gib, dflag, 128,HD,384,0);
  k_gru<<<dim3(128,2),dim3(384),0,stream>>>(gif, gib, wbgf, wbgb, oseq, zbuf, 1);

  // proj + recompute hx + final merge
  k_dense<A_B16,E_LN_RELU_TANH,2,1><<<dim3(512),dim3(256),0,stream>>>(oseq,nullptr,nullptr,
      nullptr,nullptr,nullptr,nullptr, PW,nullptr,0, PB,nullptr,PG,PBt,0, nullptr,nullptr,
      hv2,nullptr,nullptr, dflag, 256,256,HD,0);
  k_dense<A_XF,E_LN,2,1><<<dim3(512),dim3(256),0,stream>>>(X,nullptr,nullptr,
      nullptr,nullptr,nullptr,nullptr, LW,nullptr,0, LB,nullptr,LGa,LBt,0, nullptr,nullptr,
      hx2,nullptr,nullptr, dflag, 133,133,HD,0);
  k_dense<A_C3,E_LN_RELU,3,1><<<dim3(512),dim3(256),0,stream>>>(hv2,mfin,hx2,
      nullptr,nullptr,nullptr,nullptr, FW,nullptr,0, FB,nullptr,FG,FBt,0, nullptr,nullptr,
      fout,nullptr,nullptr, dflag, 384,HD,HD,0);

  // readout GRU gates (ONE launch, 6 segments) + GRU
  k_dense<A_F32,E_GI,1,6><<<dim3(512),dim3(256),0,stream>>>(fout,nullptr,nullptr,
      nullptr,nullptr,nullptr,nullptr, RIHW_F,RIHW_B,0, RIHB_F,RIHB_B,nullptr,nullptr,0,
      nullptr,nullptr, nullptr,gif_r,gib_r, dflag, 128,HD,384,0);
  k_gru<<<dim3(128,2),dim3(384),0,stream>>>(gif_r, gib_r, wrgf, wrgb, oseq, zbuf, 0);

  // BN + prediction
  k_bnstats<<<dim3(1),dim3(256),0,stream>>>(zbuf, BNG, BNB, stats, dflag);
  k_pred<<<dim3(2),dim3(256),0,stream>>>(zbuf, stats, PRW, PRB, (float*)d_out, dflag);

  (void)in_sizes; (void)n_in; (void)out_size; (void)ws_size;
}

// Round 8
// 2622.642 us; speedup vs baseline: 1.5362x; 1.0150x over previous
//
#include <hip/hip_runtime.h>
#include <hip/hip_bf16.h>

typedef unsigned short u16;
typedef unsigned int   u32;

#define NN    32768
#define NG    512
#define TSEQ  64
#define NE    131072
#define NP    65536
#define HD    128

__device__ __forceinline__ float bf2f(u16 v){ u32 u=((u32)v)<<16; float f; __builtin_memcpy(&f,&u,4); return f; }
__device__ __forceinline__ u16 f2bf(float f){ u32 u; __builtin_memcpy(&u,&f,4); u32 r=u+0x7fffu+((u>>16)&1u); return (u16)(r>>16); }
__device__ __forceinline__ float sigm(float x){ return 1.f/(1.f+__expf(-x)); }
__device__ __forceinline__ float tanhfast(float x){ return 1.f-2.f/(1.f+__expf(2.f*x)); }
// raw-input read: dt=1 -> bf16, dt=0 -> fp32
__device__ __forceinline__ float rg(const void* p, size_t i, int dt){
  return dt ? bf2f(((const u16*)p)[i]) : ((const float*)p)[i];
}

// A-source modes / epilogues
enum { A_XF, A_F32, A_B16, A_MSG, A_C3, A_EDGE, A_BOOST };
enum { E_LN_RELU, E_LN, E_LN_RELU_TANH, E_RESID_LN, E_HE0_RELU, E_GI, E_LN_RELU_DUAL };

// ===== MEASURED-CONFIG LEDGER (do not re-try losers) =====
// dense: 32-k W single-buffer SYNC stage = the proven core (r4/r7 ~2.65ms).
//   - reg double-buffer W (r5 lambda): -1.0ms REGRESSION (codegen blowup).
//   - raw-bit uint4 pipelined W (r6): -0.5ms REGRESSION.
//   => source-level W pipelining is CLOSED. This round: amortize instead
//      (128-row tiles, register epilogues). GI keeps 64-row/128-k geometry
//      (A must stay LDS-resident across the 6 weight segments).
// k_gru: 4 graphs/block, grid(128,2), launch_bounds(384,1) = BEST (318us).
//   - (384,3): VGPR 84 -> wreg spill -> 780us (r3).
//   - next-step gi prefetch: VGPR overflow -> spill -> 490us (r5).
// =========================================================

// Register-tiled fp32 GEMM core.
//  non-GI: 128x128 output tile, 8x8 acc/thread, A in 64-k chunks
//          (sa[128][68] 34KB + wb[32][128] 16KB ~= 52KB -> 3 blocks/CU),
//          register epilogues (LN stats via 16-lane shfl_xor butterfly
//          — the 16 threads of a row-group are contiguous lanes).
//  GI:     64x128 tile, 4x8 acc, A fully LDS-resident (64x132) across
//          NSEG=6 weight segments (measured r4 config).
// fp32 FMA in ascending k-order (GEMM sums bit-identical to r7).
template<int AM, int EP, int NCH, int NSEG>
__launch_bounds__(256)
__global__ void k_dense(
    const void* a0v, const void* a1v, const void* a2v,
    const int* dsti, const int* ptr, const int* cidx, const void* abias,
    const void* W, const void* W2, int wbase,
    const void* bias, const void* bias2, const void* gamma, const void* beta, int prmoff,
    const float* resid, const u16* he0b,
    float* outf, u16* outb, u16* outb2, const int* dflag,
    int ktot, int astride, int ostride, int ocoff)
{
  constexpr bool GI = (EP==E_GI);
  constexpr int NR  = GI ? 64 : 128;    // output rows per block
  constexpr int KC  = GI ? 128 : 64;    // A k-chunk width
  constexpr int STR = KC + 4;           // sa row stride (132 / 68), 16B-aligned
  constexpr int MR  = NR/16;            // acc rows per thread (4 / 8)

  __shared__ __align__(16) float sa[NR*STR];   // A tile (33792 / 34816 B)
  __shared__ __align__(16) float wb[32*128];   // W sub-chunk [k][c], 16 KB
  __shared__ int s_e[NR], s_pe[NR], s_d[NR];
  __shared__ float s_ab[128];

  const int dt  = *dflag;
  const int tid = threadIdx.x;
  const int bx  = blockIdx.x;

  if constexpr (AM==A_EDGE){
    if (tid < NR){
      int eb = bx*(NR/2);
      int e  = (tid<NR/2) ? (eb+tid) : (NP + eb + tid - NR/2);
      s_e[tid]  = e;
      s_pe[tid] = (tid<NR/2) ? (e+NP) : (e-NP);
      s_d[tid]  = dsti[e];
    }
    __syncthreads();
  }
  if constexpr (AM==A_BOOST){
    if (tid < 128) s_ab[tid] = rg(abias, tid, dt);
    __syncthreads();
  }
  const int rbase = (AM==A_EDGE) ? 0 : bx*NR;

  const int ryb = (tid>>4)*MR;          // rows ryb..ryb+MR-1
  const int cxx = (tid&15)*4;           // cols cxx..+3 and 64+cxx..+3

  float acc[MR][8];

  for (int seg=0; seg<NSEG; ++seg){
    #pragma unroll
    for (int i=0;i<MR;i++)
      #pragma unroll
      for (int j=0;j<8;j++) acc[i][j]=0.f;

    const int wb_seg = (NSEG==6) ? (seg%3)*(ktot*HD) : wbase;
    const void* Wt   = (NSEG==6 && seg>=3) ? W2 : W;
    const bool wvec = ((ktot&3)==0) && ((wb_seg&3)==0);

    for (int ch=0; ch<NCH; ++ch){
      int klim = ktot - ch*KC; if (klim > KC) klim = KC;

      if (seg==0){
        // ---- stage NRxKC fp32 A-chunk ----
        if constexpr (AM==A_XF){
          for (int idx=tid; idx<NR*KC; idx+=256){
            int r = idx/KC, lk = idx%KC, k = ch*KC + lk;
            float v = 0.f;
            if (k < ktot) v = rg(a0v, (size_t)(rbase+r)*astride + k, dt);
            sa[r*STR + lk] = v;
          }
        }
        if constexpr (AM==A_F32){
          for (int idx=tid; idx<NR*(KC/4); idx+=256){
            int r = idx/(KC/4), c4 = (idx%(KC/4))*4;
            float4 v = *(const float4*)((const float*)a0v + (size_t)(rbase+r)*astride + ch*KC + c4);
            *(float4*)&sa[r*STR + c4] = v;
          }
        }
        if constexpr (AM==A_B16){
          for (int idx=tid; idx<NR*(KC/4); idx+=256){
            int r = idx/(KC/4), c4 = (idx%(KC/4))*4;
            ushort4 u = *(const ushort4*)((const u16*)a0v + (size_t)(rbase+r)*astride + ch*KC + c4);
            *(float4*)&sa[r*STR + c4] = make_float4(bf2f(u.x),bf2f(u.y),bf2f(u.z),bf2f(u.w));
          }
        }
        if constexpr (AM==A_C3){
          const float* src = (ch<2)?(const float*)a0v:(ch<4)?(const float*)a1v:(const float*)a2v;
          const int coloff = (ch&1)*64;
          for (int idx=tid; idx<NR*(KC/4); idx+=256){
            int r = idx/(KC/4), c4 = (idx%(KC/4))*4;
            float4 v = *(const float4*)(src + (size_t)(rbase+r)*HD + coloff + c4);
            *(float4*)&sa[r*STR + c4] = v;
          }
        }
        if constexpr (AM==A_BOOST){
          for (int idx=tid; idx<NR*(KC/4); idx+=256){
            int r = idx/(KC/4), c4 = (idx%(KC/4))*4;
            float4 v = *(const float4*)((const float*)a0v + (size_t)(rbase+r)*HD + c4);
            v.x = fmaxf(v.x + s_ab[c4+0], 0.f);
            v.y = fmaxf(v.y + s_ab[c4+1], 0.f);
            v.z = fmaxf(v.z + s_ab[c4+2], 0.f);
            v.w = fmaxf(v.w + s_ab[c4+3], 0.f);
            *(float4*)&sa[r*STR + c4] = v;
          }
        }
        if constexpr (AM==A_EDGE){
          for (int idx=tid; idx<NR*(KC/4); idx+=256){
            int r = idx/(KC/4), c4 = (idx%(KC/4))*4;
            float4 va = *(const float4*)((const float*)a0v + (size_t)s_d[r]*HD + ch*KC + c4);
            float4 vb = *(const float4*)((const float*)a1v + (size_t)s_pe[r]*HD + ch*KC + c4);
            *(float4*)&sa[r*STR + c4] = make_float4(va.x-vb.x, va.y-vb.y, va.z-vb.z, va.w-vb.w);
          }
        }
        if constexpr (AM==A_MSG){
          if (ch < 2){
            for (int idx=tid; idx<NR*(KC/4); idx+=256){
              int r = idx/(KC/4), c4 = (idx%(KC/4))*4;
              float4 v = *(const float4*)((const float*)a0v + (size_t)(rbase+r)*HD + ch*KC + c4);
              *(float4*)&sa[r*STR + c4] = v;
            }
          } else {
            for (int idx=tid; idx<NR*KC; idx+=256){
              int r = idx/KC, lk = idx%KC;
              int cc = (ch-2)*KC + lk;
              int node = rbase+r;
              int b = ptr[node], en = ptr[node+1];
              float s=0.f, m=0.f;
              for (int i=b;i<en;++i){
                float t = ((const float*)a1v)[(size_t)cidx[i]*HD + cc];
                s += t; m = fmaxf(m,t);
              }
              sa[r*STR + lk] = s*m;   // m_sum * relu(segment_max); he>=0
            }
          }
        }
      }

      for (int kk=0; kk<klim; kk+=32){
        // ---- stage W sub-chunk [32 k][128 c]; thread: c=tid>>1, k-half=(tid&1)*16 ----
        {
          int c = tid>>1, kh = (tid&1)*16;
          size_t wrow = (size_t)wb_seg + (size_t)c*ktot + (size_t)ch*KC + kk;
          if (wvec && dt==0){
            const float* Wf = (const float*)Wt;
            #pragma unroll
            for (int j4=0;j4<4;j4++){
              int kq = kh + j4*4;
              float v0=0.f,v1=0.f,v2=0.f,v3=0.f;
              if (kk+kq+4 <= klim){
                float4 v = *(const float4*)(Wf + wrow + kq);
                v0=v.x; v1=v.y; v2=v.z; v3=v.w;
              } else if (kk+kq < klim){
                v0 = Wf[wrow+kq];
                if (kk+kq+1<klim) v1 = Wf[wrow+kq+1];
                if (kk+kq+2<klim) v2 = Wf[wrow+kq+2];
              }
              wb[(kq+0)*128+c]=v0; wb[(kq+1)*128+c]=v1; wb[(kq+2)*128+c]=v2; wb[(kq+3)*128+c]=v3;
            }
          } else if (wvec){
            const u16* Wh = (const u16*)Wt;
            #pragma unroll
            for (int j4=0;j4<4;j4++){
              int kq = kh + j4*4;
              float v0=0.f,v1=0.f,v2=0.f,v3=0.f;
              if (kk+kq+4 <= klim){
                ushort4 v = *(const ushort4*)(Wh + wrow + kq);
                v0=bf2f(v.x); v1=bf2f(v.y); v2=bf2f(v.z); v3=bf2f(v.w);
              } else if (kk+kq < klim){
                v0 = bf2f(Wh[wrow+kq]);
                if (kk+kq+1<klim) v1 = bf2f(Wh[wrow+kq+1]);
                if (kk+kq+2<klim) v2 = bf2f(Wh[wrow+kq+2]);
              }
              wb[(kq+0)*128+c]=v0; wb[(kq+1)*128+c]=v1; wb[(kq+2)*128+c]=v2; wb[(kq+3)*128+c]=v3;
            }
          } else {
            for (int j=0;j<16;j++){
              int kq = kh + j;
              wb[kq*128+c] = (kk+kq < klim) ? rg(Wt, wrow+kq, dt) : 0.f;
            }
          }
        }
        __syncthreads();   // sa (if staged this round) + wb ready

        // ---- compute: 32 k's, zero-padded tails contribute 0 ----
        for (int kc=0; kc<32; kc+=4){
          float4 aa[MR];
          #pragma unroll
          for (int i=0;i<MR;i++)
            aa[i] = *(const float4*)&sa[(ryb+i)*STR + kk + kc];
          #pragma unroll
          for (int t=0;t<4;t++){
            float4 b0 = *(const float4*)&wb[(kc+t)*128 + cxx];
            float4 b1 = *(const float4*)&wb[(kc+t)*128 + 64 + cxx];
            #pragma unroll
            for (int i=0;i<MR;i++){
              float a = (t==0)?aa[i].x:(t==1)?aa[i].y:(t==2)?aa[i].z:aa[i].w;
              acc[i][0]+=a*b0.x; acc[i][1]+=a*b0.y; acc[i][2]+=a*b0.z; acc[i][3]+=a*b0.w;
              acc[i][4]+=a*b1.x; acc[i][5]+=a*b1.y; acc[i][6]+=a*b1.z; acc[i][7]+=a*b1.w;
            }
          }
        }
        __syncthreads();   // before restaging wb / next A chunk
      }
    }

    if constexpr (EP==E_GI){
      // register epilogue: out = f2bf(acc + bias), packed ushort4 stores
      const void* bsrc = (NSEG==6 && seg>=3) ? bias2 : bias;
      const int   po   = (NSEG==6) ? (seg%3)*HD : prmoff;
      u16*        op   = (NSEG==6) ? (seg<3 ? outb : outb2) : outb;
      const int   oc   = (NSEG==6) ? (seg%3)*HD : ocoff;
      float b0[4], b1[4];
      #pragma unroll
      for (int j=0;j<4;j++){
        b0[j] = rg(bsrc, po + cxx + j, dt);
        b1[j] = rg(bsrc, po + 64 + cxx + j, dt);
      }
      #pragma unroll
      for (int i=0;i<MR;i++){
        size_t gr = (size_t)(rbase + ryb + i);
        ushort4 u0, u1;
        u0.x=f2bf(acc[i][0]+b0[0]); u0.y=f2bf(acc[i][1]+b0[1]);
        u0.z=f2bf(acc[i][2]+b0[2]); u0.w=f2bf(acc[i][3]+b0[3]);
        u1.x=f2bf(acc[i][4]+b1[0]); u1.y=f2bf(acc[i][5]+b1[1]);
        u1.z=f2bf(acc[i][6]+b1[2]); u1.w=f2bf(acc[i][7]+b1[3]);
        *(ushort4*)&op[gr*ostride + oc + cxx]      = u0;
        *(ushort4*)&op[gr*ostride + oc + 64 + cxx] = u1;
      }
    }
  }

  if constexpr (EP==E_GI) return;

  // ================= register epilogues (no LDS C round-trip) =================
  if constexpr (EP==E_HE0_RELU){
    float b0[4], b1[4];
    #pragma unroll
    for (int j=0;j<4;j++){
      b0[j] = rg(bias, prmoff + cxx + j, dt);
      b1[j] = rg(bias, prmoff + 64 + cxx + j, dt);
    }
    #pragma unroll
    for (int i=0;i<MR;i++){
      int e = s_e[ryb+i];
      ushort4 h0 = *(const ushort4*)&he0b[(size_t)e*HD + cxx];
      ushort4 h1 = *(const ushort4*)&he0b[(size_t)e*HD + 64 + cxx];
      float4 o0, o1;
      o0.x = fmaxf(acc[i][0]+b0[0]+bf2f(h0.x), 0.f);
      o0.y = fmaxf(acc[i][1]+b0[1]+bf2f(h0.y), 0.f);
      o0.z = fmaxf(acc[i][2]+b0[2]+bf2f(h0.z), 0.f);
      o0.w = fmaxf(acc[i][3]+b0[3]+bf2f(h0.w), 0.f);
      o1.x = fmaxf(acc[i][4]+b1[0]+bf2f(h1.x), 0.f);
      o1.y = fmaxf(acc[i][5]+b1[1]+bf2f(h1.y), 0.f);
      o1.z = fmaxf(acc[i][6]+b1[2]+bf2f(h1.z), 0.f);
      o1.w = fmaxf(acc[i][7]+b1[3]+bf2f(h1.w), 0.f);
      *(float4*)&outf[(size_t)e*HD + cxx]      = o0;
      *(float4*)&outf[(size_t)e*HD + 64 + cxx] = o1;
    }
    return;
  }
  // LayerNorm family: bias/resid folded into acc, row stats via 16-lane
  // shfl_xor butterfly (row-group threads are contiguous lanes).
  {
    float bc[8], gc[8], tc[8];
    #pragma unroll
    for (int j=0;j<4;j++){
      bc[j]   = rg(bias,  prmoff + cxx + j,      dt);
      bc[4+j] = rg(bias,  prmoff + 64 + cxx + j, dt);
      gc[j]   = rg(gamma, prmoff + cxx + j,      dt);
      gc[4+j] = rg(gamma, prmoff + 64 + cxx + j, dt);
      tc[j]   = rg(beta,  prmoff + cxx + j,      dt);
      tc[4+j] = rg(beta,  prmoff + 64 + cxx + j, dt);
    }
    #pragma unroll
    for (int i=0;i<MR;i++){
      size_t grow = (size_t)(rbase + ryb + i);
      if constexpr (EP==E_RESID_LN){
        float4 r0 = *(const float4*)&resid[grow*HD + cxx];
        float4 r1 = *(const float4*)&resid[grow*HD + 64 + cxx];
        acc[i][0] = r0.x + fmaxf(acc[i][0]+bc[0], 0.f);
        acc[i][1] = r0.y + fmaxf(acc[i][1]+bc[1], 0.f);
        acc[i][2] = r0.z + fmaxf(acc[i][2]+bc[2], 0.f);
        acc[i][3] = r0.w + fmaxf(acc[i][3]+bc[3], 0.f);
        acc[i][4] = r1.x + fmaxf(acc[i][4]+bc[4], 0.f);
        acc[i][5] = r1.y + fmaxf(acc[i][5]+bc[5], 0.f);
        acc[i][6] = r1.z + fmaxf(acc[i][6]+bc[6], 0.f);
        acc[i][7] = r1.w + fmaxf(acc[i][7]+bc[7], 0.f);
      } else {
        #pragma unroll
        for (int j=0;j<8;j++) acc[i][j] += bc[j];
      }
      float sm=0.f, sq=0.f;
      #pragma unroll
      for (int j=0;j<8;j++){ sm += acc[i][j]; sq += acc[i][j]*acc[i][j]; }
      sm += __shfl_xor(sm,1); sq += __shfl_xor(sq,1);
      sm += __shfl_xor(sm,2); sq += __shfl_xor(sq,2);
      sm += __shfl_xor(sm,4); sq += __shfl_xor(sq,4);
      sm += __shfl_xor(sm,8); sq += __shfl_xor(sq,8);
      float mu  = sm*(1.f/128.f);
      float var = sq*(1.f/128.f) - mu*mu;
      float rs  = rsqrtf(fmaxf(var,0.f)+1e-5f);
      float y[8];
      #pragma unroll
      for (int j=0;j<8;j++){
        float v = (acc[i][j]-mu)*rs*gc[j] + tc[j];
        if constexpr (EP==E_LN_RELU || EP==E_LN_RELU_DUAL) v = fmaxf(v,0.f);
        if constexpr (EP==E_LN_RELU_TANH) v = tanhfast(fmaxf(v,0.f));
        y[j] = v;
      }
      *(float4*)&outf[grow*HD + cxx]      = make_float4(y[0],y[1],y[2],y[3]);
      *(float4*)&outf[grow*HD + 64 + cxx] = make_float4(y[4],y[5],y[6],y[7]);
      if constexpr (EP==E_LN_RELU_DUAL){
        ushort4 u0, u1;
        u0.x=f2bf(y[0]); u0.y=f2bf(y[1]); u0.z=f2bf(y[2]); u0.w=f2bf(y[3]);
        u1.x=f2bf(y[4]); u1.y=f2bf(y[5]); u1.z=f2bf(y[6]); u1.w=f2bf(y[7]);
        *(ushort4*)&outb[grow*HD + cxx]      = u0;
        *(ushort4*)&outb[grow*HD + 64 + cxx] = u1;
      }
    }
  }
}

// merged weight pre-convert: 4 (whh,bhh) pairs raw -> fp32 [49152|384] blocks
__global__ void k_cvt4(const void* w0,const void* b0,const void* w1,const void* b1,
                       const void* w2,const void* b2,const void* w3,const void* b3,
                       float* d0, float* d1, float* d2, float* d3, const int* dflag){
  int dt = *dflag;
  int p  = blockIdx.y;
  const void* wsrc = (p==0)?w0:(p==1)?w1:(p==2)?w2:w3;
  const void* bsrc = (p==0)?b0:(p==1)?b1:(p==2)?b2:b3;
  float* dst       = (p==0)?d0:(p==1)?d1:(p==2)?d2:d3;
  int i = blockIdx.x*256 + threadIdx.x;
  if (i < 49152)      dst[i] = rg(wsrc, i, dt);
  else if (i < 49536) dst[i] = rg(bsrc, i-49152, dt);
}

// BiGRU, W-in-registers (EXACT r6-measured 318us config — do not touch):
// one block = 4 graphs x one dir (grid 128x2); 384 threads; thread owns
// gate-row d=tid and keeps its whh row (32 float4) in registers for all 64
// steps. launch_bounds(384,1): VGPR 128, no spill (ledger: min-waves=3 and
// next-step prefetch both spill). Same-step gi prefetch only. sgh stride 5
// (gcd(5,32)=1): conflict-free cell reads. fp32 FMA, same k-order.
__launch_bounds__(384,1)
__global__ void k_gru(
  const u16* gi_f, const u16* gi_b,
  const float* wcf, const float* wcb,
  u16* out_seq, float* zbuf, int write_seq)
{
  const int dir = blockIdx.y;
  const int g0  = blockIdx.x * 4;
  const u16* gi  = dir ? gi_b : gi_f;
  const float* whh = dir ? wcb : wcf;
  const float* bh  = whh + 49152;

  __shared__ float sgh[384*5];               // [row d][graph g], stride 5
  __shared__ __align__(16) float sh[4*128];  // h state [g][d]

  const int tid = threadIdx.x;   // 0..383, owns gate-row d=tid

  // load W row into registers (once)
  float4 wreg[32];
  {
    const float4* wrow = (const float4*)(whh + (size_t)tid*128);
    #pragma unroll
    for (int i=0;i<32;i++) wreg[i] = wrow[i];
  }
  const float bhd = bh[tid];

  // cell-phase ownership: item A = tid (g=tid>>7 in {0,1,2}, d=tid&127);
  // item B = 384+tid for tid<128 (g=3, d=tid)
  const int gA = tid>>7, dA = tid&127;

  for (int i=tid;i<512;i+=384) sh[i]=0.f;
  __syncthreads();

  for (int step=0; step<64; ++step){
    const int t = dir ? (63-step) : step;

    // ---- prefetch gi for this step's cell items (independent of LDS) ----
    const u16* gpA = gi + (size_t)((g0+gA)*TSEQ + t)*384;
    u16 aR = gpA[dA], aZ = gpA[128+dA], aN = gpA[256+dA];
    u16 bR=0, bZ=0, bN=0;
    if (tid < 128){
      const u16* gpB = gi + (size_t)((g0+3)*TSEQ + t)*384;
      bR = gpB[tid]; bZ = gpB[128+tid]; bN = gpB[256+tid];
    }

    // ---- GEMV: gh[d][g] = whh[d]·h[g] + bh[d], W from registers ----
    float a0=0.f, a1=0.f, a2=0.f, a3=0.f;
    #pragma unroll
    for (int k4=0; k4<32; k4++){
      float4 w  = wreg[k4];
      float4 h0 = *(const float4*)&sh[0*128 + k4*4];
      float4 h1 = *(const float4*)&sh[1*128 + k4*4];
      float4 h2 = *(const float4*)&sh[2*128 + k4*4];
      float4 h3 = *(const float4*)&sh[3*128 + k4*4];
      a0 += h0.x*w.x + h0.y*w.y + h0.z*w.z + h0.w*w.w;
      a1 += h1.x*w.x + h1.y*w.y + h1.z*w.z + h1.w*w.w;
      a2 += h2.x*w.x + h2.y*w.y + h2.z*w.z + h2.w*w.w;
      a3 += h3.x*w.x + h3.y*w.y + h3.z*w.z + h3.w*w.w;
    }
    sgh[tid*5+0] = a0 + bhd;
    sgh[tid*5+1] = a1 + bhd;
    sgh[tid*5+2] = a2 + bhd;
    sgh[tid*5+3] = a3 + bhd;
    __syncthreads();

    // ---- cell update ----
    {
      float r = sigm(bf2f(aR) + sgh[dA*5+gA]);
      float z = sigm(bf2f(aZ) + sgh[(128+dA)*5+gA]);
      float n = tanhfast(bf2f(aN) + r*sgh[(256+dA)*5+gA]);
      float h = (1.f-z)*n + z*sh[gA*128+dA];
      sh[gA*128+dA] = h;
      if (write_seq){
        float hc = fminf(fmaxf(h,-10.f),10.f);
        out_seq[(size_t)((g0+gA)*TSEQ + t)*256 + dir*HD + dA] = f2bf(hc);
      }
    }
    if (tid < 128){
      float r = sigm(bf2f(bR) + sgh[tid*5+3]);
      float z = sigm(bf2f(bZ) + sgh[(128+tid)*5+3]);
      float n = tanhfast(bf2f(bN) + r*sgh[(256+tid)*5+3]);
      float h = (1.f-z)*n + z*sh[3*128+tid];
      sh[3*128+tid] = h;
      if (write_seq){
        float hc = fminf(fmaxf(h,-10.f),10.f);
        out_seq[(size_t)((g0+3)*TSEQ + t)*256 + dir*HD + tid] = f2bf(hc);
      }
    }
    __syncthreads();
  }

  if (!write_seq){
    for (int i=tid;i<512;i+=384){
      int g=i>>7, d=i&127;
      zbuf[(size_t)(g0+g)*256 + dir*HD + d] = fminf(fmaxf(sh[g*128+d],-10.f),10.f);
    }
  }
}

__launch_bounds__(64)
__global__ void k_gather(const float* he, const int* ptr, const int* cidx, float* out){
  int n = blockIdx.x;
  int c = threadIdx.x;
  int b = ptr[n], e = ptr[n+1];
  float s0=0.f,s1=0.f;
  for (int i=b;i<e;++i){
    int eid = cidx[i];
    float2 v = *(const float2*)(he + (size_t)eid*HD + c*2);
    s0+=v.x; s1+=v.y;
  }
  out[(size_t)n*HD + c*2]   = s0;
  out[(size_t)n*HD + c*2+1] = s1;
}

__global__ void k_count(const int* dst, int* cnt){
  int e = blockIdx.x*256+threadIdx.x;
  if (e<NE) atomicAdd(&cnt[dst[e]],1);
}

__launch_bounds__(1024)
__global__ void k_scan(const int* cnt, int* ptr){
  __shared__ int s[1024];
  int tid=threadIdx.x;
  int loc[32]; int tot=0;
  int base = tid*32;
  #pragma unroll
  for (int i=0;i<32;i++){ loc[i]=tot; tot += cnt[base+i]; }
  s[tid]=tot; __syncthreads();
  for (int off=1; off<1024; off<<=1){
    int v = (tid>=off)? s[tid-off] : 0;
    __syncthreads();
    s[tid] += v;
    __syncthreads();
  }
  int ex = s[tid] - tot;
  for (int i=0;i<32;i++) ptr[base+i] = ex + loc[i];
  if (tid==1023) ptr[NN] = ex + tot;
}

__global__ void k_fill(const int* dst, const int* ptr, int* cur, int* cidx){
  int e = blockIdx.x*256+threadIdx.x;
  if (e<NE){
    int d = dst[e];
    int p = ptr[d] + atomicAdd(&cur[d],1);
    cidx[p] = e;
  }
}

// runtime input-dtype detector (fp32 low-halfword exponents ~uniform; bf16 ~always in-range)
__global__ void k_detect(const u16* x, int* flag){
  __shared__ int cnt;
  if (threadIdx.x==0) cnt=0;
  __syncthreads();
  u16 u = x[threadIdx.x*2];
  int e = (u>>7)&0xff;
  if (e>=100 && e<=135) atomicAdd(&cnt,1);
  __syncthreads();
  if (threadIdx.x==0) *flag = (cnt>=128) ? 1 : 0;
}

__launch_bounds__(256)
__global__ void k_bnstats(const float* z, const void* bng, const void* bnb, float* st, const int* dflag){
  int dt = *dflag;
  int c = threadIdx.x;
  float sm=0.f, sq=0.f;
  for (int g=0; g<NG; ++g){ float v = z[(size_t)g*256+c]; sm+=v; sq+=v*v; }
  float mu = sm*(1.f/(float)NG);
  float var = sq*(1.f/(float)NG) - mu*mu;
  float rs = rsqrtf(fmaxf(var,0.f)+1e-5f);
  float sc = rs*rg(bng,c,dt);
  st[c] = sc;
  st[256+c] = rg(bnb,c,dt) - mu*sc;
}

// OUTPUT fp32 (confirmed by r8: finite ref-scale error under fp32 writes)
__global__ void k_pred(const float* z, const float* st, const void* pw, const void* pb, float* out, const int* dflag){
  int dt = *dflag;
  int g = blockIdx.x*256+threadIdx.x;
  if (g>=NG) return;
  float acc = rg(pb,0,dt);
  for (int c=0;c<256;c++) acc += (z[(size_t)g*256+c]*st[c] + st[256+c])*rg(pw,c,dt);
  out[g]=acc;
}

extern "C" void kernel_launch(void* const* d_in, const int* in_sizes, int n_in,
                              void* d_out, int out_size, void* d_ws, size_t ws_size,
                              hipStream_t stream)
{
  const void* X    =d_in[0];
  const void* EA   =d_in[1];
  const void* NW   =d_in[2];
  const void* NB   =d_in[3];
  const void* NGa  =d_in[4];
  const void* NBt  =d_in[5];
  const void* EW   =d_in[6];
  const void* EB   =d_in[7];
  const void* EGa  =d_in[8];
  const void* EBt  =d_in[9];
  const void* LW   =d_in[10];
  const void* LB   =d_in[11];
  const void* LGa  =d_in[12];
  const void* LBt  =d_in[13];
  const void* NUW  =d_in[14];
  const void* NUB  =d_in[15];
  const void* NNG  =d_in[16];
  const void* NNB  =d_in[17];
  const void* EUW  =d_in[18];
  const void* EUB  =d_in[19];
  const void* BOOST=d_in[20];
  const void* BIHW_F=d_in[21];
  const void* BHHW_F=d_in[22];
  const void* BIHB_F=d_in[23];
  const void* BHHB_F=d_in[24];
  const void* BIHW_B=d_in[25];
  const void* BHHW_B=d_in[26];
  const void* BIHB_B=d_in[27];
  const void* BHHB_B=d_in[28];
  const void* PW   =d_in[29];
  const void* PB   =d_in[30];
  const void* PG   =d_in[31];
  const void* PBt  =d_in[32];
  const void* FW   =d_in[33];
  const void* FB   =d_in[34];
  const void* FG   =d_in[35];
  const void* FBt  =d_in[36];
  const void* RIHW_F=d_in[37];
  const void* RHHW_F=d_in[38];
  const void* RIHB_F=d_in[39];
  const void* RHHB_F=d_in[40];
  const void* RIHW_B=d_in[41];
  const void* RHHW_B=d_in[42];
  const void* RIHB_B=d_in[43];
  const void* RHHB_B=d_in[44];
  const void* BNG  =d_in[45];
  const void* BNB  =d_in[46];
  const void* PRW  =d_in[47];
  const void* PRB  =d_in[48];
  const int* EIDX =(const int*)d_in[49];
  const int* DST  = EIDX + NE;

  // ---- Workspace (same map as before; fp32 GRU weights in 2MB..3MB gap) ----
  char* ws=(char*)d_ws;
  const size_t MB = 1048576;
  int*   csrp =(int*)  (ws + 0);
  int*   csrc =(int*)  (ws + 135168);
  int*   csri =(int*)  (ws + 266240);
  float* zbuf =(float*)(ws + 790528);
  float* stats=(float*)(ws + 1314816);
  int*   dflag=(int*)  (ws + 1316864);
  float* wbgf =(float*)(ws + 2*MB);          // [49152 whh | 384 bhh] fp32, boost fwd
  float* wbgb = wbgf + 49536;                // boost bwd
  float* wrgf = wbgb + 49536;                // readout fwd
  float* wrgb = wrgf + 49536;                // readout bwd
  float* hv   =(float*)(ws + 6*MB);
  u16*   he0  =(u16*)  (ws + 22*MB);
  float* he   =(float*)(ws + 54*MB);
  float* mfin =(float*)(ws + 22*MB);
  u16*   gif  =(u16*)  (ws + 54*MB);
  u16*   gib  =(u16*)  (ws + 78*MB);
  u16*   oseq =(u16*)  (ws + 6*MB);
  float* hv2  =(float*)(ws + 38*MB);
  float* hx2  =(float*)(ws + 6*MB);
  float* fout =(float*)(ws + 54*MB);
  u16*   gif_r=(u16*)  (ws + 70*MB);
  u16*   gib_r=(u16*)  (ws + 94*MB);

  k_detect<<<dim3(1),dim3(256),0,stream>>>((const u16*)X, dflag);

  // pre-convert recurrent GRU weights to fp32 (one merged launch)
  k_cvt4<<<dim3(194,4),dim3(256),0,stream>>>(
      BHHW_F,BHHB_F, BHHW_B,BHHB_B, RHHW_F,RHHB_F, RHHW_B,RHHB_B,
      wbgf, wbgb, wrgf, wrgb, dflag);

  // CSR over dst
  hipMemsetAsync(csrc, 0, 131072, stream);
  k_count<<<dim3(512),dim3(256),0,stream>>>(DST, csrc);
  k_scan<<<dim3(1),dim3(1024),0,stream>>>(csrc, csrp);
  hipMemsetAsync(csrc, 0, 131072, stream);
  k_fill<<<dim3(512),dim3(256),0,stream>>>(DST, csrp, csrc, csri);

  // init embeddings (128-row tiles)
  k_dense<A_XF,E_LN_RELU,3,1><<<dim3(256),dim3(256),0,stream>>>(X,nullptr,nullptr,
      nullptr,nullptr,nullptr,nullptr, NW,nullptr,0, NB,nullptr,NGa,NBt,0, nullptr,nullptr,
      hv,nullptr,nullptr, dflag, 133,133,HD,0);
  k_dense<A_XF,E_LN_RELU_DUAL,1,1><<<dim3(1024),dim3(256),0,stream>>>(EA,nullptr,nullptr,
      nullptr,nullptr,nullptr,nullptr, EW,nullptr,0, EB,nullptr,EGa,EBt,0, nullptr,nullptr,
      he,he0,nullptr, dflag, 14,14,HD,0);

  // message passing
  for (int s=0;s<5;s++){
    k_dense<A_MSG,E_RESID_LN,4,1><<<dim3(256),dim3(256),0,stream>>>(hv,he,nullptr,
        nullptr,csrp,csri,nullptr, NUW,nullptr,s*32768, NUB,nullptr,NNG,NNB,s*128,
        hv,nullptr, hv,nullptr,nullptr, dflag, 256,HD,HD,0);
    k_dense<A_EDGE,E_HE0_RELU,2,1><<<dim3(1024),dim3(256),0,stream>>>(hv,he,nullptr,
        DST,nullptr,nullptr,nullptr, EUW,nullptr,s*16384, EUB,nullptr,nullptr,nullptr,s*128,
        nullptr,he0, he,nullptr,nullptr, dflag, 128,HD,HD,0);
  }
  k_gather<<<dim3(NN),dim3(64),0,stream>>>(he, csrp, csri, mfin);

  // boost GRU input-side gates: ONE launch, 6 weight segments (F0-2,B0-2)
  k_dense<A_BOOST,E_GI,1,6><<<dim3(512),dim3(256),0,stream>>>(hv,nullptr,nullptr,
      nullptr,nullptr,nullptr,BOOST, BIHW_F,BIHW_B,0, BIHB_F,BIHB_B,nullptr,nullptr,0,
      nullptr,nullptr, nullptr,gif,gib, dflag, 128,HD,384,0);
  k_gru<<<dim3(128,2),dim3(384),0,stream>>>(gif, gib, wbgf, wbgb, oseq, zbuf, 1);

  // proj + recompute hx + final merge (128-row tiles)
  k_dense<A_B16,E_LN_RELU_TANH,4,1><<<dim3(256),dim3(256),0,stream>>>(oseq,nullptr,nullptr,
      nullptr,nullptr,nullptr,nullptr, PW,nullptr,0, PB,nullptr,PG,PBt,0, nullptr,nullptr,
      hv2,nullptr,nullptr, dflag, 256,256,HD,0);
  k_dense<A_XF,E_LN,3,1><<<dim3(256),dim3(256),0,stream>>>(X,nullptr,nullptr,
      nullptr,nullptr,nullptr,nullptr, LW,nullptr,0, LB,nullptr,LGa,LBt,0, nullptr,nullptr,
      hx2,nullptr,nullptr, dflag, 133,133,HD,0);
  k_dense<A_C3,E_LN_RELU,6,1><<<dim3(256),dim3(256),0,stream>>>(hv2,mfin,hx2,
      nullptr,nullptr,nullptr,nullptr, FW,nullptr,0, FB,nullptr,FG,FBt,0, nullptr,nullptr,
      fout,nullptr,nullptr, dflag, 384,HD,HD,0);

  // readout GRU gates (ONE launch, 6 segments) + GRU
  k_dense<A_F32,E_GI,1,6><<<dim3(512),dim3(256),0,stream>>>(fout,nullptr,nullptr,
      nullptr,nullptr,nullptr,nullptr, RIHW_F,RIHW_B,0, RIHB_F,RIHB_B,nullptr,nullptr,0,
      nullptr,nullptr, nullptr,gif_r,gib_r, dflag, 128,HD,384,0);
  k_gru<<<dim3(128,2),dim3(384),0,stream>>>(gif_r, gib_r, wrgf, wrgb, oseq, zbuf, 0);

  // BN + prediction
  k_bnstats<<<dim3(1),dim3(256),0,stream>>>(zbuf, BNG, BNB, stats, dflag);
  k_pred<<<dim3(2),dim3(256),0,stream>>>(zbuf, stats, PRW, PRB, (float*)d_out, dflag);

  (void)in_sizes; (void)n_in; (void)out_size; (void)ws_size;
}

// Round 9
// 2126.321 us; speedup vs baseline: 1.8948x; 1.2334x over previous
//
#include <hip/hip_runtime.h>
#include <hip/hip_bf16.h>

typedef unsigned short u16;
typedef unsigned int   u32;

#define NN    32768
#define NG    512
#define TSEQ  64
#define NE    131072
#define NP    65536
#define HD    128

__device__ __forceinline__ float bf2f(u16 v){ u32 u=((u32)v)<<16; float f; __builtin_memcpy(&f,&u,4); return f; }
__device__ __forceinline__ u16 f2bf(float f){ u32 u; __builtin_memcpy(&u,&f,4); u32 r=u+0x7fffu+((u>>16)&1u); return (u16)(r>>16); }
__device__ __forceinline__ float sigm(float x){ return 1.f/(1.f+__expf(-x)); }
__device__ __forceinline__ float tanhfast(float x){ return 1.f-2.f/(1.f+__expf(2.f*x)); }
// raw-input read: dt=1 -> bf16, dt=0 -> fp32
__device__ __forceinline__ float rg(const void* p, size_t i, int dt){
  return dt ? bf2f(((const u16*)p)[i]) : ((const float*)p)[i];
}

// A-source modes / epilogues
enum { A_XF, A_F32, A_B16, A_MSG, A_C3, A_EDGE, A_BOOST };
enum { E_LN_RELU, E_LN, E_LN_RELU_TANH, E_RESID_LN, E_HE0_RELU, E_GI, E_LN_RELU_DUAL };

// ===== MEASURED-CONFIG LEDGER (do not re-try losers) =====
// dense core: 32-k W single-buffer SYNC stage is the proven kernel.
//   - reg double-buffer W (r5): -1.0ms REGRESSION (codegen blowup).
//   - raw-bit uint4 pipelined W (r6): -0.5ms REGRESSION.
//   - 128-row tiles (r8): WASH vs 64-row (amortization gain == TLP loss:
//     node grids fell to 256 blocks = 1 block/CU).
//   => r9 axis: RESIDENCY. LN launches NR=32 (1024+ blocks = 4/CU),
//      edge NR=64/KC=64 (34KB LDS = 4/CU), GI frozen at r4 geometry.
// k_gru: 4 graphs/block, grid(128,2), launch_bounds(384,1) = BEST (318us).
//   - (384,3): VGPR 84 -> wreg spill -> 780us (r3).
//   - next-step gi prefetch: VGPR overflow -> spill -> 490us (r5).
// =========================================================

// Register-tiled fp32 GEMM core.
//  non-GI: NRT x 128 output tile (NRT=32 LN-family / 64 edge), A in 64-k
//          chunks, W in 32-k sub-chunks (16 KB), register epilogues
//          (LN stats via 16-lane shfl_xor butterfly over contiguous lanes).
//  GI:     64x128 tile, KC=128: A fully LDS-resident across NSEG=6 weight
//          segments (measured r4 config, unchanged).
// fp32 FMA in ascending k-order (sums bit-identical across tile geometry).
template<int AM, int EP, int NCH, int NSEG, int NRT>
__launch_bounds__(256)
__global__ void k_dense(
    const void* a0v, const void* a1v, const void* a2v,
    const int* dsti, const int* ptr, const int* cidx, const void* abias,
    const void* W, const void* W2, int wbase,
    const void* bias, const void* bias2, const void* gamma, const void* beta, int prmoff,
    const float* resid, const u16* he0b,
    float* outf, u16* outb, u16* outb2, const int* dflag,
    int ktot, int astride, int ostride, int ocoff)
{
  constexpr bool GI = (EP==E_GI);
  constexpr int NR  = NRT;              // output rows per block
  constexpr int KC  = GI ? 128 : 64;    // A k-chunk width
  constexpr int STR = KC + 4;           // sa row stride, 16B-aligned
  constexpr int MR  = NR/16;            // acc rows per thread

  __shared__ __align__(16) float sa[NR*STR];   // A tile
  __shared__ __align__(16) float wb[32*128];   // W sub-chunk [k][c], 16 KB
  __shared__ int s_e[NR], s_pe[NR], s_d[NR];
  __shared__ float s_ab[128];

  const int dt  = *dflag;
  const int tid = threadIdx.x;
  const int bx  = blockIdx.x;

  if constexpr (AM==A_EDGE){
    if (tid < NR){
      int eb = bx*(NR/2);
      int e  = (tid<NR/2) ? (eb+tid) : (NP + eb + tid - NR/2);
      s_e[tid]  = e;
      s_pe[tid] = (tid<NR/2) ? (e+NP) : (e-NP);
      s_d[tid]  = dsti[e];
    }
    __syncthreads();
  }
  if constexpr (AM==A_BOOST){
    if (tid < 128) s_ab[tid] = rg(abias, tid, dt);
    __syncthreads();
  }
  const int rbase = (AM==A_EDGE) ? 0 : bx*NR;

  const int ryb = (tid>>4)*MR;          // rows ryb..ryb+MR-1
  const int cxx = (tid&15)*4;           // cols cxx..+3 and 64+cxx..+3

  float acc[MR][8];

  for (int seg=0; seg<NSEG; ++seg){
    #pragma unroll
    for (int i=0;i<MR;i++)
      #pragma unroll
      for (int j=0;j<8;j++) acc[i][j]=0.f;

    const int wb_seg = (NSEG==6) ? (seg%3)*(ktot*HD) : wbase;
    const void* Wt   = (NSEG==6 && seg>=3) ? W2 : W;
    const bool wvec = ((ktot&3)==0) && ((wb_seg&3)==0);

    for (int ch=0; ch<NCH; ++ch){
      int klim = ktot - ch*KC; if (klim > KC) klim = KC;

      if (seg==0){
        // ---- stage NRxKC fp32 A-chunk ----
        if constexpr (AM==A_XF){
          for (int idx=tid; idx<NR*KC; idx+=256){
            int r = idx/KC, lk = idx%KC, k = ch*KC + lk;
            float v = 0.f;
            if (k < ktot) v = rg(a0v, (size_t)(rbase+r)*astride + k, dt);
            sa[r*STR + lk] = v;
          }
        }
        if constexpr (AM==A_F32){
          for (int idx=tid; idx<NR*(KC/4); idx+=256){
            int r = idx/(KC/4), c4 = (idx%(KC/4))*4;
            float4 v = *(const float4*)((const float*)a0v + (size_t)(rbase+r)*astride + ch*KC + c4);
            *(float4*)&sa[r*STR + c4] = v;
          }
        }
        if constexpr (AM==A_B16){
          for (int idx=tid; idx<NR*(KC/4); idx+=256){
            int r = idx/(KC/4), c4 = (idx%(KC/4))*4;
            ushort4 u = *(const ushort4*)((const u16*)a0v + (size_t)(rbase+r)*astride + ch*KC + c4);
            *(float4*)&sa[r*STR + c4] = make_float4(bf2f(u.x),bf2f(u.y),bf2f(u.z),bf2f(u.w));
          }
        }
        if constexpr (AM==A_C3){
          const float* src = (ch<2)?(const float*)a0v:(ch<4)?(const float*)a1v:(const float*)a2v;
          const int coloff = (ch&1)*64;
          for (int idx=tid; idx<NR*(KC/4); idx+=256){
            int r = idx/(KC/4), c4 = (idx%(KC/4))*4;
            float4 v = *(const float4*)(src + (size_t)(rbase+r)*HD + coloff + c4);
            *(float4*)&sa[r*STR + c4] = v;
          }
        }
        if constexpr (AM==A_BOOST){
          for (int idx=tid; idx<NR*(KC/4); idx+=256){
            int r = idx/(KC/4), c4 = (idx%(KC/4))*4;
            float4 v = *(const float4*)((const float*)a0v + (size_t)(rbase+r)*HD + c4);
            v.x = fmaxf(v.x + s_ab[c4+0], 0.f);
            v.y = fmaxf(v.y + s_ab[c4+1], 0.f);
            v.z = fmaxf(v.z + s_ab[c4+2], 0.f);
            v.w = fmaxf(v.w + s_ab[c4+3], 0.f);
            *(float4*)&sa[r*STR + c4] = v;
          }
        }
        if constexpr (AM==A_EDGE){
          for (int idx=tid; idx<NR*(KC/4); idx+=256){
            int r = idx/(KC/4), c4 = (idx%(KC/4))*4;
            float4 va = *(const float4*)((const float*)a0v + (size_t)s_d[r]*HD + ch*KC + c4);
            float4 vb = *(const float4*)((const float*)a1v + (size_t)s_pe[r]*HD + ch*KC + c4);
            *(float4*)&sa[r*STR + c4] = make_float4(va.x-vb.x, va.y-vb.y, va.z-vb.z, va.w-vb.w);
          }
        }
        if constexpr (AM==A_MSG){
          if (ch < 2){
            for (int idx=tid; idx<NR*(KC/4); idx+=256){
              int r = idx/(KC/4), c4 = (idx%(KC/4))*4;
              float4 v = *(const float4*)((const float*)a0v + (size_t)(rbase+r)*HD + ch*KC + c4);
              *(float4*)&sa[r*STR + c4] = v;
            }
          } else {
            for (int idx=tid; idx<NR*KC; idx+=256){
              int r = idx/KC, lk = idx%KC;
              int cc = (ch-2)*KC + lk;
              int node = rbase+r;
              int b = ptr[node], en = ptr[node+1];
              float s=0.f, m=0.f;
              for (int i=b;i<en;++i){
                float t = ((const float*)a1v)[(size_t)cidx[i]*HD + cc];
                s += t; m = fmaxf(m,t);
              }
              sa[r*STR + lk] = s*m;   // m_sum * relu(segment_max); he>=0
            }
          }
        }
      }

      for (int kk=0; kk<klim; kk+=32){
        // ---- stage W sub-chunk [32 k][128 c]; thread: c=tid>>1, k-half=(tid&1)*16 ----
        {
          int c = tid>>1, kh = (tid&1)*16;
          size_t wrow = (size_t)wb_seg + (size_t)c*ktot + (size_t)ch*KC + kk;
          if (wvec && dt==0){
            const float* Wf = (const float*)Wt;
            #pragma unroll
            for (int j4=0;j4<4;j4++){
              int kq = kh + j4*4;
              float v0=0.f,v1=0.f,v2=0.f,v3=0.f;
              if (kk+kq+4 <= klim){
                float4 v = *(const float4*)(Wf + wrow + kq);
                v0=v.x; v1=v.y; v2=v.z; v3=v.w;
              } else if (kk+kq < klim){
                v0 = Wf[wrow+kq];
                if (kk+kq+1<klim) v1 = Wf[wrow+kq+1];
                if (kk+kq+2<klim) v2 = Wf[wrow+kq+2];
              }
              wb[(kq+0)*128+c]=v0; wb[(kq+1)*128+c]=v1; wb[(kq+2)*128+c]=v2; wb[(kq+3)*128+c]=v3;
            }
          } else if (wvec){
            const u16* Wh = (const u16*)Wt;
            #pragma unroll
            for (int j4=0;j4<4;j4++){
              int kq = kh + j4*4;
              float v0=0.f,v1=0.f,v2=0.f,v3=0.f;
              if (kk+kq+4 <= klim){
                ushort4 v = *(const ushort4*)(Wh + wrow + kq);
                v0=bf2f(v.x); v1=bf2f(v.y); v2=bf2f(v.z); v3=bf2f(v.w);
              } else if (kk+kq < klim){
                v0 = bf2f(Wh[wrow+kq]);
                if (kk+kq+1<klim) v1 = bf2f(Wh[wrow+kq+1]);
                if (kk+kq+2<klim) v2 = bf2f(Wh[wrow+kq+2]);
              }
              wb[(kq+0)*128+c]=v0; wb[(kq+1)*128+c]=v1; wb[(kq+2)*128+c]=v2; wb[(kq+3)*128+c]=v3;
            }
          } else {
            for (int j=0;j<16;j++){
              int kq = kh + j;
              wb[kq*128+c] = (kk+kq < klim) ? rg(Wt, wrow+kq, dt) : 0.f;
            }
          }
        }
        __syncthreads();   // sa (if staged this round) + wb ready

        // ---- compute: 32 k's, zero-padded tails contribute 0 ----
        for (int kc=0; kc<32; kc+=4){
          float4 aa[MR];
          #pragma unroll
          for (int i=0;i<MR;i++)
            aa[i] = *(const float4*)&sa[(ryb+i)*STR + kk + kc];
          #pragma unroll
          for (int t=0;t<4;t++){
            float4 b0 = *(const float4*)&wb[(kc+t)*128 + cxx];
            float4 b1 = *(const float4*)&wb[(kc+t)*128 + 64 + cxx];
            #pragma unroll
            for (int i=0;i<MR;i++){
              float a = (t==0)?aa[i].x:(t==1)?aa[i].y:(t==2)?aa[i].z:aa[i].w;
              acc[i][0]+=a*b0.x; acc[i][1]+=a*b0.y; acc[i][2]+=a*b0.z; acc[i][3]+=a*b0.w;
              acc[i][4]+=a*b1.x; acc[i][5]+=a*b1.y; acc[i][6]+=a*b1.z; acc[i][7]+=a*b1.w;
            }
          }
        }
        __syncthreads();   // before restaging wb / next A chunk
      }
    }

    if constexpr (EP==E_GI){
      // register epilogue: out = f2bf(acc + bias), packed ushort4 stores
      const void* bsrc = (NSEG==6 && seg>=3) ? bias2 : bias;
      const int   po   = (NSEG==6) ? (seg%3)*HD : prmoff;
      u16*        op   = (NSEG==6) ? (seg<3 ? outb : outb2) : outb;
      const int   oc   = (NSEG==6) ? (seg%3)*HD : ocoff;
      float b0[4], b1[4];
      #pragma unroll
      for (int j=0;j<4;j++){
        b0[j] = rg(bsrc, po + cxx + j, dt);
        b1[j] = rg(bsrc, po + 64 + cxx + j, dt);
      }
      #pragma unroll
      for (int i=0;i<MR;i++){
        size_t gr = (size_t)(rbase + ryb + i);
        ushort4 u0, u1;
        u0.x=f2bf(acc[i][0]+b0[0]); u0.y=f2bf(acc[i][1]+b0[1]);
        u0.z=f2bf(acc[i][2]+b0[2]); u0.w=f2bf(acc[i][3]+b0[3]);
        u1.x=f2bf(acc[i][4]+b1[0]); u1.y=f2bf(acc[i][5]+b1[1]);
        u1.z=f2bf(acc[i][6]+b1[2]); u1.w=f2bf(acc[i][7]+b1[3]);
        *(ushort4*)&op[gr*ostride + oc + cxx]      = u0;
        *(ushort4*)&op[gr*ostride + oc + 64 + cxx] = u1;
      }
    }
  }

  if constexpr (EP==E_GI) return;

  // ================= register epilogues (no LDS C round-trip) =================
  if constexpr (EP==E_HE0_RELU){
    float b0[4], b1[4];
    #pragma unroll
    for (int j=0;j<4;j++){
      b0[j] = rg(bias, prmoff + cxx + j, dt);
      b1[j] = rg(bias, prmoff + 64 + cxx + j, dt);
    }
    #pragma unroll
    for (int i=0;i<MR;i++){
      int e = s_e[ryb+i];
      ushort4 h0 = *(const ushort4*)&he0b[(size_t)e*HD + cxx];
      ushort4 h1 = *(const ushort4*)&he0b[(size_t)e*HD + 64 + cxx];
      float4 o0, o1;
      o0.x = fmaxf(acc[i][0]+b0[0]+bf2f(h0.x), 0.f);
      o0.y = fmaxf(acc[i][1]+b0[1]+bf2f(h0.y), 0.f);
      o0.z = fmaxf(acc[i][2]+b0[2]+bf2f(h0.z), 0.f);
      o0.w = fmaxf(acc[i][3]+b0[3]+bf2f(h0.w), 0.f);
      o1.x = fmaxf(acc[i][4]+b1[0]+bf2f(h1.x), 0.f);
      o1.y = fmaxf(acc[i][5]+b1[1]+bf2f(h1.y), 0.f);
      o1.z = fmaxf(acc[i][6]+b1[2]+bf2f(h1.z), 0.f);
      o1.w = fmaxf(acc[i][7]+b1[3]+bf2f(h1.w), 0.f);
      *(float4*)&outf[(size_t)e*HD + cxx]      = o0;
      *(float4*)&outf[(size_t)e*HD + 64 + cxx] = o1;
    }
    return;
  }
  // LayerNorm family: bias/resid folded into acc, row stats via 16-lane
  // shfl_xor butterfly (row-group threads are contiguous lanes).
  {
    float bc[8], gc[8], tc[8];
    #pragma unroll
    for (int j=0;j<4;j++){
      bc[j]   = rg(bias,  prmoff + cxx + j,      dt);
      bc[4+j] = rg(bias,  prmoff + 64 + cxx + j, dt);
      gc[j]   = rg(gamma, prmoff + cxx + j,      dt);
      gc[4+j] = rg(gamma, prmoff + 64 + cxx + j, dt);
      tc[j]   = rg(beta,  prmoff + cxx + j,      dt);
      tc[4+j] = rg(beta,  prmoff + 64 + cxx + j, dt);
    }
    #pragma unroll
    for (int i=0;i<MR;i++){
      size_t grow = (size_t)(rbase + ryb + i);
      if constexpr (EP==E_RESID_LN){
        float4 r0 = *(const float4*)&resid[grow*HD + cxx];
        float4 r1 = *(const float4*)&resid[grow*HD + 64 + cxx];
        acc[i][0] = r0.x + fmaxf(acc[i][0]+bc[0], 0.f);
        acc[i][1] = r0.y + fmaxf(acc[i][1]+bc[1], 0.f);
        acc[i][2] = r0.z + fmaxf(acc[i][2]+bc[2], 0.f);
        acc[i][3] = r0.w + fmaxf(acc[i][3]+bc[3], 0.f);
        acc[i][4] = r1.x + fmaxf(acc[i][4]+bc[4], 0.f);
        acc[i][5] = r1.y + fmaxf(acc[i][5]+bc[5], 0.f);
        acc[i][6] = r1.z + fmaxf(acc[i][6]+bc[6], 0.f);
        acc[i][7] = r1.w + fmaxf(acc[i][7]+bc[7], 0.f);
      } else {
        #pragma unroll
        for (int j=0;j<8;j++) acc[i][j] += bc[j];
      }
      float sm=0.f, sq=0.f;
      #pragma unroll
      for (int j=0;j<8;j++){ sm += acc[i][j]; sq += acc[i][j]*acc[i][j]; }
      sm += __shfl_xor(sm,1); sq += __shfl_xor(sq,1);
      sm += __shfl_xor(sm,2); sq += __shfl_xor(sq,2);
      sm += __shfl_xor(sm,4); sq += __shfl_xor(sq,4);
      sm += __shfl_xor(sm,8); sq += __shfl_xor(sq,8);
      float mu  = sm*(1.f/128.f);
      float var = sq*(1.f/128.f) - mu*mu;
      float rs  = rsqrtf(fmaxf(var,0.f)+1e-5f);
      float y[8];
      #pragma unroll
      for (int j=0;j<8;j++){
        float v = (acc[i][j]-mu)*rs*gc[j] + tc[j];
        if constexpr (EP==E_LN_RELU || EP==E_LN_RELU_DUAL) v = fmaxf(v,0.f);
        if constexpr (EP==E_LN_RELU_TANH) v = tanhfast(fmaxf(v,0.f));
        y[j] = v;
      }
      *(float4*)&outf[grow*HD + cxx]      = make_float4(y[0],y[1],y[2],y[3]);
      *(float4*)&outf[grow*HD + 64 + cxx] = make_float4(y[4],y[5],y[6],y[7]);
      if constexpr (EP==E_LN_RELU_DUAL){
        ushort4 u0, u1;
        u0.x=f2bf(y[0]); u0.y=f2bf(y[1]); u0.z=f2bf(y[2]); u0.w=f2bf(y[3]);
        u1.x=f2bf(y[4]); u1.y=f2bf(y[5]); u1.z=f2bf(y[6]); u1.w=f2bf(y[7]);
        *(ushort4*)&outb[grow*HD + cxx]      = u0;
        *(ushort4*)&outb[grow*HD + 64 + cxx] = u1;
      }
    }
  }
}

// merged weight pre-convert: 4 (whh,bhh) pairs raw -> fp32 [49152|384] blocks
__global__ void k_cvt4(const void* w0,const void* b0,const void* w1,const void* b1,
                       const void* w2,const void* b2,const void* w3,const void* b3,
                       float* d0, float* d1, float* d2, float* d3, const int* dflag){
  int dt = *dflag;
  int p  = blockIdx.y;
  const void* wsrc = (p==0)?w0:(p==1)?w1:(p==2)?w2:w3;
  const void* bsrc = (p==0)?b0:(p==1)?b1:(p==2)?b2:b3;
  float* dst       = (p==0)?d0:(p==1)?d1:(p==2)?d2:d3;
  int i = blockIdx.x*256 + threadIdx.x;
  if (i < 49152)      dst[i] = rg(wsrc, i, dt);
  else if (i < 49536) dst[i] = rg(bsrc, i-49152, dt);
}

// BiGRU, W-in-registers (EXACT r6-measured 318us config — do not touch):
// one block = 4 graphs x one dir (grid 128x2); 384 threads; thread owns
// gate-row d=tid and keeps its whh row (32 float4) in registers for all 64
// steps. launch_bounds(384,1): VGPR 128, no spill (ledger: min-waves=3 and
// next-step prefetch both spill). Same-step gi prefetch only. sgh stride 5
// (gcd(5,32)=1): conflict-free cell reads. fp32 FMA, same k-order.
__launch_bounds__(384,1)
__global__ void k_gru(
  const u16* gi_f, const u16* gi_b,
  const float* wcf, const float* wcb,
  u16* out_seq, float* zbuf, int write_seq)
{
  const int dir = blockIdx.y;
  const int g0  = blockIdx.x * 4;
  const u16* gi  = dir ? gi_b : gi_f;
  const float* whh = dir ? wcb : wcf;
  const float* bh  = whh + 49152;

  __shared__ float sgh[384*5];               // [row d][graph g], stride 5
  __shared__ __align__(16) float sh[4*128];  // h state [g][d]

  const int tid = threadIdx.x;   // 0..383, owns gate-row d=tid

  // load W row into registers (once)
  float4 wreg[32];
  {
    const float4* wrow = (const float4*)(whh + (size_t)tid*128);
    #pragma unroll
    for (int i=0;i<32;i++) wreg[i] = wrow[i];
  }
  const float bhd = bh[tid];

  // cell-phase ownership: item A = tid (g=tid>>7 in {0,1,2}, d=tid&127);
  // item B = 384+tid for tid<128 (g=3, d=tid)
  const int gA = tid>>7, dA = tid&127;

  for (int i=tid;i<512;i+=384) sh[i]=0.f;
  __syncthreads();

  for (int step=0; step<64; ++step){
    const int t = dir ? (63-step) : step;

    // ---- prefetch gi for this step's cell items (independent of LDS) ----
    const u16* gpA = gi + (size_t)((g0+gA)*TSEQ + t)*384;
    u16 aR = gpA[dA], aZ = gpA[128+dA], aN = gpA[256+dA];
    u16 bR=0, bZ=0, bN=0;
    if (tid < 128){
      const u16* gpB = gi + (size_t)((g0+3)*TSEQ + t)*384;
      bR = gpB[tid]; bZ = gpB[128+tid]; bN = gpB[256+tid];
    }

    // ---- GEMV: gh[d][g] = whh[d]·h[g] + bh[d], W from registers ----
    float a0=0.f, a1=0.f, a2=0.f, a3=0.f;
    #pragma unroll
    for (int k4=0; k4<32; k4++){
      float4 w  = wreg[k4];
      float4 h0 = *(const float4*)&sh[0*128 + k4*4];
      float4 h1 = *(const float4*)&sh[1*128 + k4*4];
      float4 h2 = *(const float4*)&sh[2*128 + k4*4];
      float4 h3 = *(const float4*)&sh[3*128 + k4*4];
      a0 += h0.x*w.x + h0.y*w.y + h0.z*w.z + h0.w*w.w;
      a1 += h1.x*w.x + h1.y*w.y + h1.z*w.z + h1.w*w.w;
      a2 += h2.x*w.x + h2.y*w.y + h2.z*w.z + h2.w*w.w;
      a3 += h3.x*w.x + h3.y*w.y + h3.z*w.z + h3.w*w.w;
    }
    sgh[tid*5+0] = a0 + bhd;
    sgh[tid*5+1] = a1 + bhd;
    sgh[tid*5+2] = a2 + bhd;
    sgh[tid*5+3] = a3 + bhd;
    __syncthreads();

    // ---- cell update ----
    {
      float r = sigm(bf2f(aR) + sgh[dA*5+gA]);
      float z = sigm(bf2f(aZ) + sgh[(128+dA)*5+gA]);
      float n = tanhfast(bf2f(aN) + r*sgh[(256+dA)*5+gA]);
      float h = (1.f-z)*n + z*sh[gA*128+dA];
      sh[gA*128+dA] = h;
      if (write_seq){
        float hc = fminf(fmaxf(h,-10.f),10.f);
        out_seq[(size_t)((g0+gA)*TSEQ + t)*256 + dir*HD + dA] = f2bf(hc);
      }
    }
    if (tid < 128){
      float r = sigm(bf2f(bR) + sgh[tid*5+3]);
      float z = sigm(bf2f(bZ) + sgh[(128+tid)*5+3]);
      float n = tanhfast(bf2f(bN) + r*sgh[(256+tid)*5+3]);
      float h = (1.f-z)*n + z*sh[3*128+tid];
      sh[3*128+tid] = h;
      if (write_seq){
        float hc = fminf(fmaxf(h,-10.f),10.f);
        out_seq[(size_t)((g0+3)*TSEQ + t)*256 + dir*HD + tid] = f2bf(hc);
      }
    }
    __syncthreads();
  }

  if (!write_seq){
    for (int i=tid;i<512;i+=384){
      int g=i>>7, d=i&127;
      zbuf[(size_t)(g0+g)*256 + dir*HD + d] = fminf(fmaxf(sh[g*128+d],-10.f),10.f);
    }
  }
}

__launch_bounds__(64)
__global__ void k_gather(const float* he, const int* ptr, const int* cidx, float* out){
  int n = blockIdx.x;
  int c = threadIdx.x;
  int b = ptr[n], e = ptr[n+1];
  float s0=0.f,s1=0.f;
  for (int i=b;i<e;++i){
    int eid = cidx[i];
    float2 v = *(const float2*)(he + (size_t)eid*HD + c*2);
    s0+=v.x; s1+=v.y;
  }
  out[(size_t)n*HD + c*2]   = s0;
  out[(size_t)n*HD + c*2+1] = s1;
}

__global__ void k_count(const int* dst, int* cnt){
  int e = blockIdx.x*256+threadIdx.x;
  if (e<NE) atomicAdd(&cnt[dst[e]],1);
}

__launch_bounds__(1024)
__global__ void k_scan(const int* cnt, int* ptr){
  __shared__ int s[1024];
  int tid=threadIdx.x;
  int loc[32]; int tot=0;
  int base = tid*32;
  #pragma unroll
  for (int i=0;i<32;i++){ loc[i]=tot; tot += cnt[base+i]; }
  s[tid]=tot; __syncthreads();
  for (int off=1; off<1024; off<<=1){
    int v = (tid>=off)? s[tid-off] : 0;
    __syncthreads();
    s[tid] += v;
    __syncthreads();
  }
  int ex = s[tid] - tot;
  for (int i=0;i<32;i++) ptr[base+i] = ex + loc[i];
  if (tid==1023) ptr[NN] = ex + tot;
}

__global__ void k_fill(const int* dst, const int* ptr, int* cur, int* cidx){
  int e = blockIdx.x*256+threadIdx.x;
  if (e<NE){
    int d = dst[e];
    int p = ptr[d] + atomicAdd(&cur[d],1);
    cidx[p] = e;
  }
}

// runtime input-dtype detector (fp32 low-halfword exponents ~uniform; bf16 ~always in-range)
__global__ void k_detect(const u16* x, int* flag){
  __shared__ int cnt;
  if (threadIdx.x==0) cnt=0;
  __syncthreads();
  u16 u = x[threadIdx.x*2];
  int e = (u>>7)&0xff;
  if (e>=100 && e<=135) atomicAdd(&cnt,1);
  __syncthreads();
  if (threadIdx.x==0) *flag = (cnt>=128) ? 1 : 0;
}

__launch_bounds__(256)
__global__ void k_bnstats(const float* z, const void* bng, const void* bnb, float* st, const int* dflag){
  int dt = *dflag;
  int c = threadIdx.x;
  float sm=0.f, sq=0.f;
  for (int g=0; g<NG; ++g){ float v = z[(size_t)g*256+c]; sm+=v; sq+=v*v; }
  float mu = sm*(1.f/(float)NG);
  float var = sq*(1.f/(float)NG) - mu*mu;
  float rs = rsqrtf(fmaxf(var,0.f)+1e-5f);
  float sc = rs*rg(bng,c,dt);
  st[c] = sc;
  st[256+c] = rg(bnb,c,dt) - mu*sc;
}

// OUTPUT fp32 (confirmed by r8: finite ref-scale error under fp32 writes)
__global__ void k_pred(const float* z, const float* st, const void* pw, const void* pb, float* out, const int* dflag){
  int dt = *dflag;
  int g = blockIdx.x*256+threadIdx.x;
  if (g>=NG) return;
  float acc = rg(pb,0,dt);
  for (int c=0;c<256;c++) acc += (z[(size_t)g*256+c]*st[c] + st[256+c])*rg(pw,c,dt);
  out[g]=acc;
}

extern "C" void kernel_launch(void* const* d_in, const int* in_sizes, int n_in,
                              void* d_out, int out_size, void* d_ws, size_t ws_size,
                              hipStream_t stream)
{
  const void* X    =d_in[0];
  const void* EA   =d_in[1];
  const void* NW   =d_in[2];
  const void* NB   =d_in[3];
  const void* NGa  =d_in[4];
  const void* NBt  =d_in[5];
  const void* EW   =d_in[6];
  const void* EB   =d_in[7];
  const void* EGa  =d_in[8];
  const void* EBt  =d_in[9];
  const void* LW   =d_in[10];
  const void* LB   =d_in[11];
  const void* LGa  =d_in[12];
  const void* LBt  =d_in[13];
  const void* NUW  =d_in[14];
  const void* NUB  =d_in[15];
  const void* NNG  =d_in[16];
  const void* NNB  =d_in[17];
  const void* EUW  =d_in[18];
  const void* EUB  =d_in[19];
  const void* BOOST=d_in[20];
  const void* BIHW_F=d_in[21];
  const void* BHHW_F=d_in[22];
  const void* BIHB_F=d_in[23];
  const void* BHHB_F=d_in[24];
  const void* BIHW_B=d_in[25];
  const void* BHHW_B=d_in[26];
  const void* BIHB_B=d_in[27];
  const void* BHHB_B=d_in[28];
  const void* PW   =d_in[29];
  const void* PB   =d_in[30];
  const void* PG   =d_in[31];
  const void* PBt  =d_in[32];
  const void* FW   =d_in[33];
  const void* FB   =d_in[34];
  const void* FG   =d_in[35];
  const void* FBt  =d_in[36];
  const void* RIHW_F=d_in[37];
  const void* RHHW_F=d_in[38];
  const void* RIHB_F=d_in[39];
  const void* RHHB_F=d_in[40];
  const void* RIHW_B=d_in[41];
  const void* RHHW_B=d_in[42];
  const void* RIHB_B=d_in[43];
  const void* RHHB_B=d_in[44];
  const void* BNG  =d_in[45];
  const void* BNB  =d_in[46];
  const void* PRW  =d_in[47];
  const void* PRB  =d_in[48];
  const int* EIDX =(const int*)d_in[49];
  const int* DST  = EIDX + NE;

  // ---- Workspace (same map as before; fp32 GRU weights in 2MB..3MB gap) ----
  char* ws=(char*)d_ws;
  const size_t MB = 1048576;
  int*   csrp =(int*)  (ws + 0);
  int*   csrc =(int*)  (ws + 135168);
  int*   csri =(int*)  (ws + 266240);
  float* zbuf =(float*)(ws + 790528);
  float* stats=(float*)(ws + 1314816);
  int*   dflag=(int*)  (ws + 1316864);
  float* wbgf =(float*)(ws + 2*MB);          // [49152 whh | 384 bhh] fp32, boost fwd
  float* wbgb = wbgf + 49536;                // boost bwd
  float* wrgf = wbgb + 49536;                // readout fwd
  float* wrgb = wrgf + 49536;                // readout bwd
  float* hv   =(float*)(ws + 6*MB);
  u16*   he0  =(u16*)  (ws + 22*MB);
  float* he   =(float*)(ws + 54*MB);
  float* mfin =(float*)(ws + 22*MB);
  u16*   gif  =(u16*)  (ws + 54*MB);
  u16*   gib  =(u16*)  (ws + 78*MB);
  u16*   oseq =(u16*)  (ws + 6*MB);
  float* hv2  =(float*)(ws + 38*MB);
  float* hx2  =(float*)(ws + 6*MB);
  float* fout =(float*)(ws + 54*MB);
  u16*   gif_r=(u16*)  (ws + 70*MB);
  u16*   gib_r=(u16*)  (ws + 94*MB);

  k_detect<<<dim3(1),dim3(256),0,stream>>>((const u16*)X, dflag);

  // pre-convert recurrent GRU weights to fp32 (one merged launch)
  k_cvt4<<<dim3(194,4),dim3(256),0,stream>>>(
      BHHW_F,BHHB_F, BHHW_B,BHHB_B, RHHW_F,RHHB_F, RHHW_B,RHHB_B,
      wbgf, wbgb, wrgf, wrgb, dflag);

  // CSR over dst
  hipMemsetAsync(csrc, 0, 131072, stream);
  k_count<<<dim3(512),dim3(256),0,stream>>>(DST, csrc);
  k_scan<<<dim3(1),dim3(1024),0,stream>>>(csrc, csrp);
  hipMemsetAsync(csrc, 0, 131072, stream);
  k_fill<<<dim3(512),dim3(256),0,stream>>>(DST, csrp, csrc, csri);

  // init embeddings (32-row LN tiles -> 4 blocks/CU)
  k_dense<A_XF,E_LN_RELU,3,1,32><<<dim3(1024),dim3(256),0,stream>>>(X,nullptr,nullptr,
      nullptr,nullptr,nullptr,nullptr, NW,nullptr,0, NB,nullptr,NGa,NBt,0, nullptr,nullptr,
      hv,nullptr,nullptr, dflag, 133,133,HD,0);
  k_dense<A_XF,E_LN_RELU_DUAL,1,1,32><<<dim3(4096),dim3(256),0,stream>>>(EA,nullptr,nullptr,
      nullptr,nullptr,nullptr,nullptr, EW,nullptr,0, EB,nullptr,EGa,EBt,0, nullptr,nullptr,
      he,he0,nullptr, dflag, 14,14,HD,0);

  // message passing (msg: 32-row; edge: 64-row/KC=64 -> 4 blocks/CU)
  for (int s=0;s<5;s++){
    k_dense<A_MSG,E_RESID_LN,4,1,32><<<dim3(1024),dim3(256),0,stream>>>(hv,he,nullptr,
        nullptr,csrp,csri,nullptr, NUW,nullptr,s*32768, NUB,nullptr,NNG,NNB,s*128,
        hv,nullptr, hv,nullptr,nullptr, dflag, 256,HD,HD,0);
    k_dense<A_EDGE,E_HE0_RELU,2,1,64><<<dim3(2048),dim3(256),0,stream>>>(hv,he,nullptr,
        DST,nullptr,nullptr,nullptr, EUW,nullptr,s*16384, EUB,nullptr,nullptr,nullptr,s*128,
        nullptr,he0, he,nullptr,nullptr, dflag, 128,HD,HD,0);
  }
  k_gather<<<dim3(NN),dim3(64),0,stream>>>(he, csrp, csri, mfin);

  // boost GRU input-side gates: ONE launch, 6 weight segments (frozen r4 geometry)
  k_dense<A_BOOST,E_GI,1,6,64><<<dim3(512),dim3(256),0,stream>>>(hv,nullptr,nullptr,
      nullptr,nullptr,nullptr,BOOST, BIHW_F,BIHW_B,0, BIHB_F,BIHB_B,nullptr,nullptr,0,
      nullptr,nullptr, nullptr,gif,gib, dflag, 128,HD,384,0);
  k_gru<<<dim3(128,2),dim3(384),0,stream>>>(gif, gib, wbgf, wbgb, oseq, zbuf, 1);

  // proj + recompute hx + final merge (32-row LN tiles)
  k_dense<A_B16,E_LN_RELU_TANH,4,1,32><<<dim3(1024),dim3(256),0,stream>>>(oseq,nullptr,nullptr,
      nullptr,nullptr,nullptr,nullptr, PW,nullptr,0, PB,nullptr,PG,PBt,0, nullptr,nullptr,
      hv2,nullptr,nullptr, dflag, 256,256,HD,0);
  k_dense<A_XF,E_LN,3,1,32><<<dim3(1024),dim3(256),0,stream>>>(X,nullptr,nullptr,
      nullptr,nullptr,nullptr,nullptr, LW,nullptr,0, LB,nullptr,LGa,LBt,0, nullptr,nullptr,
      hx2,nullptr,nullptr, dflag, 133,133,HD,0);
  k_dense<A_C3,E_LN_RELU,6,1,32><<<dim3(1024),dim3(256),0,stream>>>(hv2,mfin,hx2,
      nullptr,nullptr,nullptr,nullptr, FW,nullptr,0, FB,nullptr,FG,FBt,0, nullptr,nullptr,
      fout,nullptr,nullptr, dflag, 384,HD,HD,0);

  // readout GRU gates (ONE launch, 6 segments) + GRU
  k_dense<A_F32,E_GI,1,6,64><<<dim3(512),dim3(256),0,stream>>>(fout,nullptr,nullptr,
      nullptr,nullptr,nullptr,nullptr, RIHW_F,RIHW_B,0, RIHB_F,RIHB_B,nullptr,nullptr,0,
      nullptr,nullptr, nullptr,gif_r,gib_r, dflag, 128,HD,384,0);
  k_gru<<<dim3(128,2),dim3(384),0,stream>>>(gif_r, gib_r, wrgf, wrgb, oseq, zbuf, 0);

  // BN + prediction
  k_bnstats<<<dim3(1),dim3(256),0,stream>>>(zbuf, BNG, BNB, stats, dflag);
  k_pred<<<dim3(2),dim3(256),0,stream>>>(zbuf, stats, PRW, PRB, (float*)d_out, dflag);

  (void)in_sizes; (void)n_in; (void)out_size; (void)ws_size;
}

// Round 11
// 2099.651 us; speedup vs baseline: 1.9189x; 1.0127x over previous
//
#include <hip/hip_runtime.h>
#include <hip/hip_bf16.h>

typedef unsigned short u16;
typedef unsigned int   u32;

#define NN    32768
#define NG    512
#define TSEQ  64
#define NE    131072
#define NP    65536
#define HD    128

__device__ __forceinline__ float bf2f(u16 v){ u32 u=((u32)v)<<16; float f; __builtin_memcpy(&f,&u,4); return f; }
__device__ __forceinline__ u16 f2bf(float f){ u32 u; __builtin_memcpy(&u,&f,4); u32 r=u+0x7fffu+((u>>16)&1u); return (u16)(r>>16); }
__device__ __forceinline__ float sigm(float x){ return 1.f/(1.f+__expf(-x)); }
__device__ __forceinline__ float tanhfast(float x){ return 1.f-2.f/(1.f+__expf(2.f*x)); }
// raw-input read: dt=1 -> bf16, dt=0 -> fp32
__device__ __forceinline__ float rg(const void* p, size_t i, int dt){
  return dt ? bf2f(((const u16*)p)[i]) : ((const float*)p)[i];
}

// A-source modes / epilogues
enum { A_XF, A_F32, A_B16, A_MSG, A_C3, A_EDGE, A_BOOST };
enum { E_LN_RELU, E_LN, E_LN_RELU_TANH, E_RESID_LN, E_HE0_RELU, E_GI, E_LN_RELU_DUAL };

// ===== MEASURED-CONFIG LEDGER (do not re-try losers) =====
// dense core: 32-k W single-buffer SYNC stage is the proven kernel.
//   - reg double-buffer W (r5): -1.0ms REGRESSION. raw-bit uint4 (r6): -0.5ms.
//   - 128-row tiles (r8): WASH. NR=32 residency (r9): 2622->2126us. WIN.
//   - A_C3G inline-gather (r10): FAILED — gif/gib are 24MB EACH (NN*384*2);
//     extending he's lifetime past boost-GI needs ~132MB live > proven-safe
//     ~118MB footprint. k_gather stays. gif/gib sizing: 24MB, not 12.6MB.
// k_gru: 4 graphs/block, grid(128,2), launch_bounds(384,1) = BEST (318us).
//   - (384,3): spill -> 780us. next-step gi prefetch: spill -> 490us.
// ws map (r9, PROVEN): hv@6[6,22) he0@22[22,54) he@54[54,118)
//   mfin@22 (he0 dead after last edge) | gif@54 gib@78 (he dead after
//   k_gather) | oseq@6 (hv dead after boost-GI) | hv2@38 hx2@6 fout@54
//   gif_r@70 gib_r@94. Peak < 118MB.
// =========================================================

// Register-tiled fp32 GEMM core.
//  non-GI: NRT x 128 output tile (NRT=32 everywhere now: LN + edge), A in
//          64-k chunks, W in 32-k sub-chunks (16 KB), register epilogues
//          (LN stats via 16-lane shfl_xor butterfly over contiguous lanes).
//  GI:     64x128 tile, KC=128: A fully LDS-resident across NSEG=6 weight
//          segments (measured r4 config, unchanged).
// fp32 FMA in ascending k-order (sums bit-identical across tile geometry).
template<int AM, int EP, int NCH, int NSEG, int NRT>
__launch_bounds__(256)
__global__ void k_dense(
    const void* a0v, const void* a1v, const void* a2v,
    const int* dsti, const int* ptr, const int* cidx, const void* abias,
    const void* W, const void* W2, int wbase,
    const void* bias, const void* bias2, const void* gamma, const void* beta, int prmoff,
    const float* resid, const u16* he0b,
    float* outf, u16* outb, u16* outb2, const int* dflag,
    int ktot, int astride, int ostride, int ocoff)
{
  constexpr bool GI = (EP==E_GI);
  constexpr int NR  = NRT;              // output rows per block
  constexpr int KC  = GI ? 128 : 64;    // A k-chunk width
  constexpr int STR = KC + 4;           // sa row stride, 16B-aligned
  constexpr int MR  = NR/16;            // acc rows per thread

  __shared__ __align__(16) float sa[NR*STR];   // A tile
  __shared__ __align__(16) float wb[32*128];   // W sub-chunk [k][c], 16 KB
  __shared__ int s_e[NR], s_pe[NR], s_d[NR];
  __shared__ float s_ab[128];

  const int dt  = *dflag;
  const int tid = threadIdx.x;
  const int bx  = blockIdx.x;

  if constexpr (AM==A_EDGE){
    if (tid < NR){
      int eb = bx*(NR/2);
      int e  = (tid<NR/2) ? (eb+tid) : (NP + eb + tid - NR/2);
      s_e[tid]  = e;
      s_pe[tid] = (tid<NR/2) ? (e+NP) : (e-NP);
      s_d[tid]  = dsti[e];
    }
    __syncthreads();
  }
  if constexpr (AM==A_BOOST){
    if (tid < 128) s_ab[tid] = rg(abias, tid, dt);
    __syncthreads();
  }
  const int rbase = (AM==A_EDGE) ? 0 : bx*NR;

  const int ryb = (tid>>4)*MR;          // rows ryb..ryb+MR-1
  const int cxx = (tid&15)*4;           // cols cxx..+3 and 64+cxx..+3

  float acc[MR][8];

  for (int seg=0; seg<NSEG; ++seg){
    #pragma unroll
    for (int i=0;i<MR;i++)
      #pragma unroll
      for (int j=0;j<8;j++) acc[i][j]=0.f;

    const int wb_seg = (NSEG==6) ? (seg%3)*(ktot*HD) : wbase;
    const void* Wt   = (NSEG==6 && seg>=3) ? W2 : W;
    const bool wvec = ((ktot&3)==0) && ((wb_seg&3)==0);

    for (int ch=0; ch<NCH; ++ch){
      int klim = ktot - ch*KC; if (klim > KC) klim = KC;

      if (seg==0){
        // ---- stage NRxKC fp32 A-chunk ----
        if constexpr (AM==A_XF){
          for (int idx=tid; idx<NR*KC; idx+=256){
            int r = idx/KC, lk = idx%KC, k = ch*KC + lk;
            float v = 0.f;
            if (k < ktot) v = rg(a0v, (size_t)(rbase+r)*astride + k, dt);
            sa[r*STR + lk] = v;
          }
        }
        if constexpr (AM==A_F32){
          for (int idx=tid; idx<NR*(KC/4); idx+=256){
            int r = idx/(KC/4), c4 = (idx%(KC/4))*4;
            float4 v = *(const float4*)((const float*)a0v + (size_t)(rbase+r)*astride + ch*KC + c4);
            *(float4*)&sa[r*STR + c4] = v;
          }
        }
        if constexpr (AM==A_B16){
          for (int idx=tid; idx<NR*(KC/4); idx+=256){
            int r = idx/(KC/4), c4 = (idx%(KC/4))*4;
            ushort4 u = *(const ushort4*)((const u16*)a0v + (size_t)(rbase+r)*astride + ch*KC + c4);
            *(float4*)&sa[r*STR + c4] = make_float4(bf2f(u.x),bf2f(u.y),bf2f(u.z),bf2f(u.w));
          }
        }
        if constexpr (AM==A_C3){
          const float* src = (ch<2)?(const float*)a0v:(ch<4)?(const float*)a1v:(const float*)a2v;
          const int coloff = (ch&1)*64;
          for (int idx=tid; idx<NR*(KC/4); idx+=256){
            int r = idx/(KC/4), c4 = (idx%(KC/4))*4;
            float4 v = *(const float4*)(src + (size_t)(rbase+r)*HD + coloff + c4);
            *(float4*)&sa[r*STR + c4] = v;
          }
        }
        if constexpr (AM==A_BOOST){
          for (int idx=tid; idx<NR*(KC/4); idx+=256){
            int r = idx/(KC/4), c4 = (idx%(KC/4))*4;
            float4 v = *(const float4*)((const float*)a0v + (size_t)(rbase+r)*HD + c4);
            v.x = fmaxf(v.x + s_ab[c4+0], 0.f);
            v.y = fmaxf(v.y + s_ab[c4+1], 0.f);
            v.z = fmaxf(v.z + s_ab[c4+2], 0.f);
            v.w = fmaxf(v.w + s_ab[c4+3], 0.f);
            *(float4*)&sa[r*STR + c4] = v;
          }
        }
        if constexpr (AM==A_EDGE){
          for (int idx=tid; idx<NR*(KC/4); idx+=256){
            int r = idx/(KC/4), c4 = (idx%(KC/4))*4;
            float4 va = *(const float4*)((const float*)a0v + (size_t)s_d[r]*HD + ch*KC + c4);
            float4 vb = *(const float4*)((const float*)a1v + (size_t)s_pe[r]*HD + ch*KC + c4);
            *(float4*)&sa[r*STR + c4] = make_float4(va.x-vb.x, va.y-vb.y, va.z-vb.z, va.w-vb.w);
          }
        }
        if constexpr (AM==A_MSG){
          if (ch < 2){
            for (int idx=tid; idx<NR*(KC/4); idx+=256){
              int r = idx/(KC/4), c4 = (idx%(KC/4))*4;
              float4 v = *(const float4*)((const float*)a0v + (size_t)(rbase+r)*HD + ch*KC + c4);
              *(float4*)&sa[r*STR + c4] = v;
            }
          } else {
            for (int idx=tid; idx<NR*KC; idx+=256){
              int r = idx/KC, lk = idx%KC;
              int cc = (ch-2)*KC + lk;
              int node = rbase+r;
              int b = ptr[node], en = ptr[node+1];
              float s=0.f, m=0.f;
              for (int i=b;i<en;++i){
                float t = ((const float*)a1v)[(size_t)cidx[i]*HD + cc];
                s += t; m = fmaxf(m,t);
              }
              sa[r*STR + lk] = s*m;   // m_sum * relu(segment_max); he>=0
            }
          }
        }
      }

      for (int kk=0; kk<klim; kk+=32){
        // ---- stage W sub-chunk [32 k][128 c]; thread: c=tid>>1, k-half=(tid&1)*16 ----
        {
          int c = tid>>1, kh = (tid&1)*16;
          size_t wrow = (size_t)wb_seg + (size_t)c*ktot + (size_t)ch*KC + kk;
          if (wvec && dt==0){
            const float* Wf = (const float*)Wt;
            #pragma unroll
            for (int j4=0;j4<4;j4++){
              int kq = kh + j4*4;
              float v0=0.f,v1=0.f,v2=0.f,v3=0.f;
              if (kk+kq+4 <= klim){
                float4 v = *(const float4*)(Wf + wrow + kq);
                v0=v.x; v1=v.y; v2=v.z; v3=v.w;
              } else if (kk+kq < klim){
                v0 = Wf[wrow+kq];
                if (kk+kq+1<klim) v1 = Wf[wrow+kq+1];
                if (kk+kq+2<klim) v2 = Wf[wrow+kq+2];
              }
              wb[(kq+0)*128+c]=v0; wb[(kq+1)*128+c]=v1; wb[(kq+2)*128+c]=v2; wb[(kq+3)*128+c]=v3;
            }
          } else if (wvec){
            const u16* Wh = (const u16*)Wt;
            #pragma unroll
            for (int j4=0;j4<4;j4++){
              int kq = kh + j4*4;
              float v0=0.f,v1=0.f,v2=0.f,v3=0.f;
              if (kk+kq+4 <= klim){
                ushort4 v = *(const ushort4*)(Wh + wrow + kq);
                v0=bf2f(v.x); v1=bf2f(v.y); v2=bf2f(v.z); v3=bf2f(v.w);
              } else if (kk+kq < klim){
                v0 = bf2f(Wh[wrow+kq]);
                if (kk+kq+1<klim) v1 = bf2f(Wh[wrow+kq+1]);
                if (kk+kq+2<klim) v2 = bf2f(Wh[wrow+kq+2]);
              }
              wb[(kq+0)*128+c]=v0; wb[(kq+1)*128+c]=v1; wb[(kq+2)*128+c]=v2; wb[(kq+3)*128+c]=v3;
            }
          } else {
            for (int j=0;j<16;j++){
              int kq = kh + j;
              wb[kq*128+c] = (kk+kq < klim) ? rg(Wt, wrow+kq, dt) : 0.f;
            }
          }
        }
        __syncthreads();   // sa (if staged this round) + wb ready

        // ---- compute: 32 k's, zero-padded tails contribute 0 ----
        for (int kc=0; kc<32; kc+=4){
          float4 aa[MR];
          #pragma unroll
          for (int i=0;i<MR;i++)
            aa[i] = *(const float4*)&sa[(ryb+i)*STR + kk + kc];
          #pragma unroll
          for (int t=0;t<4;t++){
            float4 b0 = *(const float4*)&wb[(kc+t)*128 + cxx];
            float4 b1 = *(const float4*)&wb[(kc+t)*128 + 64 + cxx];
            #pragma unroll
            for (int i=0;i<MR;i++){
              float a = (t==0)?aa[i].x:(t==1)?aa[i].y:(t==2)?aa[i].z:aa[i].w;
              acc[i][0]+=a*b0.x; acc[i][1]+=a*b0.y; acc[i][2]+=a*b0.z; acc[i][3]+=a*b0.w;
              acc[i][4]+=a*b1.x; acc[i][5]+=a*b1.y; acc[i][6]+=a*b1.z; acc[i][7]+=a*b1.w;
            }
          }
        }
        __syncthreads();   // before restaging wb / next A chunk
      }
    }

    if constexpr (EP==E_GI){
      // register epilogue: out = f2bf(acc + bias), packed ushort4 stores
      const void* bsrc = (NSEG==6 && seg>=3) ? bias2 : bias;
      const int   po   = (NSEG==6) ? (seg%3)*HD : prmoff;
      u16*        op   = (NSEG==6) ? (seg<3 ? outb : outb2) : outb;
      const int   oc   = (NSEG==6) ? (seg%3)*HD : ocoff;
      float b0[4], b1[4];
      #pragma unroll
      for (int j=0;j<4;j++){
        b0[j] = rg(bsrc, po + cxx + j, dt);
        b1[j] = rg(bsrc, po + 64 + cxx + j, dt);
      }
      #pragma unroll
      for (int i=0;i<MR;i++){
        size_t gr = (size_t)(rbase + ryb + i);
        ushort4 u0, u1;
        u0.x=f2bf(acc[i][0]+b0[0]); u0.y=f2bf(acc[i][1]+b0[1]);
        u0.z=f2bf(acc[i][2]+b0[2]); u0.w=f2bf(acc[i][3]+b0[3]);
        u1.x=f2bf(acc[i][4]+b1[0]); u1.y=f2bf(acc[i][5]+b1[1]);
        u1.z=f2bf(acc[i][6]+b1[2]); u1.w=f2bf(acc[i][7]+b1[3]);
        *(ushort4*)&op[gr*ostride + oc + cxx]      = u0;
        *(ushort4*)&op[gr*ostride + oc + 64 + cxx] = u1;
      }
    }
  }

  if constexpr (EP==E_GI) return;

  // ================= register epilogues (no LDS C round-trip) =================
  if constexpr (EP==E_HE0_RELU){
    float b0[4], b1[4];
    #pragma unroll
    for (int j=0;j<4;j++){
      b0[j] = rg(bias, prmoff + cxx + j, dt);
      b1[j] = rg(bias, prmoff + 64 + cxx + j, dt);
    }
    #pragma unroll
    for (int i=0;i<MR;i++){
      int e = s_e[ryb+i];
      ushort4 h0 = *(const ushort4*)&he0b[(size_t)e*HD + cxx];
      ushort4 h1 = *(const ushort4*)&he0b[(size_t)e*HD + 64 + cxx];
      float4 o0, o1;
      o0.x = fmaxf(acc[i][0]+b0[0]+bf2f(h0.x), 0.f);
      o0.y = fmaxf(acc[i][1]+b0[1]+bf2f(h0.y), 0.f);
      o0.z = fmaxf(acc[i][2]+b0[2]+bf2f(h0.z), 0.f);
      o0.w = fmaxf(acc[i][3]+b0[3]+bf2f(h0.w), 0.f);
      o1.x = fmaxf(acc[i][4]+b1[0]+bf2f(h1.x), 0.f);
      o1.y = fmaxf(acc[i][5]+b1[1]+bf2f(h1.y), 0.f);
      o1.z = fmaxf(acc[i][6]+b1[2]+bf2f(h1.z), 0.f);
      o1.w = fmaxf(acc[i][7]+b1[3]+bf2f(h1.w), 0.f);
      *(float4*)&outf[(size_t)e*HD + cxx]      = o0;
      *(float4*)&outf[(size_t)e*HD + 64 + cxx] = o1;
    }
    return;
  }
  // LayerNorm family: bias/resid folded into acc, row stats via 16-lane
  // shfl_xor butterfly (row-group threads are contiguous lanes).
  {
    float bc[8], gc[8], tc[8];
    #pragma unroll
    for (int j=0;j<4;j++){
      bc[j]   = rg(bias,  prmoff + cxx + j,      dt);
      bc[4+j] = rg(bias,  prmoff + 64 + cxx + j, dt);
      gc[j]   = rg(gamma, prmoff + cxx + j,      dt);
      gc[4+j] = rg(gamma, prmoff + 64 + cxx + j, dt);
      tc[j]   = rg(beta,  prmoff + cxx + j,      dt);
      tc[4+j] = rg(beta,  prmoff + 64 + cxx + j, dt);
    }
    #pragma unroll
    for (int i=0;i<MR;i++){
      size_t grow = (size_t)(rbase + ryb + i);
      if constexpr (EP==E_RESID_LN){
        float4 r0 = *(const float4*)&resid[grow*HD + cxx];
        float4 r1 = *(const float4*)&resid[grow*HD + 64 + cxx];
        acc[i][0] = r0.x + fmaxf(acc[i][0]+bc[0], 0.f);
        acc[i][1] = r0.y + fmaxf(acc[i][1]+bc[1], 0.f);
        acc[i][2] = r0.z + fmaxf(acc[i][2]+bc[2], 0.f);
        acc[i][3] = r0.w + fmaxf(acc[i][3]+bc[3], 0.f);
        acc[i][4] = r1.x + fmaxf(acc[i][4]+bc[4], 0.f);
        acc[i][5] = r1.y + fmaxf(acc[i][5]+bc[5], 0.f);
        acc[i][6] = r1.z + fmaxf(acc[i][6]+bc[6], 0.f);
        acc[i][7] = r1.w + fmaxf(acc[i][7]+bc[7], 0.f);
      } else {
        #pragma unroll
        for (int j=0;j<8;j++) acc[i][j] += bc[j];
      }
      float sm=0.f, sq=0.f;
      #pragma unroll
      for (int j=0;j<8;j++){ sm += acc[i][j]; sq += acc[i][j]*acc[i][j]; }
      sm += __shfl_xor(sm,1); sq += __shfl_xor(sq,1);
      sm += __shfl_xor(sm,2); sq += __shfl_xor(sq,2);
      sm += __shfl_xor(sm,4); sq += __shfl_xor(sq,4);
      sm += __shfl_xor(sm,8); sq += __shfl_xor(sq,8);
      float mu  = sm*(1.f/128.f);
      float var = sq*(1.f/128.f) - mu*mu;
      float rs  = rsqrtf(fmaxf(var,0.f)+1e-5f);
      float y[8];
      #pragma unroll
      for (int j=0;j<8;j++){
        float v = (acc[i][j]-mu)*rs*gc[j] + tc[j];
        if constexpr (EP==E_LN_RELU || EP==E_LN_RELU_DUAL) v = fmaxf(v,0.f);
        if constexpr (EP==E_LN_RELU_TANH) v = tanhfast(fmaxf(v,0.f));
        y[j] = v;
      }
      *(float4*)&outf[grow*HD + cxx]      = make_float4(y[0],y[1],y[2],y[3]);
      *(float4*)&outf[grow*HD + 64 + cxx] = make_float4(y[4],y[5],y[6],y[7]);
      if constexpr (EP==E_LN_RELU_DUAL){
        ushort4 u0, u1;
        u0.x=f2bf(y[0]); u0.y=f2bf(y[1]); u0.z=f2bf(y[2]); u0.w=f2bf(y[3]);
        u1.x=f2bf(y[4]); u1.y=f2bf(y[5]); u1.z=f2bf(y[6]); u1.w=f2bf(y[7]);
        *(ushort4*)&outb[grow*HD + cxx]      = u0;
        *(ushort4*)&outb[grow*HD + 64 + cxx] = u1;
      }
    }
  }
}

// merged weight pre-convert: 4 (whh,bhh) pairs raw -> fp32 [49152|384] blocks
__global__ void k_cvt4(const void* w0,const void* b0,const void* w1,const void* b1,
                       const void* w2,const void* b2,const void* w3,const void* b3,
                       float* d0, float* d1, float* d2, float* d3, const int* dflag){
  int dt = *dflag;
  int p  = blockIdx.y;
  const void* wsrc = (p==0)?w0:(p==1)?w1:(p==2)?w2:w3;
  const void* bsrc = (p==0)?b0:(p==1)?b1:(p==2)?b2:b3;
  float* dst       = (p==0)?d0:(p==1)?d1:(p==2)?d2:d3;
  int i = blockIdx.x*256 + threadIdx.x;
  if (i < 49152)      dst[i] = rg(wsrc, i, dt);
  else if (i < 49536) dst[i] = rg(bsrc, i-49152, dt);
}

// BiGRU, W-in-registers (EXACT r6-measured 318us config — do not touch).
__launch_bounds__(384,1)
__global__ void k_gru(
  const u16* gi_f, const u16* gi_b,
  const float* wcf, const float* wcb,
  u16* out_seq, float* zbuf, int write_seq)
{
  const int dir = blockIdx.y;
  const int g0  = blockIdx.x * 4;
  const u16* gi  = dir ? gi_b : gi_f;
  const float* whh = dir ? wcb : wcf;
  const float* bh  = whh + 49152;

  __shared__ float sgh[384*5];               // [row d][graph g], stride 5
  __shared__ __align__(16) float sh[4*128];  // h state [g][d]

  const int tid = threadIdx.x;   // 0..383, owns gate-row d=tid

  float4 wreg[32];
  {
    const float4* wrow = (const float4*)(whh + (size_t)tid*128);
    #pragma unroll
    for (int i=0;i<32;i++) wreg[i] = wrow[i];
  }
  const float bhd = bh[tid];

  const int gA = tid>>7, dA = tid&127;

  for (int i=tid;i<512;i+=384) sh[i]=0.f;
  __syncthreads();

  for (int step=0; step<64; ++step){
    const int t = dir ? (63-step) : step;

    const u16* gpA = gi + (size_t)((g0+gA)*TSEQ + t)*384;
    u16 aR = gpA[dA], aZ = gpA[128+dA], aN = gpA[256+dA];
    u16 bR=0, bZ=0, bN=0;
    if (tid < 128){
      const u16* gpB = gi + (size_t)((g0+3)*TSEQ + t)*384;
      bR = gpB[tid]; bZ = gpB[128+tid]; bN = gpB[256+tid];
    }

    float a0=0.f, a1=0.f, a2=0.f, a3=0.f;
    #pragma unroll
    for (int k4=0; k4<32; k4++){
      float4 w  = wreg[k4];
      float4 h0 = *(const float4*)&sh[0*128 + k4*4];
      float4 h1 = *(const float4*)&sh[1*128 + k4*4];
      float4 h2 = *(const float4*)&sh[2*128 + k4*4];
      float4 h3 = *(const float4*)&sh[3*128 + k4*4];
      a0 += h0.x*w.x + h0.y*w.y + h0.z*w.z + h0.w*w.w;
      a1 += h1.x*w.x + h1.y*w.y + h1.z*w.z + h1.w*w.w;
      a2 += h2.x*w.x + h2.y*w.y + h2.z*w.z + h2.w*w.w;
      a3 += h3.x*w.x + h3.y*w.y + h3.z*w.z + h3.w*w.w;
    }
    sgh[tid*5+0] = a0 + bhd;
    sgh[tid*5+1] = a1 + bhd;
    sgh[tid*5+2] = a2 + bhd;
    sgh[tid*5+3] = a3 + bhd;
    __syncthreads();

    {
      float r = sigm(bf2f(aR) + sgh[dA*5+gA]);
      float z = sigm(bf2f(aZ) + sgh[(128+dA)*5+gA]);
      float n = tanhfast(bf2f(aN) + r*sgh[(256+dA)*5+gA]);
      float h = (1.f-z)*n + z*sh[gA*128+dA];
      sh[gA*128+dA] = h;
      if (write_seq){
        float hc = fminf(fmaxf(h,-10.f),10.f);
        out_seq[(size_t)((g0+gA)*TSEQ + t)*256 + dir*HD + dA] = f2bf(hc);
      }
    }
    if (tid < 128){
      float r = sigm(bf2f(bR) + sgh[tid*5+3]);
      float z = sigm(bf2f(bZ) + sgh[(128+tid)*5+3]);
      float n = tanhfast(bf2f(bN) + r*sgh[(256+tid)*5+3]);
      float h = (1.f-z)*n + z*sh[3*128+tid];
      sh[3*128+tid] = h;
      if (write_seq){
        float hc = fminf(fmaxf(h,-10.f),10.f);
        out_seq[(size_t)((g0+3)*TSEQ + t)*256 + dir*HD + tid] = f2bf(hc);
      }
    }
    __syncthreads();
  }

  if (!write_seq){
    for (int i=tid;i<512;i+=384){
      int g=i>>7, d=i&127;
      zbuf[(size_t)(g0+g)*256 + dir*HD + d] = fminf(fmaxf(sh[g*128+d],-10.f),10.f);
    }
  }
}

__launch_bounds__(64)
__global__ void k_gather(const float* he, const int* ptr, const int* cidx, float* out){
  int n = blockIdx.x;
  int c = threadIdx.x;
  int b = ptr[n], e = ptr[n+1];
  float s0=0.f,s1=0.f;
  for (int i=b;i<e;++i){
    int eid = cidx[i];
    float2 v = *(const float2*)(he + (size_t)eid*HD + c*2);
    s0+=v.x; s1+=v.y;
  }
  out[(size_t)n*HD + c*2]   = s0;
  out[(size_t)n*HD + c*2+1] = s1;
}

__global__ void k_count(const int* dst, int* cnt){
  int e = blockIdx.x*256+threadIdx.x;
  if (e<NE) atomicAdd(&cnt[dst[e]],1);
}

__launch_bounds__(1024)
__global__ void k_scan(const int* cnt, int* ptr){
  __shared__ int s[1024];
  int tid=threadIdx.x;
  int loc[32]; int tot=0;
  int base = tid*32;
  #pragma unroll
  for (int i=0;i<32;i++){ loc[i]=tot; tot += cnt[base+i]; }
  s[tid]=tot; __syncthreads();
  for (int off=1; off<1024; off<<=1){
    int v = (tid>=off)? s[tid-off] : 0;
    __syncthreads();
    s[tid] += v;
    __syncthreads();
  }
  int ex = s[tid] - tot;
  for (int i=0;i<32;i++) ptr[base+i] = ex + loc[i];
  if (tid==1023) ptr[NN] = ex + tot;
}

__global__ void k_fill(const int* dst, const int* ptr, int* cur, int* cidx){
  int e = blockIdx.x*256+threadIdx.x;
  if (e<NE){
    int d = dst[e];
    int p = ptr[d] + atomicAdd(&cur[d],1);
    cidx[p] = e;
  }
}

// runtime input-dtype detector (fp32 low-halfword exponents ~uniform; bf16 ~always in-range)
__global__ void k_detect(const u16* x, int* flag){
  __shared__ int cnt;
  if (threadIdx.x==0) cnt=0;
  __syncthreads();
  u16 u = x[threadIdx.x*2];
  int e = (u>>7)&0xff;
  if (e>=100 && e<=135) atomicAdd(&cnt,1);
  __syncthreads();
  if (threadIdx.x==0) *flag = (cnt>=128) ? 1 : 0;
}

__launch_bounds__(256)
__global__ void k_bnstats(const float* z, const void* bng, const void* bnb, float* st, const int* dflag){
  int dt = *dflag;
  int c = threadIdx.x;
  float sm=0.f, sq=0.f;
  for (int g=0; g<NG; ++g){ float v = z[(size_t)g*256+c]; sm+=v; sq+=v*v; }
  float mu = sm*(1.f/(float)NG);
  float var = sq*(1.f/(float)NG) - mu*mu;
  float rs = rsqrtf(fmaxf(var,0.f)+1e-5f);
  float sc = rs*rg(bng,c,dt);
  st[c] = sc;
  st[256+c] = rg(bnb,c,dt) - mu*sc;
}

// OUTPUT fp32 (confirmed: finite ref-scale error under fp32 writes)
__global__ void k_pred(const float* z, const float* st, const void* pw, const void* pb, float* out, const int* dflag){
  int dt = *dflag;
  int g = blockIdx.x*256+threadIdx.x;
  if (g>=NG) return;
  float acc = rg(pb,0,dt);
  for (int c=0;c<256;c++) acc += (z[(size_t)g*256+c]*st[c] + st[256+c])*rg(pw,c,dt);
  out[g]=acc;
}

extern "C" void kernel_launch(void* const* d_in, const int* in_sizes, int n_in,
                              void* d_out, int out_size, void* d_ws, size_t ws_size,
                              hipStream_t stream)
{
  const void* X    =d_in[0];
  const void* EA   =d_in[1];
  const void* NW   =d_in[2];
  const void* NB   =d_in[3];
  const void* NGa  =d_in[4];
  const void* NBt  =d_in[5];
  const void* EW   =d_in[6];
  const void* EB   =d_in[7];
  const void* EGa  =d_in[8];
  const void* EBt  =d_in[9];
  const void* LW   =d_in[10];
  const void* LB   =d_in[11];
  const void* LGa  =d_in[12];
  const void* LBt  =d_in[13];
  const void* NUW  =d_in[14];
  const void* NUB  =d_in[15];
  const void* NNG  =d_in[16];
  const void* NNB  =d_in[17];
  const void* EUW  =d_in[18];
  const void* EUB  =d_in[19];
  const void* BOOST=d_in[20];
  const void* BIHW_F=d_in[21];
  const void* BHHW_F=d_in[22];
  const void* BIHB_F=d_in[23];
  const void* BHHB_F=d_in[24];
  const void* BIHW_B=d_in[25];
  const void* BHHW_B=d_in[26];
  const void* BIHB_B=d_in[27];
  const void* BHHB_B=d_in[28];
  const void* PW   =d_in[29];
  const void* PB   =d_in[30];
  const void* PG   =d_in[31];
  const void* PBt  =d_in[32];
  const void* FW   =d_in[33];
  const void* FB   =d_in[34];
  const void* FG   =d_in[35];
  const void* FBt  =d_in[36];
  const void* RIHW_F=d_in[37];
  const void* RHHW_F=d_in[38];
  const void* RIHB_F=d_in[39];
  const void* RHHB_F=d_in[40];
  const void* RIHW_B=d_in[41];
  const void* RHHW_B=d_in[42];
  const void* RIHB_B=d_in[43];
  const void* RHHB_B=d_in[44];
  const void* BNG  =d_in[45];
  const void* BNB  =d_in[46];
  const void* PRW  =d_in[47];
  const void* PRB  =d_in[48];
  const int* EIDX =(const int*)d_in[49];
  const int* DST  = EIDX + NE;

  // ---- Workspace (EXACT r9 proven map; peak < 118MB) ----
  char* ws=(char*)d_ws;
  const size_t MB = 1048576;
  int*   csrp =(int*)  (ws + 0);
  int*   csrc =(int*)  (ws + 135168);
  int*   csri =(int*)  (ws + 266240);
  float* zbuf =(float*)(ws + 790528);
  float* stats=(float*)(ws + 1314816);
  int*   dflag=(int*)  (ws + 1316864);
  float* wbgf =(float*)(ws + 2*MB);          // [49152 whh | 384 bhh] fp32, boost fwd
  float* wbgb = wbgf + 49536;                // boost bwd
  float* wrgf = wbgb + 49536;                // readout fwd
  float* wrgb = wrgf + 49536;                // readout bwd
  float* hv   =(float*)(ws + 6*MB);          // [6,22)
  u16*   he0  =(u16*)  (ws + 22*MB);         // [22,54), dead after last edge
  float* he   =(float*)(ws + 54*MB);         // [54,118), dead after k_gather
  float* mfin =(float*)(ws + 22*MB);         // aliases he0 (dead)
  u16*   gif  =(u16*)  (ws + 54*MB);         // aliases he (dead), [54,78)
  u16*   gib  =(u16*)  (ws + 78*MB);         // [78,102)
  u16*   oseq =(u16*)  (ws + 6*MB);          // aliases hv (dead after boost-GI)
  float* hv2  =(float*)(ws + 38*MB);         // [38,54)
  float* hx2  =(float*)(ws + 6*MB);          // aliases oseq (dead after proj)
  float* fout =(float*)(ws + 54*MB);         // aliases gif (dead), [54,70)
  u16*   gif_r=(u16*)  (ws + 70*MB);         // [70,94)
  u16*   gib_r=(u16*)  (ws + 94*MB);         // [94,118)

  k_detect<<<dim3(1),dim3(256),0,stream>>>((const u16*)X, dflag);

  // pre-convert recurrent GRU weights to fp32 (one merged launch)
  k_cvt4<<<dim3(194,4),dim3(256),0,stream>>>(
      BHHW_F,BHHB_F, BHHW_B,BHHB_B, RHHW_F,RHHB_F, RHHW_B,RHHB_B,
      wbgf, wbgb, wrgf, wrgb, dflag);

  // CSR over dst
  hipMemsetAsync(csrc, 0, 131072, stream);
  k_count<<<dim3(512),dim3(256),0,stream>>>(DST, csrc);
  k_scan<<<dim3(1),dim3(1024),0,stream>>>(csrc, csrp);
  hipMemsetAsync(csrc, 0, 131072, stream);
  k_fill<<<dim3(512),dim3(256),0,stream>>>(DST, csrp, csrc, csri);

  // init embeddings (32-row LN tiles -> 4+ blocks/CU)
  k_dense<A_XF,E_LN_RELU,3,1,32><<<dim3(1024),dim3(256),0,stream>>>(X,nullptr,nullptr,
      nullptr,nullptr,nullptr,nullptr, NW,nullptr,0, NB,nullptr,NGa,NBt,0, nullptr,nullptr,
      hv,nullptr,nullptr, dflag, 133,133,HD,0);
  k_dense<A_XF,E_LN_RELU_DUAL,1,1,32><<<dim3(4096),dim3(256),0,stream>>>(EA,nullptr,nullptr,
      nullptr,nullptr,nullptr,nullptr, EW,nullptr,0, EB,nullptr,EGa,EBt,0, nullptr,nullptr,
      he,he0,nullptr, dflag, 14,14,HD,0);

  // message passing (msg: 32-row; edge: 32-row -> ~6 blocks/CU)
  for (int s=0;s<5;s++){
    k_dense<A_MSG,E_RESID_LN,4,1,32><<<dim3(1024),dim3(256),0,stream>>>(hv,he,nullptr,
        nullptr,csrp,csri,nullptr, NUW,nullptr,s*32768, NUB,nullptr,NNG,NNB,s*128,
        hv,nullptr, hv,nullptr,nullptr, dflag, 256,HD,HD,0);
    k_dense<A_EDGE,E_HE0_RELU,2,1,32><<<dim3(4096),dim3(256),0,stream>>>(hv,he,nullptr,
        DST,nullptr,nullptr,nullptr, EUW,nullptr,s*16384, EUB,nullptr,nullptr,nullptr,s*128,
        nullptr,he0, he,nullptr,nullptr, dflag, 128,HD,HD,0);
  }
  k_gather<<<dim3(NN),dim3(64),0,stream>>>(he, csrp, csri, mfin);

  // boost GRU input-side gates: ONE launch, 6 weight segments (frozen geometry)
  k_dense<A_BOOST,E_GI,1,6,64><<<dim3(512),dim3(256),0,stream>>>(hv,nullptr,nullptr,
      nullptr,nullptr,nullptr,BOOST, BIHW_F,BIHW_B,0, BIHB_F,BIHB_B,nullptr,nullptr,0,
      nullptr,nullptr, nullptr,gif,gib, dflag, 128,HD,384,0);
  k_gru<<<dim3(128,2),dim3(384),0,stream>>>(gif, gib, wbgf, wbgb, oseq, zbuf, 1);

  // proj + recompute hx + final merge (32-row LN tiles)
  k_dense<A_B16,E_LN_RELU_TANH,4,1,32><<<dim3(1024),dim3(256),0,stream>>>(oseq,nullptr,nullptr,
      nullptr,nullptr,nullptr,nullptr, PW,nullptr,0, PB,nullptr,PG,PBt,0, nullptr,nullptr,
      hv2,nullptr,nullptr, dflag, 256,256,HD,0);
  k_dense<A_XF,E_LN,3,1,32><<<dim3(1024),dim3(256),0,stream>>>(X,nullptr,nullptr,
      nullptr,nullptr,nullptr,nullptr, LW,nullptr,0, LB,nullptr,LGa,LBt,0, nullptr,nullptr,
      hx2,nullptr,nullptr, dflag, 133,133,HD,0);
  k_dense<A_C3,E_LN_RELU,6,1,32><<<dim3(1024),dim3(256),0,stream>>>(hv2,mfin,hx2,
      nullptr,nullptr,nullptr,nullptr, FW,nullptr,0, FB,nullptr,FG,FBt,0, nullptr,nullptr,
      fout,nullptr,nullptr, dflag, 384,HD,HD,0);

  // readout GRU gates (ONE launch, 6 segments) + GRU
  k_dense<A_F32,E_GI,1,6,64><<<dim3(512),dim3(256),0,stream>>>(fout,nullptr,nullptr,
      nullptr,nullptr,nullptr,nullptr, RIHW_F,RIHW_B,0, RIHB_F,RIHB_B,nullptr,nullptr,0,
      nullptr,nullptr, nullptr,gif_r,gib_r, dflag, 128,HD,384,0);
  k_gru<<<dim3(128,2),dim3(384),0,stream>>>(gif_r, gib_r, wrgf, wrgb, oseq, zbuf, 0);

  // BN + prediction
  k_bnstats<<<dim3(1),dim3(256),0,stream>>>(zbuf, BNG, BNB, stats, dflag);
  k_pred<<<dim3(2),dim3(256),0,stream>>>(zbuf, stats, PRW, PRB, (float*)d_out, dflag);

  (void)in_sizes; (void)n_in; (void)out_size; (void)ws_size;
}